// Round 6
// baseline (3474.088 us; speedup 1.0000x reference)
//
#include <hip/hip_runtime.h>
#include <hip/hip_bf16.h>
#include <math.h>

#define NP 65536L
#define HHH 256
#define WWW 256
#define QKCH 16

typedef unsigned short u16;
typedef unsigned short ushort8_t __attribute__((ext_vector_type(8)));
typedef short s16x8 __attribute__((ext_vector_type(8)));
typedef float f32x4 __attribute__((ext_vector_type(4)));

__device__ __forceinline__ float bf2f(u16 u) { return __uint_as_float(((unsigned)u) << 16); }
__device__ __forceinline__ u16 f2bf(float f) {
    __hip_bfloat16 h = __float2bfloat16(f);
    return *reinterpret_cast<u16*>(&h);
}
__device__ __forceinline__ float sigmoidf_(float x) { return 1.f / (1.f + __expf(-x)); }
__device__ __forceinline__ float gelu_exact(float x) {
    return 0.5f * x * (1.f + erff(x * 0.70710678118654752f));
}

__global__ void diag_kernel(float* out, float v) {
    if (threadIdx.x == 0 && blockIdx.x == 0) out[0] = v;
}

// fp32 -> bf16 bulk convert (n multiple of 4; grid = n/1024)
__global__ __launch_bounds__(256) void cvt_f2b(const float* __restrict__ src,
                                               u16* __restrict__ dst, long n)
{
    long i = ((long)blockIdx.x * 256 + threadIdx.x) * 4;
    if (i >= n) return;
    float4 v = *(const float4*)(src + i);
    ushort4 o;
    o.x = f2bf(v.x); o.y = f2bf(v.y); o.z = f2bf(v.z); o.w = f2bf(v.w);
    *(ushort4*)(dst + i) = o;
}

// ---------------------------------------------------------------------------
// MFMA bf16 GEMM for 1x1 conv: out[b][o][p] = sum_c w[o][c] * in[b][c][p]
// block: 256 thr = 4 waves; tile M=64 o x N=256 px; K chunks of 64.
// LDS: XT transposed [px][c] (pad 8) so B-frag = one ds_read_b128.
// grid (M/64, 256, nb)
// ---------------------------------------------------------------------------
template<int OUT_BF16, int RESID, int DUAL, int BIAS>
__global__ __launch_bounds__(256) void gemm_mfma(
    const u16* __restrict__ in, long inBS,
    const u16* __restrict__ wbf, long wBS,
    const float* __restrict__ bias,
    const float* __restrict__ resid, long resBS,
    void* __restrict__ outp, long outBS,
    float* __restrict__ out2, long out2BS,
    int Cin)
{
    __shared__ u16 XT[256][72];
    __shared__ u16 WT[64][72];
    int b = blockIdx.z;
    int oBase = blockIdx.x * 64;
    long P0 = (long)blockIdx.y * 256;
    int tid = threadIdx.x;
    int lane = tid & 63, wave = tid >> 6;
    const u16* inB = in + (long)b * inBS;
    const u16* wB = wbf + (long)b * wBS;

    f32x4 acc[4][4];
#pragma unroll
    for (int m = 0; m < 4; ++m)
#pragma unroll
        for (int n = 0; n < 4; ++n) acc[m][n] = (f32x4){0.f, 0.f, 0.f, 0.f};

    for (int ck = 0; ck < Cin; ck += 64) {
        if (ck) __syncthreads();
        {   // stage weights chunk [64 o][64 c]
            int o = tid >> 2, cs = (tid & 3) * 16;
            const u16* src = wB + (long)(oBase + o) * Cin + ck + cs;
            ushort8_t w0 = *(const ushort8_t*)src;
            ushort8_t w1 = *(const ushort8_t*)(src + 8);
            *(ushort8_t*)&WT[o][cs] = w0;
            *(ushort8_t*)&WT[o][cs + 8] = w1;
        }
        {   // stage X chunk transposed: [256 px][64 c]
            int c0 = (tid & 7) * 8;
            int pt = (tid >> 3) * 8;
            ushort8_t r[8];
#pragma unroll
            for (int i = 0; i < 8; ++i)
                r[i] = *(const ushort8_t*)(inB + (long)(ck + c0 + i) * NP + P0 + pt);
#pragma unroll
            for (int j = 0; j < 8; ++j) {
                ushort8_t v;
#pragma unroll
                for (int i = 0; i < 8; ++i) v[i] = r[i][j];
                *(ushort8_t*)&XT[pt + j][c0] = v;
            }
        }
        __syncthreads();
        int rl = lane & 15;
#pragma unroll
        for (int ks = 0; ks < 2; ++ks) {
            int kc = ks * 32 + (lane >> 4) * 8;
            s16x8 a[4], bb[4];
#pragma unroll
            for (int m = 0; m < 4; ++m)
                a[m] = *(const s16x8*)&WT[m * 16 + rl][kc];
#pragma unroll
            for (int n = 0; n < 4; ++n)
                bb[n] = *(const s16x8*)&XT[wave * 64 + n * 16 + rl][kc];
#pragma unroll
            for (int m = 0; m < 4; ++m)
#pragma unroll
                for (int n = 0; n < 4; ++n)
                    acc[m][n] = __builtin_amdgcn_mfma_f32_16x16x32_bf16(
                        a[m], bb[n], acc[m][n], 0, 0, 0);
        }
    }
    // epilogue: D col = lane&15 (pixel), row = (lane>>4)*4 + reg (o)
    int rl = lane & 15, rg = lane >> 4;
#pragma unroll
    for (int m = 0; m < 4; ++m) {
        int o0 = oBase + m * 16 + rg * 4;
#pragma unroll
        for (int n = 0; n < 4; ++n) {
            long px = P0 + wave * 64 + n * 16 + rl;
#pragma unroll
            for (int r = 0; r < 4; ++r) {
                int oo = o0 + r;
                float v = acc[m][n][r];
                if (BIAS) v += bias[oo];
                if (RESID) v += resid[(long)b * resBS + (long)oo * NP + px];
                if (OUT_BF16) ((u16*)outp)[(long)b * outBS + (long)oo * NP + px] = f2bf(v);
                else ((float*)outp)[(long)b * outBS + (long)oo * NP + px] = v;
                if (DUAL) out2[(long)b * out2BS + (long)oo * NP + px] = v;
            }
        }
    }
}

// LN standardize pre-pass: XN = (X - mu)/sqrt(var+eps), bf16. grid (256, nb)
__global__ __launch_bounds__(256) void ln_norm(
    const float* __restrict__ X, u16* __restrict__ XN)
{
    int b = blockIdx.y;
    long p = (long)blockIdx.x * 256 + threadIdx.x;
    const float* xb = X + (long)b * 64 * NP + p;
    float x[64];
    float s = 0.f, s2 = 0.f;
#pragma unroll
    for (int c = 0; c < 64; ++c) {
        x[c] = xb[(long)c * NP];
        s += x[c]; s2 = fmaf(x[c], x[c], s2);
    }
    float mu = s * (1.f / 64.f);
    float var = fmaxf(s2 * (1.f / 64.f) - mu * mu, 0.f);
    float inv = rsqrtf(var + 1e-5f);
    u16* xo = XN + (long)b * 64 * NP + p;
#pragma unroll
    for (int c = 0; c < 64; ++c) xo[(long)c * NP] = f2bf((x[c] - mu) * inv);
}

// fold LN gamma/beta into qkv / ffn-in weights; bf16 weights + fp32 bias.
__global__ void fold_ln(
    const float* __restrict__ wqkv, const float* __restrict__ ln1w, const float* __restrict__ ln1b,
    const float* __restrict__ win,  const float* __restrict__ ln2w, const float* __restrict__ ln2b,
    u16* __restrict__ fq, float* __restrict__ fqB,
    u16* __restrict__ ff, float* __restrict__ ffB)
{
    int g = blockIdx.x;
    int i = g / 7, r = g % 7;
    const float *wsrc, *lg, *lb;
    u16* wd; float* Bd;
    int obase;
    if (r < 3) {
        wsrc = wqkv + (long)i * 192 * 64; lg = ln1w + i * 64; lb = ln1b + i * 64;
        wd = fq + (long)i * 192 * 64; Bd = fqB + i * 192; obase = r * 64;
    } else {
        wsrc = win + (long)i * 256 * 64; lg = ln2w + i * 64; lb = ln2b + i * 64;
        wd = ff + (long)i * 256 * 64; Bd = ffB + i * 256; obase = (r - 3) * 64;
    }
    int o = obase + threadIdx.x;
    float Bv = 0.f;
    for (int c = 0; c < 64; ++c) {
        float wv = wsrc[(long)o * 64 + c];
        wd[(long)o * 64 + c] = f2bf(wv * lg[c]);
        Bv += wv * lb[c];
    }
    Bd[o] = Bv;
}

// per-(b,c) mean of bf16 buffer. grid (C, nb)
__global__ __launch_bounds__(256) void chanreduce_bf(
    const u16* __restrict__ in, long bs, float* __restrict__ out,
    int C, float scale)
{
    int c = blockIdx.x, b = blockIdx.y;
    const u16* p = in + (long)b * bs + (long)c * NP;
    float s = 0.f;
    for (long i = threadIdx.x * 4; i < NP; i += 1024) {
        ushort4 u = *(const ushort4*)(p + i);
        s += bf2f(u.x) + bf2f(u.y) + bf2f(u.z) + bf2f(u.w);
    }
    __shared__ float red[256];
    red[threadIdx.x] = s;
    __syncthreads();
    for (int st = 128; st > 0; st >>= 1) {
        if (threadIdx.x < st) red[threadIdx.x] += red[threadIdx.x + st];
        __syncthreads();
    }
    if (threadIdx.x == 0) out[b * C + c] = red[0] * scale;
}

// stage one LDS row (16 px) of a bf16 channel strip
__device__ __forceinline__ void stage_row(float (*S)[260], const u16* __restrict__ src,
                                          int y0, int j, int px)
{
    int row = y0 - 1 + j;
    if (row >= 0 && row < HHH) {
        ushort8_t a = *(const ushort8_t*)(src + row * WWW + px);
        ushort8_t b = *(const ushort8_t*)(src + row * WWW + px + 8);
#pragma unroll
        for (int e = 0; e < 8; ++e) { S[j][1 + px + e] = bf2f(a[e]); S[j][9 + px + e] = bf2f(b[e]); }
    } else {
#pragma unroll
        for (int e = 0; e < 16; ++e) S[j][1 + px + e] = 0.f;
    }
}
__device__ __forceinline__ float conv9(const float (*S)[260], int r, int col,
                                       const float* __restrict__ w9)
{
    float a = 0.f;
#pragma unroll
    for (int ky = 0; ky < 3; ++ky)
#pragma unroll
        for (int kx = 0; kx < 3; ++kx)
            a = fmaf(w9[ky * 3 + kx], S[r + ky][col + kx], a);
    return a;
}

// depthwise 3x3, 16-row strips. grid (16, C, nb)
__global__ __launch_bounds__(256) void dw3x3_strip(
    const u16* __restrict__ in, long inBS, const float* __restrict__ w,
    u16* __restrict__ out, long outBS)
{
    int strip = blockIdx.x, c = blockIdx.y, b = blockIdx.z;
    int y0 = strip * 16, tid = threadIdx.x;
    __shared__ float S[18][260];
    const u16* src = in + (long)b * inBS + (long)c * NP;
    int j = tid >> 4, px = (tid & 15) * 16;
    stage_row(S, src, y0, j, px);
    if (tid < 32) stage_row(S, src, y0, 16 + (tid >> 4), px);
    if (tid < 18) { S[tid][0] = 0.f; S[tid][257] = 0.f; }
    __syncthreads();
    float w9[9];
#pragma unroll
    for (int k = 0; k < 9; ++k) w9[k] = w[c * 9 + k];
    u16* dst = out + (long)b * outBS + (long)c * NP;
#pragma unroll
    for (int r = 0; r < 16; ++r)
        dst[(y0 + r) * WWW + tid] = f2bf(conv9(S, r, tid, w9));
}

// ffn: dw3x3 on (c, c+128) + gelu(y1)*y2, strips. grid (16, 128, nb)
__global__ __launch_bounds__(256) void ffn_dw_glu_strip(
    const u16* __restrict__ y, long yBS, const float* __restrict__ w,
    u16* __restrict__ g, long gBS)
{
    int strip = blockIdx.x, c = blockIdx.y, b = blockIdx.z;
    int y0 = strip * 16, tid = threadIdx.x;
    __shared__ float S1[18][260];
    __shared__ float S2[18][260];
    const u16* s1 = y + (long)b * yBS + (long)c * NP;
    const u16* s2 = y + (long)b * yBS + (long)(c + 128) * NP;
    int j = tid >> 4, px = (tid & 15) * 16;
    stage_row(S1, s1, y0, j, px);
    if (tid < 32) stage_row(S1, s1, y0, 16 + (tid >> 4), px);
    stage_row(S2, s2, y0, j, px);
    if (tid < 32) stage_row(S2, s2, y0, 16 + (tid >> 4), px);
    if (tid < 18) { S1[tid][0] = S1[tid][257] = 0.f; S2[tid][0] = S2[tid][257] = 0.f; }
    __syncthreads();
    float w1[9], w2[9];
#pragma unroll
    for (int k = 0; k < 9; ++k) { w1[k] = w[c * 9 + k]; w2[k] = w[(c + 128) * 9 + k]; }
    u16* dst = g + (long)b * gBS + (long)c * NP;
#pragma unroll
    for (int r = 0; r < 16; ++r) {
        float a1 = conv9(S1, r, tid, w1);
        float a2 = conv9(S2, r, tid, w2);
        dst[(y0 + r) * WWW + tid] = f2bf(gelu_exact(a1) * a2);
    }
}

// CIIM grouped dw conv, strips. grid (16, 64, nb)
__global__ __launch_bounds__(256) void ciim_dw_strip(
    const u16* __restrict__ fuse, long fBS, const float* __restrict__ means,
    const float* __restrict__ wdw, const float* __restrict__ bdw,
    u16* __restrict__ hl, long hlBS)
{
    int strip = blockIdx.x, c = blockIdx.y, b = blockIdx.z;
    int y0 = strip * 16, tid = threadIdx.x;
    __shared__ float S[18][260];
    float acc[16];
    float bias = bdw[c];
#pragma unroll
    for (int r = 0; r < 16; ++r) acc[r] = bias;
    for (int j6 = 0; j6 < 6; ++j6) {
        int ic = 6 * c + j6;
        const float* w9p = wdw + (c * 6 + j6) * 9;
        float w9[9];
#pragma unroll
        for (int k = 0; k < 9; ++k) w9[k] = w9p[k];
        if (ic < 128) {
            __syncthreads();
            const u16* src = fuse + (long)b * fBS + (long)ic * NP;
            int j = tid >> 4, px = (tid & 15) * 16;
            stage_row(S, src, y0, j, px);
            if (tid < 32) stage_row(S, src, y0, 16 + (tid >> 4), px);
            if (tid < 18) { S[tid][0] = 0.f; S[tid][257] = 0.f; }
            __syncthreads();
#pragma unroll
            for (int r = 0; r < 16; ++r) acc[r] += conv9(S, r, tid, w9);
        } else {
            float mv = means[b * 256 + ic - 128];
#pragma unroll
            for (int r = 0; r < 16; ++r) {
                int row = y0 + r;
                float ws = 0.f;
#pragma unroll
                for (int ky = 0; ky < 3; ++ky) {
                    int yy = row + ky - 1;
                    if (yy < 0 || yy >= HHH) continue;
#pragma unroll
                    for (int kx = 0; kx < 3; ++kx) {
                        int xx = tid + kx - 1;
                        if (xx < 0 || xx >= WWW) continue;
                        ws += w9[ky * 3 + kx];
                    }
                }
                acc[r] += mv * ws;
            }
        }
    }
    u16* dst = hl + (long)b * hlBS + (long)c * NP;
#pragma unroll
    for (int r = 0; r < 16; ++r) dst[(y0 + r) * WWW + tid] = f2bf(acc[r]);
}

// gating + concat + channel shuffle. grid (64, 128, nb)
__global__ __launch_bounds__(256) void outsh4(
    const u16* __restrict__ hl, long hlBS,
    const float* __restrict__ low, long lBS,
    const float* __restrict__ high,
    u16* __restrict__ outb, long oBS)
{
    long p = ((long)blockIdx.x * 256 + threadIdx.x) * 4;
    int cn = blockIdx.y, b = blockIdx.z;
    int co = (cn & 31) * 4 + (cn >> 5);
    const u16* hp;
    const float* sp;
    if (co < 64) {
        hp = hl + (long)b * hlBS + (long)co * NP + p;
        sp = low + (long)b * lBS + (long)co * NP + p;
    } else {
        hp = hl + (long)b * hlBS + (long)(co - 64) * NP + p;
        sp = high + (long)b * lBS + (long)(co - 64) * NP + p;
    }
    ushort4 hu = *(const ushort4*)hp;
    float4 sv = *(const float4*)sp;
    float hv[4] = {bf2f(hu.x), bf2f(hu.y), bf2f(hu.z), bf2f(hu.w)};
    float s4[4] = {sv.x, sv.y, sv.z, sv.w};
    ushort4 ovec;
    u16* ov = (u16*)&ovec;
#pragma unroll
    for (int k = 0; k < 4; ++k) {
        float gg = (co < 64) ? sigmoidf_(gelu_exact(hv[k])) : sigmoidf_(fmaxf(hv[k], 0.f));
        ov[k] = f2bf(gg * s4[k]);
    }
    *(ushort4*)((u16*)outb + (long)b * oBS + (long)cn * NP + p) = ovec;
}

// scaled rc2 weights (bf16). grid (nb*32)
__global__ __launch_bounds__(256) void rc2w_build(
    const float* __restrict__ ecam, const float* __restrict__ ecaw,
    const float* __restrict__ wrc2, u16* __restrict__ wout)
{
    int idx = blockIdx.x * 256 + threadIdx.x;
    int c = idx & 127, o = (idx >> 7) & 63, b = idx >> 13;
    float y = sigmoidf_(ecam[b * 128 + c] * ecaw[c]);
    wout[idx] = f2bf(wrc2[o * 128 + c] * y);
}

// q.k dots + sumsq norms over pixel chunks. grid (QKCH, 8, nb)
__global__ __launch_bounds__(256) void qk_dot(
    const u16* __restrict__ D, long dBS, float* __restrict__ part)
{
    int chunk = blockIdx.x, h = blockIdx.y, b = blockIdx.z;
    int tid = threadIdx.x, lane = tid & 63, wave = tid >> 6;
    const u16* q = D + (long)b * dBS + (long)(h * 8) * NP;
    const u16* k = q + 64 * NP;
    float dots[64], nq[8], nk[8];
#pragma unroll
    for (int a = 0; a < 64; ++a) dots[a] = 0.f;
#pragma unroll
    for (int a = 0; a < 8; ++a) { nq[a] = 0.f; nk[a] = 0.f; }
    long base = (long)chunk * 4096 + tid * 8;
    for (int pass = 0; pass < 2; ++pass) {
        long p = base + pass * 2048;
        ushort8_t qv[8], kv[8];
#pragma unroll
        for (int i = 0; i < 8; ++i) qv[i] = *(const ushort8_t*)(q + (long)i * NP + p);
#pragma unroll
        for (int i = 0; i < 8; ++i) kv[i] = *(const ushort8_t*)(k + (long)i * NP + p);
#pragma unroll
        for (int e = 0; e < 8; ++e) {
            float qe[8], ke[8];
#pragma unroll
            for (int i = 0; i < 8; ++i) { qe[i] = bf2f(qv[i][e]); ke[i] = bf2f(kv[i][e]); }
#pragma unroll
            for (int i = 0; i < 8; ++i) {
                nq[i] = fmaf(qe[i], qe[i], nq[i]);
                nk[i] = fmaf(ke[i], ke[i], nk[i]);
#pragma unroll
                for (int jj = 0; jj < 8; ++jj)
                    dots[i * 8 + jj] = fmaf(qe[i], ke[jj], dots[i * 8 + jj]);
            }
        }
    }
    __shared__ float red[4][80];
#pragma unroll
    for (int a = 0; a < 64; ++a) {
        float v = dots[a];
#pragma unroll
        for (int o = 32; o > 0; o >>= 1) v += __shfl_xor(v, o);
        if (lane == 0) red[wave][a] = v;
    }
#pragma unroll
    for (int a = 0; a < 8; ++a) {
        float v1 = nq[a], v2 = nk[a];
#pragma unroll
        for (int o = 32; o > 0; o >>= 1) { v1 += __shfl_xor(v1, o); v2 += __shfl_xor(v2, o); }
        if (lane == 0) { red[wave][64 + a] = v1; red[wave][72 + a] = v2; }
    }
    __syncthreads();
    if (tid < 80) {
        float v = red[0][tid] + red[1][tid] + red[2][tid] + red[3][tid];
        part[(((long)b * 8 + h) * 80 + tid) * QKCH + chunk] = v;
    }
}

// reduce partials + softmax + Weff (bf16). grid (nb), block 64
__global__ void attn_finalize(
    const float* __restrict__ part, const float* __restrict__ temp,
    const float* __restrict__ wproj, u16* __restrict__ weffb)
{
    int b = blockIdx.x, t = threadIdx.x;
    __shared__ float Sg[8][80];
    __shared__ float att[8][8][8];
    for (int h = 0; h < 8; ++h)
        for (int e = t; e < 80; e += 64) {
            const float* pp = part + (((long)b * 8 + h) * 80 + e) * QKCH;
            float s = 0.f;
#pragma unroll
            for (int c = 0; c < QKCH; ++c) s += pp[c];
            Sg[h][e] = s;
        }
    __syncthreads();
    {
        int h = t >> 3, iq = t & 7;
        float nqv = fmaxf(sqrtf(Sg[h][64 + iq]), 1e-12f);
        float tp = temp[h];
        float row[8], mx = -1e30f;
#pragma unroll
        for (int jj = 0; jj < 8; ++jj) {
            float nkv = fmaxf(sqrtf(Sg[h][72 + jj]), 1e-12f);
            row[jj] = Sg[h][iq * 8 + jj] / (nqv * nkv) * tp;
            mx = fmaxf(mx, row[jj]);
        }
        float sum = 0.f;
#pragma unroll
        for (int jj = 0; jj < 8; ++jj) { row[jj] = __expf(row[jj] - mx); sum += row[jj]; }
        float rinv = 1.f / sum;
#pragma unroll
        for (int jj = 0; jj < 8; ++jj) att[h][iq][jj] = row[jj] * rinv;
    }
    __syncthreads();
    for (int cv = 0; cv < 64; ++cv) {
        int h = cv >> 3, jj = cv & 7;
        float s = 0.f;
#pragma unroll
        for (int i = 0; i < 8; ++i) s = fmaf(wproj[t * 64 + h * 8 + i], att[h][i][jj], s);
        weffb[((long)b * 64 + t) * 64 + cv] = f2bf(s);
    }
}

// head conv1: 3x3, 64->32, leaky. grid (64, 2, nb)
__global__ __launch_bounds__(256) void head_conv1(
    const float* __restrict__ x, const float* __restrict__ w,
    float* __restrict__ out)
{
    int b = blockIdx.z;
    int oBase = blockIdx.y * 16;
    int r = threadIdx.x >> 6;
    int lx = threadIdx.x & 63;
    int y = blockIdx.x * 4 + r;
    int x0 = lx * 4;
    __shared__ float wl[64][9][16];
    for (int idx = threadIdx.x; idx < 64 * 9 * 16; idx += 256) {
        int o = idx & 15, tap = (idx >> 4) % 9, c = idx / 144;
        wl[c][tap][o] = w[((long)(oBase + o) * 64 + c) * 9 + tap];
    }
    __syncthreads();
    float acc[16][4];
#pragma unroll
    for (int o = 0; o < 16; ++o)
#pragma unroll
        for (int px = 0; px < 4; ++px) acc[o][px] = 0.f;
    for (int c = 0; c < 64; ++c) {
        const float* src = x + ((long)b * 64 + c) * NP;
        float row[3][6];
#pragma unroll
        for (int ky = 0; ky < 3; ++ky) {
            int yy = y + ky - 1;
            bool yok = (yy >= 0 && yy < HHH);
#pragma unroll
            for (int dx = 0; dx < 6; ++dx) {
                int xx = x0 + dx - 1;
                row[ky][dx] = (yok && xx >= 0 && xx < WWW) ? src[yy * WWW + xx] : 0.f;
            }
        }
#pragma unroll
        for (int ky = 0; ky < 3; ++ky)
#pragma unroll
            for (int kx = 0; kx < 3; ++kx) {
                int tap = ky * 3 + kx;
#pragma unroll
                for (int px = 0; px < 4; ++px) {
                    float xv = row[ky][kx + px];
#pragma unroll
                    for (int o = 0; o < 16; ++o)
                        acc[o][px] = fmaf(wl[c][tap][o], xv, acc[o][px]);
                }
            }
    }
#pragma unroll
    for (int o = 0; o < 16; ++o) {
        float v[4];
#pragma unroll
        for (int px = 0; px < 4; ++px) {
            float a = acc[o][px];
            v[px] = a > 0.f ? a : 0.01f * a;
        }
        *(float4*)(out + ((long)b * 32 + oBase + o) * NP + y * WWW + x0) =
            make_float4(v[0], v[1], v[2], v[3]);
    }
}

// head conv2: 3x3, 32->1, + inp, sigmoid. grid (256, nb)
__global__ __launch_bounds__(256) void head_conv2(
    const float* __restrict__ x, const float* __restrict__ w,
    const float* __restrict__ inp, float* __restrict__ out)
{
    int xx0 = threadIdx.x, y = blockIdx.x, b = blockIdx.y;
    __shared__ float wl[288];
    for (int idx = threadIdx.x; idx < 288; idx += 256) wl[idx] = w[idx];
    __syncthreads();
    float acc = 0.f;
    for (int c = 0; c < 32; ++c) {
        const float* src = x + ((long)b * 32 + c) * NP;
#pragma unroll
        for (int ky = 0; ky < 3; ++ky) {
            int yy = y + ky - 1;
            if (yy < 0 || yy >= HHH) continue;
#pragma unroll
            for (int kx = 0; kx < 3; ++kx) {
                int xx = xx0 + kx - 1;
                if (xx < 0 || xx >= WWW) continue;
                acc += wl[c * 9 + ky * 3 + kx] * src[yy * WWW + xx];
            }
        }
    }
    float v = acc + inp[(long)b * NP + y * WWW + xx0];
    out[(long)b * NP + y * WWW + xx0] = 1.f / (1.f + expf(-v));
}

// ---------------------------------------------------------------------------
extern "C" void kernel_launch(void* const* d_in, const int* in_sizes, int n_in,
                              void* d_out, int out_size, void* d_ws, size_t ws_size,
                              hipStream_t stream)
{
    const float* inp    = (const float*)d_in[0];
    const float* base   = (const float*)d_in[1];
    const float* detail = (const float*)d_in[2];
    const float* w_ir   = (const float*)d_in[3];
    const float* w_vi   = (const float*)d_in[4];
    const float* w_fu   = (const float*)d_in[5];
    const float* b_fu   = (const float*)d_in[6];
    const float* w_dwc  = (const float*)d_in[7];
    const float* b_dwc  = (const float*)d_in[8];
    const float* eca_w  = (const float*)d_in[9];
    const float* w_rc2  = (const float*)d_in[10];
    const float* ln1w   = (const float*)d_in[11];
    const float* ln1b   = (const float*)d_in[12];
    const float* w_qkv  = (const float*)d_in[13];
    const float* w_qdw  = (const float*)d_in[14];
    const float* temp   = (const float*)d_in[15];
    const float* w_proj = (const float*)d_in[16];
    const float* ln2w   = (const float*)d_in[17];
    const float* ln2b   = (const float*)d_in[18];
    const float* w_in_  = (const float*)d_in[19];
    const float* w_fdw  = (const float*)d_in[20];
    const float* w_out_ = (const float*)d_in[21];
    const float* w_h1   = (const float*)d_in[22];
    const float* w_h2   = (const float*)d_in[23];

    float* out = (float*)d_out;

    auto needB = [&](long nb) -> size_t {
        return (size_t)nb * NP * (64 * 4 + 64 * 2 + 256 * 2 + 192 * 2) + (16u << 20);
    };
    int bInner;
    if (ws_size >= needB(4)) bInner = 4;
    else if (ws_size >= needB(1)) bInner = 1;
    else {
        diag_kernel<<<1, 64, 0, stream>>>(out, (float)(ws_size >> 20));
        return;
    }
    const long nb = bInner;

    char* p = (char*)d_ws;
    auto alloc = [&](size_t bytes) -> char* {
        char* r = p; p += (bytes + 255) & ~(size_t)255; return r;
    };
    float* X      = (float*)alloc((size_t)nb * 64 * NP * 4);
    u16*   XN     = (u16*)alloc((size_t)nb * 64 * NP * 2);
    u16*   Y      = (u16*)alloc((size_t)nb * 256 * NP * 2);
    u16*   Dq     = (u16*)alloc((size_t)nb * 192 * NP * 2);
    float* part   = (float*)alloc((size_t)nb * 8 * 80 * QKCH * 4);
    u16*   weffb  = (u16*)alloc((size_t)nb * 4096 * 2);
    u16*   rc2wb  = (u16*)alloc((size_t)nb * 8192 * 2);
    float* means  = (float*)alloc((size_t)nb * 256 * 4);
    float* ecam   = (float*)alloc((size_t)nb * 128 * 4);
    u16*   fq_bf  = (u16*)alloc((size_t)4 * 192 * 64 * 2);
    float* fqB    = (float*)alloc((size_t)4 * 192 * 4);
    u16*   ff_bf  = (u16*)alloc((size_t)4 * 256 * 64 * 2);
    float* ffB    = (float*)alloc((size_t)4 * 256 * 4);
    u16*   wir_bf = (u16*)alloc(8192 * 2);
    u16*   wvi_bf = (u16*)alloc(8192 * 2);
    u16*   wfu_bf = (u16*)alloc(32768 * 2);
    u16*   wout_bf= (u16*)alloc(32768 * 2);
    float* H32 = (float*)Y;

    dim3 blk(256);

    // one-time weight prep
    fold_ln<<<dim3(28), dim3(64), 0, stream>>>(w_qkv, ln1w, ln1b, w_in_, ln2w, ln2b,
                                               fq_bf, fqB, ff_bf, ffB);
    cvt_f2b<<<dim3(8), blk, 0, stream>>>(w_ir, wir_bf, 8192);
    cvt_f2b<<<dim3(8), blk, 0, stream>>>(w_vi, wvi_bf, 8192);
    cvt_f2b<<<dim3(32), blk, 0, stream>>>(w_fu, wfu_bf, 32768);
    cvt_f2b<<<dim3(32), blk, 0, stream>>>(w_out_, wout_bf, 32768);

    for (int b0 = 0; b0 < 4; b0 += bInner) {
        const float* inpB    = inp + (long)b0 * NP;
        const float* baseB   = base + (long)b0 * 64 * NP;
        const float* detailB = detail + (long)b0 * 64 * NP;
        float* out0  = out + (long)b0 * NP;
        float* outX0 = out + 262144 + (long)b0 * 64 * NP;
        long cvtN = nb * 64 * NP;

        // ---- CIIM ----
        cvt_f2b<<<dim3(cvtN / 1024), blk, 0, stream>>>(baseB, XN, cvtN);
        gemm_mfma<1, 0, 0, 0><<<dim3(2, 256, nb), blk, 0, stream>>>(
            XN, 64 * NP, wir_bf, 0, nullptr, nullptr, 0, Y, 256 * NP, nullptr, 0, 64);
        cvt_f2b<<<dim3(cvtN / 1024), blk, 0, stream>>>(detailB, Dq, cvtN);
        gemm_mfma<1, 0, 0, 0><<<dim3(2, 256, nb), blk, 0, stream>>>(
            Dq, 64 * NP, wvi_bf, 0, nullptr, nullptr, 0, Y + 128 * NP, 256 * NP, nullptr, 0, 64);
        chanreduce_bf<<<dim3(256, nb), blk, 0, stream>>>(Y, 256 * NP, means, 256, 1.f / NP);
        gemm_mfma<1, 0, 0, 1><<<dim3(2, 256, nb), blk, 0, stream>>>(
            Y, 256 * NP, wfu_bf, 0, b_fu, nullptr, 0, Dq, 192 * NP, nullptr, 0, 256);
        ciim_dw_strip<<<dim3(16, 64, nb), blk, 0, stream>>>(
            Dq, 192 * NP, means, w_dwc, b_dwc, XN, 64 * NP);
        outsh4<<<dim3(64, 128, nb), blk, 0, stream>>>(
            XN, 64 * NP, baseB, 64 * NP, detailB, Y, 256 * NP);
        chanreduce_bf<<<dim3(128, nb), blk, 0, stream>>>(Y, 256 * NP, ecam, 128, 1.f / NP);
        rc2w_build<<<dim3(nb * 32), blk, 0, stream>>>(ecam, eca_w, w_rc2, rc2wb);
        gemm_mfma<0, 0, 1, 0><<<dim3(1, 256, nb), blk, 0, stream>>>(
            Y, 256 * NP, rc2wb, 8192, nullptr, nullptr, 0, X, 64 * NP, outX0, 64 * NP, 128);

        // ---- transformer blocks ----
        for (int i = 0; i < 4; ++i) {
            ln_norm<<<dim3(256, nb), blk, 0, stream>>>(X, XN);
            gemm_mfma<1, 0, 0, 1><<<dim3(3, 256, nb), blk, 0, stream>>>(
                XN, 64 * NP, fq_bf + (long)i * 192 * 64, 0, fqB + i * 192,
                nullptr, 0, Y, 256 * NP, nullptr, 0, 64);
            dw3x3_strip<<<dim3(16, 192, nb), blk, 0, stream>>>(
                Y, 256 * NP, w_qdw + (long)i * 192 * 9, Dq, 192 * NP);
            qk_dot<<<dim3(QKCH, 8, nb), blk, 0, stream>>>(Dq, 192 * NP, part);
            attn_finalize<<<dim3(nb), dim3(64), 0, stream>>>(
                part, temp + i * 8, w_proj + (long)i * 4096, weffb);
            gemm_mfma<0, 1, 0, 0><<<dim3(1, 256, nb), blk, 0, stream>>>(
                Dq + 128 * NP, 192 * NP, weffb, 4096, nullptr, X, 64 * NP,
                X, 64 * NP, nullptr, 0, 64);
            ln_norm<<<dim3(256, nb), blk, 0, stream>>>(X, XN);
            gemm_mfma<1, 0, 0, 1><<<dim3(4, 256, nb), blk, 0, stream>>>(
                XN, 64 * NP, ff_bf + (long)i * 256 * 64, 0, ffB + i * 256,
                nullptr, 0, Y, 256 * NP, nullptr, 0, 64);
            ffn_dw_glu_strip<<<dim3(16, 128, nb), blk, 0, stream>>>(
                Y, 256 * NP, w_fdw + (long)i * 256 * 9, Dq, 192 * NP);
            gemm_mfma<0, 1, 0, 0><<<dim3(1, 256, nb), blk, 0, stream>>>(
                Dq, 192 * NP, wout_bf + (long)i * 8192, 0, nullptr, X, 64 * NP,
                X, 64 * NP, nullptr, 0, 128);
        }

        // ---- head ----
        head_conv1<<<dim3(64, 2, nb), blk, 0, stream>>>(X, w_h1, H32);
        head_conv2<<<dim3(256, nb), blk, 0, stream>>>(H32, w_h2, inpB, out0);
    }
}

// Round 7
// 3464.043 us; speedup vs baseline: 1.0029x; 1.0029x over previous
//
#include <hip/hip_runtime.h>
#include <hip/hip_bf16.h>
#include <math.h>

#define NP 65536L
#define HHH 256
#define WWW 256
#define QKCH 16

typedef unsigned short u16;
typedef unsigned short ushort8_t __attribute__((ext_vector_type(8)));
typedef short s16x8 __attribute__((ext_vector_type(8)));
typedef float f32x4 __attribute__((ext_vector_type(4)));

__device__ __forceinline__ float bf2f(u16 u) { return __uint_as_float(((unsigned)u) << 16); }
__device__ __forceinline__ u16 f2bf(float f) {
    __hip_bfloat16 h = __float2bfloat16(f);
    return *reinterpret_cast<u16*>(&h);
}
__device__ __forceinline__ float sigmoidf_(float x) { return 1.f / (1.f + __expf(-x)); }
__device__ __forceinline__ float gelu_exact(float x) {
    return 0.5f * x * (1.f + erff(x * 0.70710678118654752f));
}

__global__ void diag_kernel(float* out, float v) {
    if (threadIdx.x == 0 && blockIdx.x == 0) out[0] = v;
}

// fp32 -> bf16 bulk convert (n multiple of 4; grid = n/1024)
__global__ __launch_bounds__(256) void cvt_f2b(const float* __restrict__ src,
                                               u16* __restrict__ dst, long n)
{
    long i = ((long)blockIdx.x * 256 + threadIdx.x) * 4;
    if (i >= n) return;
    float4 v = *(const float4*)(src + i);
    ushort4 o;
    o.x = f2bf(v.x); o.y = f2bf(v.y); o.z = f2bf(v.z); o.w = f2bf(v.w);
    *(ushort4*)(dst + i) = o;
}

// ---------------------------------------------------------------------------
// MFMA bf16 GEMM for 1x1 conv: out[b][o][p] = sum_c w[o][c] * in[b][c][p]
// block: 256 thr = 4 waves; tile M=64 o x N=256 px; K chunks of 64.
// LDS: XT transposed [px][c] (pad 8) so B-frag = one ds_read_b128.
// grid (M/64, 256, nb)
// ---------------------------------------------------------------------------
template<int OUT_BF16, int RESID, int DUAL, int BIAS>
__global__ __launch_bounds__(256) void gemm_mfma(
    const u16* __restrict__ in, long inBS,
    const u16* __restrict__ wbf, long wBS,
    const float* __restrict__ bias,
    const float* __restrict__ resid, long resBS,
    void* __restrict__ outp, long outBS,
    float* __restrict__ out2, long out2BS,
    int Cin)
{
    __shared__ u16 XT[256][72];
    __shared__ u16 WT[64][72];
    int b = blockIdx.z;
    int oBase = blockIdx.x * 64;
    long P0 = (long)blockIdx.y * 256;
    int tid = threadIdx.x;
    int lane = tid & 63, wave = tid >> 6;
    const u16* inB = in + (long)b * inBS;
    const u16* wB = wbf + (long)b * wBS;

    f32x4 acc[4][4];
#pragma unroll
    for (int m = 0; m < 4; ++m)
#pragma unroll
        for (int n = 0; n < 4; ++n) acc[m][n] = (f32x4){0.f, 0.f, 0.f, 0.f};

    for (int ck = 0; ck < Cin; ck += 64) {
        if (ck) __syncthreads();
        {   // stage weights chunk [64 o][64 c]
            int o = tid >> 2, cs = (tid & 3) * 16;
            const u16* src = wB + (long)(oBase + o) * Cin + ck + cs;
            ushort8_t w0 = *(const ushort8_t*)src;
            ushort8_t w1 = *(const ushort8_t*)(src + 8);
            *(ushort8_t*)&WT[o][cs] = w0;
            *(ushort8_t*)&WT[o][cs + 8] = w1;
        }
        {   // stage X chunk transposed: [256 px][64 c]
            int c0 = (tid & 7) * 8;
            int pt = (tid >> 3) * 8;
            ushort8_t r[8];
#pragma unroll
            for (int i = 0; i < 8; ++i)
                r[i] = *(const ushort8_t*)(inB + (long)(ck + c0 + i) * NP + P0 + pt);
#pragma unroll
            for (int j = 0; j < 8; ++j) {
                ushort8_t v;
#pragma unroll
                for (int i = 0; i < 8; ++i) v[i] = r[i][j];
                *(ushort8_t*)&XT[pt + j][c0] = v;
            }
        }
        __syncthreads();
        int rl = lane & 15;
#pragma unroll
        for (int ks = 0; ks < 2; ++ks) {
            int kc = ks * 32 + (lane >> 4) * 8;
            s16x8 a[4], bb[4];
#pragma unroll
            for (int m = 0; m < 4; ++m)
                a[m] = *(const s16x8*)&WT[m * 16 + rl][kc];
#pragma unroll
            for (int n = 0; n < 4; ++n)
                bb[n] = *(const s16x8*)&XT[wave * 64 + n * 16 + rl][kc];
#pragma unroll
            for (int m = 0; m < 4; ++m)
#pragma unroll
                for (int n = 0; n < 4; ++n)
                    acc[m][n] = __builtin_amdgcn_mfma_f32_16x16x32_bf16(
                        a[m], bb[n], acc[m][n], 0, 0, 0);
        }
    }
    // epilogue: D col = lane&15 (pixel), row = (lane>>4)*4 + reg (o)
    int rl = lane & 15, rg = lane >> 4;
#pragma unroll
    for (int m = 0; m < 4; ++m) {
        int o0 = oBase + m * 16 + rg * 4;
#pragma unroll
        for (int n = 0; n < 4; ++n) {
            long px = P0 + wave * 64 + n * 16 + rl;
#pragma unroll
            for (int r = 0; r < 4; ++r) {
                int oo = o0 + r;
                float v = acc[m][n][r];
                if (BIAS) v += bias[oo];
                if (RESID) v += resid[(long)b * resBS + (long)oo * NP + px];
                if (OUT_BF16) ((u16*)outp)[(long)b * outBS + (long)oo * NP + px] = f2bf(v);
                else ((float*)outp)[(long)b * outBS + (long)oo * NP + px] = v;
                if (DUAL) out2[(long)b * out2BS + (long)oo * NP + px] = v;
            }
        }
    }
}

// LN standardize pre-pass: XN = (X - mu)/sqrt(var+eps), bf16. grid (256, nb)
__global__ __launch_bounds__(256) void ln_norm(
    const float* __restrict__ X, u16* __restrict__ XN)
{
    int b = blockIdx.y;
    long p = (long)blockIdx.x * 256 + threadIdx.x;
    const float* xb = X + (long)b * 64 * NP + p;
    float x[64];
    float s = 0.f, s2 = 0.f;
#pragma unroll
    for (int c = 0; c < 64; ++c) {
        x[c] = xb[(long)c * NP];
        s += x[c]; s2 = fmaf(x[c], x[c], s2);
    }
    float mu = s * (1.f / 64.f);
    float var = fmaxf(s2 * (1.f / 64.f) - mu * mu, 0.f);
    float inv = rsqrtf(var + 1e-5f);
    u16* xo = XN + (long)b * 64 * NP + p;
#pragma unroll
    for (int c = 0; c < 64; ++c) xo[(long)c * NP] = f2bf((x[c] - mu) * inv);
}

// fold LN gamma/beta into qkv / ffn-in weights; bf16 weights + fp32 bias.
__global__ void fold_ln(
    const float* __restrict__ wqkv, const float* __restrict__ ln1w, const float* __restrict__ ln1b,
    const float* __restrict__ win,  const float* __restrict__ ln2w, const float* __restrict__ ln2b,
    u16* __restrict__ fq, float* __restrict__ fqB,
    u16* __restrict__ ff, float* __restrict__ ffB)
{
    int g = blockIdx.x;
    int i = g / 7, r = g % 7;
    const float *wsrc, *lg, *lb;
    u16* wd; float* Bd;
    int obase;
    if (r < 3) {
        wsrc = wqkv + (long)i * 192 * 64; lg = ln1w + i * 64; lb = ln1b + i * 64;
        wd = fq + (long)i * 192 * 64; Bd = fqB + i * 192; obase = r * 64;
    } else {
        wsrc = win + (long)i * 256 * 64; lg = ln2w + i * 64; lb = ln2b + i * 64;
        wd = ff + (long)i * 256 * 64; Bd = ffB + i * 256; obase = (r - 3) * 64;
    }
    int o = obase + threadIdx.x;
    float Bv = 0.f;
    for (int c = 0; c < 64; ++c) {
        float wv = wsrc[(long)o * 64 + c];
        wd[(long)o * 64 + c] = f2bf(wv * lg[c]);
        Bv += wv * lb[c];
    }
    Bd[o] = Bv;
}

// per-(b,c) mean of bf16 buffer. grid (C, nb)
__global__ __launch_bounds__(256) void chanreduce_bf(
    const u16* __restrict__ in, long bs, float* __restrict__ out,
    int C, float scale)
{
    int c = blockIdx.x, b = blockIdx.y;
    const u16* p = in + (long)b * bs + (long)c * NP;
    float s = 0.f;
    for (long i = threadIdx.x * 4; i < NP; i += 1024) {
        ushort4 u = *(const ushort4*)(p + i);
        s += bf2f(u.x) + bf2f(u.y) + bf2f(u.z) + bf2f(u.w);
    }
    __shared__ float red[256];
    red[threadIdx.x] = s;
    __syncthreads();
    for (int st = 128; st > 0; st >>= 1) {
        if (threadIdx.x < st) red[threadIdx.x] += red[threadIdx.x + st];
        __syncthreads();
    }
    if (threadIdx.x == 0) out[b * C + c] = red[0] * scale;
}

// stage one LDS row (16 px) of a bf16 channel strip
__device__ __forceinline__ void stage_row(float (*S)[260], const u16* __restrict__ src,
                                          int y0, int j, int px)
{
    int row = y0 - 1 + j;
    if (row >= 0 && row < HHH) {
        ushort8_t a = *(const ushort8_t*)(src + row * WWW + px);
        ushort8_t b = *(const ushort8_t*)(src + row * WWW + px + 8);
#pragma unroll
        for (int e = 0; e < 8; ++e) { S[j][1 + px + e] = bf2f(a[e]); S[j][9 + px + e] = bf2f(b[e]); }
    } else {
#pragma unroll
        for (int e = 0; e < 16; ++e) S[j][1 + px + e] = 0.f;
    }
}
__device__ __forceinline__ float conv9(const float (*S)[260], int r, int col,
                                       const float* __restrict__ w9)
{
    float a = 0.f;
#pragma unroll
    for (int ky = 0; ky < 3; ++ky)
#pragma unroll
        for (int kx = 0; kx < 3; ++kx)
            a = fmaf(w9[ky * 3 + kx], S[r + ky][col + kx], a);
    return a;
}

// depthwise 3x3, 16-row strips. grid (16, C, nb)
__global__ __launch_bounds__(256) void dw3x3_strip(
    const u16* __restrict__ in, long inBS, const float* __restrict__ w,
    u16* __restrict__ out, long outBS)
{
    int strip = blockIdx.x, c = blockIdx.y, b = blockIdx.z;
    int y0 = strip * 16, tid = threadIdx.x;
    __shared__ float S[18][260];
    const u16* src = in + (long)b * inBS + (long)c * NP;
    int j = tid >> 4, px = (tid & 15) * 16;
    stage_row(S, src, y0, j, px);
    if (tid < 32) stage_row(S, src, y0, 16 + (tid >> 4), px);
    if (tid < 18) { S[tid][0] = 0.f; S[tid][257] = 0.f; }
    __syncthreads();
    float w9[9];
#pragma unroll
    for (int k = 0; k < 9; ++k) w9[k] = w[c * 9 + k];
    u16* dst = out + (long)b * outBS + (long)c * NP;
#pragma unroll
    for (int r = 0; r < 16; ++r)
        dst[(y0 + r) * WWW + tid] = f2bf(conv9(S, r, tid, w9));
}

// ffn: dw3x3 on (c, c+128) + gelu(y1)*y2, strips. grid (16, 128, nb)
__global__ __launch_bounds__(256) void ffn_dw_glu_strip(
    const u16* __restrict__ y, long yBS, const float* __restrict__ w,
    u16* __restrict__ g, long gBS)
{
    int strip = blockIdx.x, c = blockIdx.y, b = blockIdx.z;
    int y0 = strip * 16, tid = threadIdx.x;
    __shared__ float S1[18][260];
    __shared__ float S2[18][260];
    const u16* s1 = y + (long)b * yBS + (long)c * NP;
    const u16* s2 = y + (long)b * yBS + (long)(c + 128) * NP;
    int j = tid >> 4, px = (tid & 15) * 16;
    stage_row(S1, s1, y0, j, px);
    if (tid < 32) stage_row(S1, s1, y0, 16 + (tid >> 4), px);
    stage_row(S2, s2, y0, j, px);
    if (tid < 32) stage_row(S2, s2, y0, 16 + (tid >> 4), px);
    if (tid < 18) { S1[tid][0] = S1[tid][257] = 0.f; S2[tid][0] = S2[tid][257] = 0.f; }
    __syncthreads();
    float w1[9], w2[9];
#pragma unroll
    for (int k = 0; k < 9; ++k) { w1[k] = w[c * 9 + k]; w2[k] = w[(c + 128) * 9 + k]; }
    u16* dst = g + (long)b * gBS + (long)c * NP;
#pragma unroll
    for (int r = 0; r < 16; ++r) {
        float a1 = conv9(S1, r, tid, w1);
        float a2 = conv9(S2, r, tid, w2);
        dst[(y0 + r) * WWW + tid] = f2bf(gelu_exact(a1) * a2);
    }
}

// CIIM grouped dw conv, strips. grid (16, 64, nb)
__global__ __launch_bounds__(256) void ciim_dw_strip(
    const u16* __restrict__ fuse, long fBS, const float* __restrict__ means,
    const float* __restrict__ wdw, const float* __restrict__ bdw,
    u16* __restrict__ hl, long hlBS)
{
    int strip = blockIdx.x, c = blockIdx.y, b = blockIdx.z;
    int y0 = strip * 16, tid = threadIdx.x;
    __shared__ float S[18][260];
    float acc[16];
    float bias = bdw[c];
#pragma unroll
    for (int r = 0; r < 16; ++r) acc[r] = bias;
    for (int j6 = 0; j6 < 6; ++j6) {
        int ic = 6 * c + j6;
        const float* w9p = wdw + (c * 6 + j6) * 9;
        float w9[9];
#pragma unroll
        for (int k = 0; k < 9; ++k) w9[k] = w9p[k];
        if (ic < 128) {
            __syncthreads();
            const u16* src = fuse + (long)b * fBS + (long)ic * NP;
            int j = tid >> 4, px = (tid & 15) * 16;
            stage_row(S, src, y0, j, px);
            if (tid < 32) stage_row(S, src, y0, 16 + (tid >> 4), px);
            if (tid < 18) { S[tid][0] = 0.f; S[tid][257] = 0.f; }
            __syncthreads();
#pragma unroll
            for (int r = 0; r < 16; ++r) acc[r] += conv9(S, r, tid, w9);
        } else {
            float mv = means[b * 256 + ic - 128];
#pragma unroll
            for (int r = 0; r < 16; ++r) {
                int row = y0 + r;
                float ws = 0.f;
#pragma unroll
                for (int ky = 0; ky < 3; ++ky) {
                    int yy = row + ky - 1;
                    if (yy < 0 || yy >= HHH) continue;
#pragma unroll
                    for (int kx = 0; kx < 3; ++kx) {
                        int xx = tid + kx - 1;
                        if (xx < 0 || xx >= WWW) continue;
                        ws += w9[ky * 3 + kx];
                    }
                }
                acc[r] += mv * ws;
            }
        }
    }
    u16* dst = hl + (long)b * hlBS + (long)c * NP;
#pragma unroll
    for (int r = 0; r < 16; ++r) dst[(y0 + r) * WWW + tid] = f2bf(acc[r]);
}

// gating + concat + channel shuffle. grid (64, 128, nb)
__global__ __launch_bounds__(256) void outsh4(
    const u16* __restrict__ hl, long hlBS,
    const float* __restrict__ low, long lBS,
    const float* __restrict__ high,
    u16* __restrict__ outb, long oBS)
{
    long p = ((long)blockIdx.x * 256 + threadIdx.x) * 4;
    int cn = blockIdx.y, b = blockIdx.z;
    int co = (cn & 31) * 4 + (cn >> 5);
    const u16* hp;
    const float* sp;
    if (co < 64) {
        hp = hl + (long)b * hlBS + (long)co * NP + p;
        sp = low + (long)b * lBS + (long)co * NP + p;
    } else {
        hp = hl + (long)b * hlBS + (long)(co - 64) * NP + p;
        sp = high + (long)b * lBS + (long)(co - 64) * NP + p;
    }
    ushort4 hu = *(const ushort4*)hp;
    float4 sv = *(const float4*)sp;
    float hv[4] = {bf2f(hu.x), bf2f(hu.y), bf2f(hu.z), bf2f(hu.w)};
    float s4[4] = {sv.x, sv.y, sv.z, sv.w};
    ushort4 ovec;
    u16* ov = (u16*)&ovec;
#pragma unroll
    for (int k = 0; k < 4; ++k) {
        float gg = (co < 64) ? sigmoidf_(gelu_exact(hv[k])) : sigmoidf_(fmaxf(hv[k], 0.f));
        ov[k] = f2bf(gg * s4[k]);
    }
    *(ushort4*)((u16*)outb + (long)b * oBS + (long)cn * NP + p) = ovec;
}

// scaled rc2 weights (bf16). grid (nb*32)
__global__ __launch_bounds__(256) void rc2w_build(
    const float* __restrict__ ecam, const float* __restrict__ ecaw,
    const float* __restrict__ wrc2, u16* __restrict__ wout)
{
    int idx = blockIdx.x * 256 + threadIdx.x;
    int c = idx & 127, o = (idx >> 7) & 63, b = idx >> 13;
    float y = sigmoidf_(ecam[b * 128 + c] * ecaw[c]);
    wout[idx] = f2bf(wrc2[o * 128 + c] * y);
}

// q.k dots + sumsq norms over pixel chunks. grid (QKCH, 8, nb)
__global__ __launch_bounds__(256) void qk_dot(
    const u16* __restrict__ D, long dBS, float* __restrict__ part)
{
    int chunk = blockIdx.x, h = blockIdx.y, b = blockIdx.z;
    int tid = threadIdx.x, lane = tid & 63, wave = tid >> 6;
    const u16* q = D + (long)b * dBS + (long)(h * 8) * NP;
    const u16* k = q + 64 * NP;
    float dots[64], nq[8], nk[8];
#pragma unroll
    for (int a = 0; a < 64; ++a) dots[a] = 0.f;
#pragma unroll
    for (int a = 0; a < 8; ++a) { nq[a] = 0.f; nk[a] = 0.f; }
    long base = (long)chunk * 4096 + tid * 8;
    for (int pass = 0; pass < 2; ++pass) {
        long p = base + pass * 2048;
        ushort8_t qv[8], kv[8];
#pragma unroll
        for (int i = 0; i < 8; ++i) qv[i] = *(const ushort8_t*)(q + (long)i * NP + p);
#pragma unroll
        for (int i = 0; i < 8; ++i) kv[i] = *(const ushort8_t*)(k + (long)i * NP + p);
#pragma unroll
        for (int e = 0; e < 8; ++e) {
            float qe[8], ke[8];
#pragma unroll
            for (int i = 0; i < 8; ++i) { qe[i] = bf2f(qv[i][e]); ke[i] = bf2f(kv[i][e]); }
#pragma unroll
            for (int i = 0; i < 8; ++i) {
                nq[i] = fmaf(qe[i], qe[i], nq[i]);
                nk[i] = fmaf(ke[i], ke[i], nk[i]);
#pragma unroll
                for (int jj = 0; jj < 8; ++jj)
                    dots[i * 8 + jj] = fmaf(qe[i], ke[jj], dots[i * 8 + jj]);
            }
        }
    }
    __shared__ float red[4][80];
#pragma unroll
    for (int a = 0; a < 64; ++a) {
        float v = dots[a];
#pragma unroll
        for (int o = 32; o > 0; o >>= 1) v += __shfl_xor(v, o);
        if (lane == 0) red[wave][a] = v;
    }
#pragma unroll
    for (int a = 0; a < 8; ++a) {
        float v1 = nq[a], v2 = nk[a];
#pragma unroll
        for (int o = 32; o > 0; o >>= 1) { v1 += __shfl_xor(v1, o); v2 += __shfl_xor(v2, o); }
        if (lane == 0) { red[wave][64 + a] = v1; red[wave][72 + a] = v2; }
    }
    __syncthreads();
    if (tid < 80) {
        float v = red[0][tid] + red[1][tid] + red[2][tid] + red[3][tid];
        part[(((long)b * 8 + h) * 80 + tid) * QKCH + chunk] = v;
    }
}

// reduce partials + softmax + Weff (bf16). grid (nb), block 64
__global__ void attn_finalize(
    const float* __restrict__ part, const float* __restrict__ temp,
    const float* __restrict__ wproj, u16* __restrict__ weffb)
{
    int b = blockIdx.x, t = threadIdx.x;
    __shared__ float Sg[8][80];
    __shared__ float att[8][8][8];
    for (int h = 0; h < 8; ++h)
        for (int e = t; e < 80; e += 64) {
            const float* pp = part + (((long)b * 8 + h) * 80 + e) * QKCH;
            float s = 0.f;
#pragma unroll
            for (int c = 0; c < QKCH; ++c) s += pp[c];
            Sg[h][e] = s;
        }
    __syncthreads();
    {
        int h = t >> 3, iq = t & 7;
        float nqv = fmaxf(sqrtf(Sg[h][64 + iq]), 1e-12f);
        float tp = temp[h];
        float row[8], mx = -1e30f;
#pragma unroll
        for (int jj = 0; jj < 8; ++jj) {
            float nkv = fmaxf(sqrtf(Sg[h][72 + jj]), 1e-12f);
            row[jj] = Sg[h][iq * 8 + jj] / (nqv * nkv) * tp;
            mx = fmaxf(mx, row[jj]);
        }
        float sum = 0.f;
#pragma unroll
        for (int jj = 0; jj < 8; ++jj) { row[jj] = __expf(row[jj] - mx); sum += row[jj]; }
        float rinv = 1.f / sum;
#pragma unroll
        for (int jj = 0; jj < 8; ++jj) att[h][iq][jj] = row[jj] * rinv;
    }
    __syncthreads();
    for (int cv = 0; cv < 64; ++cv) {
        int h = cv >> 3, jj = cv & 7;
        float s = 0.f;
#pragma unroll
        for (int i = 0; i < 8; ++i) s = fmaf(wproj[t * 64 + h * 8 + i], att[h][i][jj], s);
        weffb[((long)b * 64 + t) * 64 + cv] = f2bf(s);
    }
}

// head conv1: 3x3, 64->32, leaky. grid (64, 2, nb)
__global__ __launch_bounds__(256) void head_conv1(
    const float* __restrict__ x, const float* __restrict__ w,
    float* __restrict__ out)
{
    int b = blockIdx.z;
    int oBase = blockIdx.y * 16;
    int r = threadIdx.x >> 6;
    int lx = threadIdx.x & 63;
    int y = blockIdx.x * 4 + r;
    int x0 = lx * 4;
    __shared__ float wl[64][9][16];
    for (int idx = threadIdx.x; idx < 64 * 9 * 16; idx += 256) {
        int o = idx & 15, tap = (idx >> 4) % 9, c = idx / 144;
        wl[c][tap][o] = w[((long)(oBase + o) * 64 + c) * 9 + tap];
    }
    __syncthreads();
    float acc[16][4];
#pragma unroll
    for (int o = 0; o < 16; ++o)
#pragma unroll
        for (int px = 0; px < 4; ++px) acc[o][px] = 0.f;
    for (int c = 0; c < 64; ++c) {
        const float* src = x + ((long)b * 64 + c) * NP;
        float row[3][6];
#pragma unroll
        for (int ky = 0; ky < 3; ++ky) {
            int yy = y + ky - 1;
            bool yok = (yy >= 0 && yy < HHH);
#pragma unroll
            for (int dx = 0; dx < 6; ++dx) {
                int xx = x0 + dx - 1;
                row[ky][dx] = (yok && xx >= 0 && xx < WWW) ? src[yy * WWW + xx] : 0.f;
            }
        }
#pragma unroll
        for (int ky = 0; ky < 3; ++ky)
#pragma unroll
            for (int kx = 0; kx < 3; ++kx) {
                int tap = ky * 3 + kx;
#pragma unroll
                for (int px = 0; px < 4; ++px) {
                    float xv = row[ky][kx + px];
#pragma unroll
                    for (int o = 0; o < 16; ++o)
                        acc[o][px] = fmaf(wl[c][tap][o], xv, acc[o][px]);
                }
            }
    }
#pragma unroll
    for (int o = 0; o < 16; ++o) {
        float v[4];
#pragma unroll
        for (int px = 0; px < 4; ++px) {
            float a = acc[o][px];
            v[px] = a > 0.f ? a : 0.01f * a;
        }
        *(float4*)(out + ((long)b * 32 + oBase + o) * NP + y * WWW + x0) =
            make_float4(v[0], v[1], v[2], v[3]);
    }
}

// head conv2: 3x3, 32->1, + inp, sigmoid. grid (256, nb)
__global__ __launch_bounds__(256) void head_conv2(
    const float* __restrict__ x, const float* __restrict__ w,
    const float* __restrict__ inp, float* __restrict__ out)
{
    int xx0 = threadIdx.x, y = blockIdx.x, b = blockIdx.y;
    __shared__ float wl[288];
    for (int idx = threadIdx.x; idx < 288; idx += 256) wl[idx] = w[idx];
    __syncthreads();
    float acc = 0.f;
    for (int c = 0; c < 32; ++c) {
        const float* src = x + ((long)b * 32 + c) * NP;
#pragma unroll
        for (int ky = 0; ky < 3; ++ky) {
            int yy = y + ky - 1;
            if (yy < 0 || yy >= HHH) continue;
#pragma unroll
            for (int kx = 0; kx < 3; ++kx) {
                int xx = xx0 + kx - 1;
                if (xx < 0 || xx >= WWW) continue;
                acc += wl[c * 9 + ky * 3 + kx] * src[yy * WWW + xx];
            }
        }
    }
    float v = acc + inp[(long)b * NP + y * WWW + xx0];
    out[(long)b * NP + y * WWW + xx0] = 1.f / (1.f + expf(-v));
}

// ---------------------------------------------------------------------------
extern "C" void kernel_launch(void* const* d_in, const int* in_sizes, int n_in,
                              void* d_out, int out_size, void* d_ws, size_t ws_size,
                              hipStream_t stream)
{
    const float* inp    = (const float*)d_in[0];
    const float* base   = (const float*)d_in[1];
    const float* detail = (const float*)d_in[2];
    const float* w_ir   = (const float*)d_in[3];
    const float* w_vi   = (const float*)d_in[4];
    const float* w_fu   = (const float*)d_in[5];
    const float* b_fu   = (const float*)d_in[6];
    const float* w_dwc  = (const float*)d_in[7];
    const float* b_dwc  = (const float*)d_in[8];
    const float* eca_w  = (const float*)d_in[9];
    const float* w_rc2  = (const float*)d_in[10];
    const float* ln1w   = (const float*)d_in[11];
    const float* ln1b   = (const float*)d_in[12];
    const float* w_qkv  = (const float*)d_in[13];
    const float* w_qdw  = (const float*)d_in[14];
    const float* temp   = (const float*)d_in[15];
    const float* w_proj = (const float*)d_in[16];
    const float* ln2w   = (const float*)d_in[17];
    const float* ln2b   = (const float*)d_in[18];
    const float* w_in_  = (const float*)d_in[19];
    const float* w_fdw  = (const float*)d_in[20];
    const float* w_out_ = (const float*)d_in[21];
    const float* w_h1   = (const float*)d_in[22];
    const float* w_h2   = (const float*)d_in[23];

    float* out = (float*)d_out;

    auto needB = [&](long nb) -> size_t {
        return (size_t)nb * NP * (64 * 4 + 64 * 2 + 256 * 2 + 192 * 2) + (16u << 20);
    };
    int bInner;
    if (ws_size >= needB(4)) bInner = 4;
    else if (ws_size >= needB(1)) bInner = 1;
    else {
        diag_kernel<<<1, 64, 0, stream>>>(out, (float)(ws_size >> 20));
        return;
    }
    const long nb = bInner;

    char* p = (char*)d_ws;
    auto alloc = [&](size_t bytes) -> char* {
        char* r = p; p += (bytes + 255) & ~(size_t)255; return r;
    };
    float* X      = (float*)alloc((size_t)nb * 64 * NP * 4);
    u16*   XN     = (u16*)alloc((size_t)nb * 64 * NP * 2);
    u16*   Y      = (u16*)alloc((size_t)nb * 256 * NP * 2);
    u16*   Dq     = (u16*)alloc((size_t)nb * 192 * NP * 2);
    float* part   = (float*)alloc((size_t)nb * 8 * 80 * QKCH * 4);
    u16*   weffb  = (u16*)alloc((size_t)nb * 4096 * 2);
    u16*   rc2wb  = (u16*)alloc((size_t)nb * 8192 * 2);
    float* means  = (float*)alloc((size_t)nb * 256 * 4);
    float* ecam   = (float*)alloc((size_t)nb * 128 * 4);
    u16*   fq_bf  = (u16*)alloc((size_t)4 * 192 * 64 * 2);
    float* fqB    = (float*)alloc((size_t)4 * 192 * 4);
    u16*   ff_bf  = (u16*)alloc((size_t)4 * 256 * 64 * 2);
    float* ffB    = (float*)alloc((size_t)4 * 256 * 4);
    u16*   wir_bf = (u16*)alloc(8192 * 2);
    u16*   wvi_bf = (u16*)alloc(8192 * 2);
    u16*   wfu_bf = (u16*)alloc(32768 * 2);
    u16*   wout_bf= (u16*)alloc(32768 * 2);
    float* H32 = (float*)Y;

    dim3 blk(256);

    // one-time weight prep
    fold_ln<<<dim3(28), dim3(64), 0, stream>>>(w_qkv, ln1w, ln1b, w_in_, ln2w, ln2b,
                                               fq_bf, fqB, ff_bf, ffB);
    cvt_f2b<<<dim3(8), blk, 0, stream>>>(w_ir, wir_bf, 8192);
    cvt_f2b<<<dim3(8), blk, 0, stream>>>(w_vi, wvi_bf, 8192);
    cvt_f2b<<<dim3(32), blk, 0, stream>>>(w_fu, wfu_bf, 32768);
    cvt_f2b<<<dim3(32), blk, 0, stream>>>(w_out_, wout_bf, 32768);

    for (int b0 = 0; b0 < 4; b0 += bInner) {
        const float* inpB    = inp + (long)b0 * NP;
        const float* baseB   = base + (long)b0 * 64 * NP;
        const float* detailB = detail + (long)b0 * 64 * NP;
        float* out0  = out + (long)b0 * NP;
        float* outX0 = out + 262144 + (long)b0 * 64 * NP;
        long cvtN = nb * 64 * NP;

        // ---- CIIM ----
        cvt_f2b<<<dim3(cvtN / 1024), blk, 0, stream>>>(baseB, XN, cvtN);
        gemm_mfma<1, 0, 0, 0><<<dim3(2, 256, nb), blk, 0, stream>>>(
            XN, 64 * NP, wir_bf, 0, nullptr, nullptr, 0, Y, 256 * NP, nullptr, 0, 64);
        cvt_f2b<<<dim3(cvtN / 1024), blk, 0, stream>>>(detailB, Dq, cvtN);
        gemm_mfma<1, 0, 0, 0><<<dim3(2, 256, nb), blk, 0, stream>>>(
            Dq, 64 * NP, wvi_bf, 0, nullptr, nullptr, 0, Y + 128 * NP, 256 * NP, nullptr, 0, 64);
        chanreduce_bf<<<dim3(256, nb), blk, 0, stream>>>(Y, 256 * NP, means, 256, 1.f / NP);
        gemm_mfma<1, 0, 0, 1><<<dim3(2, 256, nb), blk, 0, stream>>>(
            Y, 256 * NP, wfu_bf, 0, b_fu, nullptr, 0, Dq, 192 * NP, nullptr, 0, 256);
        ciim_dw_strip<<<dim3(16, 64, nb), blk, 0, stream>>>(
            Dq, 192 * NP, means, w_dwc, b_dwc, XN, 64 * NP);
        outsh4<<<dim3(64, 128, nb), blk, 0, stream>>>(
            XN, 64 * NP, baseB, 64 * NP, detailB, Y, 256 * NP);
        chanreduce_bf<<<dim3(128, nb), blk, 0, stream>>>(Y, 256 * NP, ecam, 128, 1.f / NP);
        rc2w_build<<<dim3(nb * 32), blk, 0, stream>>>(ecam, eca_w, w_rc2, rc2wb);
        gemm_mfma<0, 0, 1, 0><<<dim3(1, 256, nb), blk, 0, stream>>>(
            Y, 256 * NP, rc2wb, 8192, nullptr, nullptr, 0, X, 64 * NP, outX0, 64 * NP, 128);

        // ---- transformer blocks ----
        for (int i = 0; i < 4; ++i) {
            ln_norm<<<dim3(256, nb), blk, 0, stream>>>(X, XN);
            gemm_mfma<1, 0, 0, 1><<<dim3(3, 256, nb), blk, 0, stream>>>(
                XN, 64 * NP, fq_bf + (long)i * 192 * 64, 0, fqB + i * 192,
                nullptr, 0, Y, 256 * NP, nullptr, 0, 64);
            dw3x3_strip<<<dim3(16, 192, nb), blk, 0, stream>>>(
                Y, 256 * NP, w_qdw + (long)i * 192 * 9, Dq, 192 * NP);
            qk_dot<<<dim3(QKCH, 8, nb), blk, 0, stream>>>(Dq, 192 * NP, part);
            attn_finalize<<<dim3(nb), dim3(64), 0, stream>>>(
                part, temp + i * 8, w_proj + (long)i * 4096, weffb);
            gemm_mfma<0, 1, 0, 0><<<dim3(1, 256, nb), blk, 0, stream>>>(
                Dq + 128 * NP, 192 * NP, weffb, 4096, nullptr, X, 64 * NP,
                X, 64 * NP, nullptr, 0, 64);
            ln_norm<<<dim3(256, nb), blk, 0, stream>>>(X, XN);
            gemm_mfma<1, 0, 0, 1><<<dim3(4, 256, nb), blk, 0, stream>>>(
                XN, 64 * NP, ff_bf + (long)i * 256 * 64, 0, ffB + i * 256,
                nullptr, 0, Y, 256 * NP, nullptr, 0, 64);
            ffn_dw_glu_strip<<<dim3(16, 128, nb), blk, 0, stream>>>(
                Y, 256 * NP, w_fdw + (long)i * 256 * 9, Dq, 192 * NP);
            gemm_mfma<0, 1, 0, 0><<<dim3(1, 256, nb), blk, 0, stream>>>(
                Dq, 192 * NP, wout_bf + (long)i * 8192, 0, nullptr, X, 64 * NP,
                X, 64 * NP, nullptr, 0, 128);
        }

        // ---- head ----
        head_conv1<<<dim3(64, 2, nb), blk, 0, stream>>>(X, w_h1, H32);
        head_conv2<<<dim3(256, nb), blk, 0, stream>>>(H32, w_h2, inpB, out0);
    }
}

// Round 8
// 2838.496 us; speedup vs baseline: 1.2239x; 1.2204x over previous
//
#include <hip/hip_runtime.h>
#include <hip/hip_bf16.h>
#include <math.h>

#define NP 65536L
#define HHH 256
#define WWW 256
#define QKCH 16

typedef unsigned short u16;
typedef unsigned short ushort8_t __attribute__((ext_vector_type(8)));
typedef short s16x8 __attribute__((ext_vector_type(8)));
typedef float f32x4 __attribute__((ext_vector_type(4)));

__device__ __forceinline__ float bf2f(u16 u) { return __uint_as_float(((unsigned)u) << 16); }
__device__ __forceinline__ u16 f2bf(float f) {
    __hip_bfloat16 h = __float2bfloat16(f);
    return *reinterpret_cast<u16*>(&h);
}
__device__ __forceinline__ float sigmoidf_(float x) { return 1.f / (1.f + __expf(-x)); }
__device__ __forceinline__ float gelu_exact(float x) {
    return 0.5f * x * (1.f + erff(x * 0.70710678118654752f));
}

__global__ void diag_kernel(float* out, float v) {
    if (threadIdx.x == 0 && blockIdx.x == 0) out[0] = v;
}

// fp32 -> bf16 bulk convert (weights only)
__global__ __launch_bounds__(256) void cvt_f2b(const float* __restrict__ src,
                                               u16* __restrict__ dst, long n)
{
    long i = ((long)blockIdx.x * 256 + threadIdx.x) * 4;
    if (i >= n) return;
    float4 v = *(const float4*)(src + i);
    ushort4 o;
    o.x = f2bf(v.x); o.y = f2bf(v.y); o.z = f2bf(v.z); o.w = f2bf(v.w);
    *(ushort4*)(dst + i) = o;
}

// rearrange w_h1 [32][64][9] -> wtap bf16 [9][32][64]. grid (9)
__global__ __launch_bounds__(256) void prep_wtap(const float* __restrict__ wh1,
                                                 u16* __restrict__ wtap)
{
    int tap = blockIdx.x;
    for (int e = threadIdx.x; e < 2048; e += 256) {
        wtap[tap * 2048 + e] = f2bf(wh1[(long)e * 9 + tap]);
    }
}

// ---------------------------------------------------------------------------
// MFMA bf16 GEMM for 1x1 conv + fused extras.
// tile M=64 o x N=256 px, K chunks of 64. grid (Cout/64, 256, nb).
// INF32: stage fp32 input (convert during transpose). LNOUT: write per-pixel
// standardized bf16 copy to xn (requires Cout==64, grid.x==1). WEFF: build
// the 64x64 attention-effective weight in the prologue from part/temp/wproj.
// ---------------------------------------------------------------------------
template<int INF32, int OUT_BF16, int RESID, int DUAL, int BIAS, int LNOUT, int WEFF>
__global__ __launch_bounds__(256) void gemm_mfma(
    const void* __restrict__ inp, long inBS,
    const u16* __restrict__ wbf, long wBS,
    const float* __restrict__ bias,
    const float* __restrict__ resid, long resBS,
    void* __restrict__ outp, long outBS,
    float* __restrict__ out2, long out2BS,
    u16* __restrict__ xn,
    const float* __restrict__ part, const float* __restrict__ temp,
    const float* __restrict__ wproj,
    int Cin)
{
    __shared__ u16 XT[256][72];
    __shared__ u16 WT[64][72];
    int b = blockIdx.z;
    int oBase = blockIdx.x * 64;
    long P0 = (long)blockIdx.y * 256;
    int tid = threadIdx.x;
    int lane = tid & 63, wave = tid >> 6;
    int rl = lane & 15, rg = lane >> 4;

    if (WEFF) {
        // reduce part chunks -> Sg[8][80]; softmax -> att; weff -> WT
        float* SgF = (float*)&XT[0][0];
        float* attF = SgF + 640;
        for (int e = tid; e < 640; e += 256) {
            int h = e / 80, k = e % 80;
            const float* pp = part + (((long)b * 8 + h) * 80 + k) * QKCH;
            float s = 0.f;
#pragma unroll
            for (int c = 0; c < QKCH; ++c) s += pp[c];
            SgF[e] = s;
        }
        __syncthreads();
        if (tid < 64) {
            int h = tid >> 3, iq = tid & 7;
            float nqv = fmaxf(sqrtf(SgF[h * 80 + 64 + iq]), 1e-12f);
            float tp = temp[h];
            float row[8], mx = -1e30f;
#pragma unroll
            for (int jj = 0; jj < 8; ++jj) {
                float nkv = fmaxf(sqrtf(SgF[h * 80 + 72 + jj]), 1e-12f);
                row[jj] = SgF[h * 80 + iq * 8 + jj] / (nqv * nkv) * tp;
                mx = fmaxf(mx, row[jj]);
            }
            float sum = 0.f;
#pragma unroll
            for (int jj = 0; jj < 8; ++jj) { row[jj] = __expf(row[jj] - mx); sum += row[jj]; }
            float rinv = 1.f / sum;
#pragma unroll
            for (int jj = 0; jj < 8; ++jj) attF[(h * 8 + iq) * 8 + jj] = row[jj] * rinv;
        }
        __syncthreads();
        {
            int o = tid >> 2;
            int cv0 = (tid & 3) * 16;
#pragma unroll
            for (int cv = 0; cv < 16; ++cv) {
                int c = cv0 + cv;
                int h = c >> 3, jj = c & 7;
                float s = 0.f;
#pragma unroll
                for (int i = 0; i < 8; ++i)
                    s = fmaf(wproj[o * 64 + h * 8 + i], attF[(h * 8 + i) * 8 + jj], s);
                WT[o][c] = f2bf(s);
            }
        }
        __syncthreads();
    }

    f32x4 acc[4][4];
#pragma unroll
    for (int m = 0; m < 4; ++m)
#pragma unroll
        for (int n = 0; n < 4; ++n) acc[m][n] = (f32x4){0.f, 0.f, 0.f, 0.f};

    for (int ck = 0; ck < Cin; ck += 64) {
        if (ck) __syncthreads();
        if (!WEFF) {   // stage weights chunk [64 o][64 c]
            int o = tid >> 2, cs = (tid & 3) * 16;
            const u16* src = wbf + (long)b * wBS + (long)(oBase + o) * Cin + ck + cs;
            *(ushort8_t*)&WT[o][cs] = *(const ushort8_t*)src;
            *(ushort8_t*)&WT[o][cs + 8] = *(const ushort8_t*)(src + 8);
        }
        {   // stage X chunk transposed: [256 px][64 c]
            int c0 = (tid & 7) * 8;
            int pt = (tid >> 3) * 8;
            if (INF32) {
                const float* inF = (const float*)inp + (long)b * inBS;
                u16 rr[8][8];
#pragma unroll
                for (int i = 0; i < 8; ++i) {
                    const float* sp = inF + (long)(ck + c0 + i) * NP + P0 + pt;
                    float4 a = *(const float4*)sp;
                    float4 b4 = *(const float4*)(sp + 4);
                    rr[i][0] = f2bf(a.x); rr[i][1] = f2bf(a.y);
                    rr[i][2] = f2bf(a.z); rr[i][3] = f2bf(a.w);
                    rr[i][4] = f2bf(b4.x); rr[i][5] = f2bf(b4.y);
                    rr[i][6] = f2bf(b4.z); rr[i][7] = f2bf(b4.w);
                }
#pragma unroll
                for (int j = 0; j < 8; ++j) {
                    ushort8_t v;
#pragma unroll
                    for (int i = 0; i < 8; ++i) v[i] = rr[i][j];
                    *(ushort8_t*)&XT[pt + j][c0] = v;
                }
            } else {
                const u16* inB = (const u16*)inp + (long)b * inBS;
                ushort8_t r[8];
#pragma unroll
                for (int i = 0; i < 8; ++i)
                    r[i] = *(const ushort8_t*)(inB + (long)(ck + c0 + i) * NP + P0 + pt);
#pragma unroll
                for (int j = 0; j < 8; ++j) {
                    ushort8_t v;
#pragma unroll
                    for (int i = 0; i < 8; ++i) v[i] = r[i][j];
                    *(ushort8_t*)&XT[pt + j][c0] = v;
                }
            }
        }
        __syncthreads();
#pragma unroll
        for (int ks = 0; ks < 2; ++ks) {
            int kc = ks * 32 + rg * 8;
            s16x8 a[4], bb[4];
#pragma unroll
            for (int m = 0; m < 4; ++m)
                a[m] = *(const s16x8*)&WT[m * 16 + rl][kc];
#pragma unroll
            for (int n = 0; n < 4; ++n)
                bb[n] = *(const s16x8*)&XT[wave * 64 + n * 16 + rl][kc];
#pragma unroll
            for (int m = 0; m < 4; ++m)
#pragma unroll
                for (int n = 0; n < 4; ++n)
                    acc[m][n] = __builtin_amdgcn_mfma_f32_16x16x32_bf16(
                        a[m], bb[n], acc[m][n], 0, 0, 0);
        }
    }

    // ---- epilogue: bias + resid, optional fused LN, stores ----
    float bv[4][4];
    if (BIAS) {
#pragma unroll
        for (int m = 0; m < 4; ++m)
#pragma unroll
            for (int r = 0; r < 4; ++r) bv[m][r] = bias[oBase + m * 16 + rg * 4 + r];
    }
#pragma unroll
    for (int m = 0; m < 4; ++m)
#pragma unroll
        for (int n = 0; n < 4; ++n)
#pragma unroll
            for (int r = 0; r < 4; ++r) {
                float t = acc[m][n][r];
                if (BIAS) t += bv[m][r];
                if (RESID) {
                    int oo = oBase + m * 16 + rg * 4 + r;
                    long px = P0 + wave * 64 + n * 16 + rl;
                    t += resid[(long)b * resBS + (long)oo * NP + px];
                }
                acc[m][n][r] = t;
            }
    float muA[4], invA[4];
    if (LNOUT) {
#pragma unroll
        for (int n = 0; n < 4; ++n) {
            float s = 0.f, s2 = 0.f;
#pragma unroll
            for (int m = 0; m < 4; ++m)
#pragma unroll
                for (int r = 0; r < 4; ++r) {
                    float t = acc[m][n][r];
                    s += t; s2 = fmaf(t, t, s2);
                }
            s += __shfl_xor(s, 16);  s += __shfl_xor(s, 32);
            s2 += __shfl_xor(s2, 16); s2 += __shfl_xor(s2, 32);
            float mu = s * (1.f / 64.f);
            float var = fmaxf(s2 * (1.f / 64.f) - mu * mu, 0.f);
            muA[n] = mu;
            invA[n] = rsqrtf(var + 1e-5f);
        }
    }
#pragma unroll
    for (int m = 0; m < 4; ++m)
#pragma unroll
        for (int n = 0; n < 4; ++n) {
            long px = P0 + wave * 64 + n * 16 + rl;
#pragma unroll
            for (int r = 0; r < 4; ++r) {
                int oo = oBase + m * 16 + rg * 4 + r;
                float v = acc[m][n][r];
                if (OUT_BF16) ((u16*)outp)[(long)b * outBS + (long)oo * NP + px] = f2bf(v);
                else ((float*)outp)[(long)b * outBS + (long)oo * NP + px] = v;
                if (DUAL) out2[(long)b * out2BS + (long)oo * NP + px] = v;
                if (LNOUT) xn[((long)b * 64 + oo) * NP + px] = f2bf((v - muA[n]) * invA[n]);
            }
        }
}

// fold LN gamma/beta into qkv / ffn-in weights; bf16 weights + fp32 bias.
__global__ void fold_ln(
    const float* __restrict__ wqkv, const float* __restrict__ ln1w, const float* __restrict__ ln1b,
    const float* __restrict__ win,  const float* __restrict__ ln2w, const float* __restrict__ ln2b,
    u16* __restrict__ fq, float* __restrict__ fqB,
    u16* __restrict__ ff, float* __restrict__ ffB)
{
    int g = blockIdx.x;
    int i = g / 7, r = g % 7;
    const float *wsrc, *lg, *lb;
    u16* wd; float* Bd;
    int obase;
    if (r < 3) {
        wsrc = wqkv + (long)i * 192 * 64; lg = ln1w + i * 64; lb = ln1b + i * 64;
        wd = fq + (long)i * 192 * 64; Bd = fqB + i * 192; obase = r * 64;
    } else {
        wsrc = win + (long)i * 256 * 64; lg = ln2w + i * 64; lb = ln2b + i * 64;
        wd = ff + (long)i * 256 * 64; Bd = ffB + i * 256; obase = (r - 3) * 64;
    }
    int o = obase + threadIdx.x;
    float Bv = 0.f;
    for (int c = 0; c < 64; ++c) {
        float wv = wsrc[(long)o * 64 + c];
        wd[(long)o * 64 + c] = f2bf(wv * lg[c]);
        Bv += wv * lb[c];
    }
    Bd[o] = Bv;
}

// per-(b,c) mean of bf16 buffer. grid (C, nb)
__global__ __launch_bounds__(256) void chanreduce_bf(
    const u16* __restrict__ in, long bs, float* __restrict__ out,
    int C, float scale)
{
    int c = blockIdx.x, b = blockIdx.y;
    const u16* p = in + (long)b * bs + (long)c * NP;
    float s = 0.f;
    for (long i = threadIdx.x * 4; i < NP; i += 1024) {
        ushort4 u = *(const ushort4*)(p + i);
        s += bf2f(u.x) + bf2f(u.y) + bf2f(u.z) + bf2f(u.w);
    }
    __shared__ float red[256];
    red[threadIdx.x] = s;
    __syncthreads();
    for (int st = 128; st > 0; st >>= 1) {
        if (threadIdx.x < st) red[threadIdx.x] += red[threadIdx.x + st];
        __syncthreads();
    }
    if (threadIdx.x == 0) out[b * C + c] = red[0] * scale;
}

// stage one LDS row (16 px) of a bf16 channel strip
__device__ __forceinline__ void stage_row(float (*S)[260], const u16* __restrict__ src,
                                          int y0, int j, int px)
{
    int row = y0 - 1 + j;
    if (row >= 0 && row < HHH) {
        ushort8_t a = *(const ushort8_t*)(src + row * WWW + px);
        ushort8_t b = *(const ushort8_t*)(src + row * WWW + px + 8);
#pragma unroll
        for (int e = 0; e < 8; ++e) { S[j][1 + px + e] = bf2f(a[e]); S[j][9 + px + e] = bf2f(b[e]); }
    } else {
#pragma unroll
        for (int e = 0; e < 16; ++e) S[j][1 + px + e] = 0.f;
    }
}
__device__ __forceinline__ float conv9(const float (*S)[260], int r, int col,
                                       const float* __restrict__ w9)
{
    float a = 0.f;
#pragma unroll
    for (int ky = 0; ky < 3; ++ky)
#pragma unroll
        for (int kx = 0; kx < 3; ++kx)
            a = fmaf(w9[ky * 3 + kx], S[r + ky][col + kx], a);
    return a;
}

// depthwise 3x3, 16-row strips. grid (16, C, nb)
__global__ __launch_bounds__(256) void dw3x3_strip(
    const u16* __restrict__ in, long inBS, const float* __restrict__ w,
    u16* __restrict__ out, long outBS)
{
    int strip = blockIdx.x, c = blockIdx.y, b = blockIdx.z;
    int y0 = strip * 16, tid = threadIdx.x;
    __shared__ float S[18][260];
    const u16* src = in + (long)b * inBS + (long)c * NP;
    int j = tid >> 4, px = (tid & 15) * 16;
    stage_row(S, src, y0, j, px);
    if (tid < 32) stage_row(S, src, y0, 16 + (tid >> 4), px);
    if (tid < 18) { S[tid][0] = 0.f; S[tid][257] = 0.f; }
    __syncthreads();
    float w9[9];
#pragma unroll
    for (int k = 0; k < 9; ++k) w9[k] = w[c * 9 + k];
    u16* dst = out + (long)b * outBS + (long)c * NP;
#pragma unroll
    for (int r = 0; r < 16; ++r)
        dst[(y0 + r) * WWW + tid] = f2bf(conv9(S, r, tid, w9));
}

// ffn: dw3x3 on (c, c+128) + gelu(y1)*y2, strips. grid (16, 128, nb)
__global__ __launch_bounds__(256) void ffn_dw_glu_strip(
    const u16* __restrict__ y, long yBS, const float* __restrict__ w,
    u16* __restrict__ g, long gBS)
{
    int strip = blockIdx.x, c = blockIdx.y, b = blockIdx.z;
    int y0 = strip * 16, tid = threadIdx.x;
    __shared__ float S1[18][260];
    __shared__ float S2[18][260];
    const u16* s1 = y + (long)b * yBS + (long)c * NP;
    const u16* s2 = y + (long)b * yBS + (long)(c + 128) * NP;
    int j = tid >> 4, px = (tid & 15) * 16;
    stage_row(S1, s1, y0, j, px);
    if (tid < 32) stage_row(S1, s1, y0, 16 + (tid >> 4), px);
    stage_row(S2, s2, y0, j, px);
    if (tid < 32) stage_row(S2, s2, y0, 16 + (tid >> 4), px);
    if (tid < 18) { S1[tid][0] = S1[tid][257] = 0.f; S2[tid][0] = S2[tid][257] = 0.f; }
    __syncthreads();
    float w1[9], w2[9];
#pragma unroll
    for (int k = 0; k < 9; ++k) { w1[k] = w[c * 9 + k]; w2[k] = w[(c + 128) * 9 + k]; }
    u16* dst = g + (long)b * gBS + (long)c * NP;
#pragma unroll
    for (int r = 0; r < 16; ++r) {
        float a1 = conv9(S1, r, tid, w1);
        float a2 = conv9(S2, r, tid, w2);
        dst[(y0 + r) * WWW + tid] = f2bf(gelu_exact(a1) * a2);
    }
}

// CIIM grouped dw conv, strips. grid (16, 64, nb)
__global__ __launch_bounds__(256) void ciim_dw_strip(
    const u16* __restrict__ fuse, long fBS, const float* __restrict__ means,
    const float* __restrict__ wdw, const float* __restrict__ bdw,
    u16* __restrict__ hl, long hlBS)
{
    int strip = blockIdx.x, c = blockIdx.y, b = blockIdx.z;
    int y0 = strip * 16, tid = threadIdx.x;
    __shared__ float S[18][260];
    float acc[16];
    float bias = bdw[c];
#pragma unroll
    for (int r = 0; r < 16; ++r) acc[r] = bias;
    for (int j6 = 0; j6 < 6; ++j6) {
        int ic = 6 * c + j6;
        const float* w9p = wdw + (c * 6 + j6) * 9;
        float w9[9];
#pragma unroll
        for (int k = 0; k < 9; ++k) w9[k] = w9p[k];
        if (ic < 128) {
            __syncthreads();
            const u16* src = fuse + (long)b * fBS + (long)ic * NP;
            int j = tid >> 4, px = (tid & 15) * 16;
            stage_row(S, src, y0, j, px);
            if (tid < 32) stage_row(S, src, y0, 16 + (tid >> 4), px);
            if (tid < 18) { S[tid][0] = 0.f; S[tid][257] = 0.f; }
            __syncthreads();
#pragma unroll
            for (int r = 0; r < 16; ++r) acc[r] += conv9(S, r, tid, w9);
        } else {
            float mv = means[b * 256 + ic - 128];
#pragma unroll
            for (int r = 0; r < 16; ++r) {
                int row = y0 + r;
                float ws = 0.f;
#pragma unroll
                for (int ky = 0; ky < 3; ++ky) {
                    int yy = row + ky - 1;
                    if (yy < 0 || yy >= HHH) continue;
#pragma unroll
                    for (int kx = 0; kx < 3; ++kx) {
                        int xx = tid + kx - 1;
                        if (xx < 0 || xx >= WWW) continue;
                        ws += w9[ky * 3 + kx];
                    }
                }
                acc[r] += mv * ws;
            }
        }
    }
    u16* dst = hl + (long)b * hlBS + (long)c * NP;
#pragma unroll
    for (int r = 0; r < 16; ++r) dst[(y0 + r) * WWW + tid] = f2bf(acc[r]);
}

// gating + concat + channel shuffle. grid (64, 128, nb)
__global__ __launch_bounds__(256) void outsh4(
    const u16* __restrict__ hl, long hlBS,
    const float* __restrict__ low, long lBS,
    const float* __restrict__ high,
    u16* __restrict__ outb, long oBS)
{
    long p = ((long)blockIdx.x * 256 + threadIdx.x) * 4;
    int cn = blockIdx.y, b = blockIdx.z;
    int co = (cn & 31) * 4 + (cn >> 5);
    const u16* hp;
    const float* sp;
    if (co < 64) {
        hp = hl + (long)b * hlBS + (long)co * NP + p;
        sp = low + (long)b * lBS + (long)co * NP + p;
    } else {
        hp = hl + (long)b * hlBS + (long)(co - 64) * NP + p;
        sp = high + (long)b * lBS + (long)(co - 64) * NP + p;
    }
    ushort4 hu = *(const ushort4*)hp;
    float4 sv = *(const float4*)sp;
    float hv[4] = {bf2f(hu.x), bf2f(hu.y), bf2f(hu.z), bf2f(hu.w)};
    float s4[4] = {sv.x, sv.y, sv.z, sv.w};
    ushort4 ovec;
    u16* ov = (u16*)&ovec;
#pragma unroll
    for (int k = 0; k < 4; ++k) {
        float gg = (co < 64) ? sigmoidf_(gelu_exact(hv[k])) : sigmoidf_(fmaxf(hv[k], 0.f));
        ov[k] = f2bf(gg * s4[k]);
    }
    *(ushort4*)((u16*)outb + (long)b * oBS + (long)cn * NP + p) = ovec;
}

// scaled rc2 weights (bf16). grid (nb*32)
__global__ __launch_bounds__(256) void rc2w_build(
    const float* __restrict__ ecam, const float* __restrict__ ecaw,
    const float* __restrict__ wrc2, u16* __restrict__ wout)
{
    int idx = blockIdx.x * 256 + threadIdx.x;
    int c = idx & 127, o = (idx >> 7) & 63, b = idx >> 13;
    float y = sigmoidf_(ecam[b * 128 + c] * ecaw[c]);
    wout[idx] = f2bf(wrc2[o * 128 + c] * y);
}

// q.k dots + sumsq norms over pixel chunks. grid (QKCH, 8, nb)
__global__ __launch_bounds__(256) void qk_dot(
    const u16* __restrict__ D, long dBS, float* __restrict__ part)
{
    int chunk = blockIdx.x, h = blockIdx.y, b = blockIdx.z;
    int tid = threadIdx.x, lane = tid & 63, wave = tid >> 6;
    const u16* q = D + (long)b * dBS + (long)(h * 8) * NP;
    const u16* k = q + 64 * NP;
    float dots[64], nq[8], nk[8];
#pragma unroll
    for (int a = 0; a < 64; ++a) dots[a] = 0.f;
#pragma unroll
    for (int a = 0; a < 8; ++a) { nq[a] = 0.f; nk[a] = 0.f; }
    long base = (long)chunk * 4096 + tid * 8;
    for (int pass = 0; pass < 2; ++pass) {
        long p = base + pass * 2048;
        ushort8_t qv[8], kv[8];
#pragma unroll
        for (int i = 0; i < 8; ++i) qv[i] = *(const ushort8_t*)(q + (long)i * NP + p);
#pragma unroll
        for (int i = 0; i < 8; ++i) kv[i] = *(const ushort8_t*)(k + (long)i * NP + p);
#pragma unroll
        for (int e = 0; e < 8; ++e) {
            float qe[8], ke[8];
#pragma unroll
            for (int i = 0; i < 8; ++i) { qe[i] = bf2f(qv[i][e]); ke[i] = bf2f(kv[i][e]); }
#pragma unroll
            for (int i = 0; i < 8; ++i) {
                nq[i] = fmaf(qe[i], qe[i], nq[i]);
                nk[i] = fmaf(ke[i], ke[i], nk[i]);
#pragma unroll
                for (int jj = 0; jj < 8; ++jj)
                    dots[i * 8 + jj] = fmaf(qe[i], ke[jj], dots[i * 8 + jj]);
            }
        }
    }
    __shared__ float red[4][80];
#pragma unroll
    for (int a = 0; a < 64; ++a) {
        float v = dots[a];
#pragma unroll
        for (int o = 32; o > 0; o >>= 1) v += __shfl_xor(v, o);
        if (lane == 0) red[wave][a] = v;
    }
#pragma unroll
    for (int a = 0; a < 8; ++a) {
        float v1 = nq[a], v2 = nk[a];
#pragma unroll
        for (int o = 32; o > 0; o >>= 1) { v1 += __shfl_xor(v1, o); v2 += __shfl_xor(v2, o); }
        if (lane == 0) { red[wave][64 + a] = v1; red[wave][72 + a] = v2; }
    }
    __syncthreads();
    if (tid < 80) {
        float v = red[0][tid] + red[1][tid] + red[2][tid] + red[3][tid];
        part[(((long)b * 8 + h) * 80 + tid) * QKCH + chunk] = v;
    }
}

// head conv1 as implicit MFMA GEMM: 64->32, 3x3, leaky, bf16 out.
// grid (16 ty, 16 tx, nb); 16x16 px tile; K = 9 taps x 64 c.
__global__ __launch_bounds__(256) void head1_mfma(
    const float* __restrict__ X, const u16* __restrict__ wtap,
    u16* __restrict__ H)
{
    __shared__ u16 P[18][18][72];
    int ty = blockIdx.x, tx = blockIdx.y, b = blockIdx.z;
    int tid = threadIdx.x, lane = tid & 63, wave = tid >> 6;
    int rl = lane & 15, rg = lane >> 4;
    // stage 18x18 patch of all 64 channels (fp32 -> bf16)
    {
        int lane5 = tid & 31;
        int cbase = tid >> 5;  // 0..7
#pragma unroll
        for (int cg = 0; cg < 8; ++cg) {
            int c = cg * 8 + cbase;
            const float* src = X + ((long)b * 64 + c) * NP;
            for (int it = 0; it < 11; ++it) {
                int px = lane5 + it * 32;
                if (px < 324) {
                    int row = px / 18, col = px % 18;
                    int gy = ty * 16 - 1 + row, gx = tx * 16 - 1 + col;
                    float v = (gy >= 0 && gy < HHH && gx >= 0 && gx < WWW)
                                  ? src[gy * WWW + gx] : 0.f;
                    P[row][col][c] = f2bf(v);
                }
            }
        }
    }
    __syncthreads();
    f32x4 acc[2][4];
#pragma unroll
    for (int m = 0; m < 2; ++m)
#pragma unroll
        for (int n = 0; n < 4; ++n) acc[m][n] = (f32x4){0.f, 0.f, 0.f, 0.f};
#pragma unroll
    for (int tap = 0; tap < 9; ++tap) {
        int ky = tap / 3, kx = tap % 3;
#pragma unroll
        for (int ks = 0; ks < 2; ++ks) {
            int kc = ks * 32 + rg * 8;
            s16x8 a0 = *(const s16x8*)(wtap + tap * 2048 + (long)(0 + rl) * 64 + kc);
            s16x8 a1 = *(const s16x8*)(wtap + tap * 2048 + (long)(16 + rl) * 64 + kc);
#pragma unroll
            for (int n = 0; n < 4; ++n) {
                int py = wave * 4 + n;
                s16x8 bb = *(const s16x8*)&P[py + ky][kx + rl][kc];
                acc[0][n] = __builtin_amdgcn_mfma_f32_16x16x32_bf16(a0, bb, acc[0][n], 0, 0, 0);
                acc[1][n] = __builtin_amdgcn_mfma_f32_16x16x32_bf16(a1, bb, acc[1][n], 0, 0, 0);
            }
        }
    }
#pragma unroll
    for (int m = 0; m < 2; ++m)
#pragma unroll
        for (int n = 0; n < 4; ++n) {
            int py = wave * 4 + n;
#pragma unroll
            for (int r = 0; r < 4; ++r) {
                int o = m * 16 + rg * 4 + r;
                float v = acc[m][n][r];
                v = v > 0.f ? v : 0.01f * v;
                H[((long)b * 32 + o) * NP + (ty * 16 + py) * WWW + tx * 16 + rl] = f2bf(v);
            }
        }
}

// head conv2: 3x3, 32->1 (bf16 in), + inp, sigmoid. grid (256, nb)
__global__ __launch_bounds__(256) void head_conv2(
    const u16* __restrict__ x, const float* __restrict__ w,
    const float* __restrict__ inp, float* __restrict__ out)
{
    int xx0 = threadIdx.x, y = blockIdx.x, b = blockIdx.y;
    __shared__ float wl[288];
    for (int idx = threadIdx.x; idx < 288; idx += 256) wl[idx] = w[idx];
    __syncthreads();
    float acc = 0.f;
    for (int c = 0; c < 32; ++c) {
        const u16* src = x + ((long)b * 32 + c) * NP;
#pragma unroll
        for (int ky = 0; ky < 3; ++ky) {
            int yy = y + ky - 1;
            if (yy < 0 || yy >= HHH) continue;
#pragma unroll
            for (int kx = 0; kx < 3; ++kx) {
                int xx = xx0 + kx - 1;
                if (xx < 0 || xx >= WWW) continue;
                acc += wl[c * 9 + ky * 3 + kx] * bf2f(src[yy * WWW + xx]);
            }
        }
    }
    float v = acc + inp[(long)b * NP + y * WWW + xx0];
    out[(long)b * NP + y * WWW + xx0] = 1.f / (1.f + expf(-v));
}

// ---------------------------------------------------------------------------
extern "C" void kernel_launch(void* const* d_in, const int* in_sizes, int n_in,
                              void* d_out, int out_size, void* d_ws, size_t ws_size,
                              hipStream_t stream)
{
    const float* inp    = (const float*)d_in[0];
    const float* base   = (const float*)d_in[1];
    const float* detail = (const float*)d_in[2];
    const float* w_ir   = (const float*)d_in[3];
    const float* w_vi   = (const float*)d_in[4];
    const float* w_fu   = (const float*)d_in[5];
    const float* b_fu   = (const float*)d_in[6];
    const float* w_dwc  = (const float*)d_in[7];
    const float* b_dwc  = (const float*)d_in[8];
    const float* eca_w  = (const float*)d_in[9];
    const float* w_rc2  = (const float*)d_in[10];
    const float* ln1w   = (const float*)d_in[11];
    const float* ln1b   = (const float*)d_in[12];
    const float* w_qkv  = (const float*)d_in[13];
    const float* w_qdw  = (const float*)d_in[14];
    const float* temp   = (const float*)d_in[15];
    const float* w_proj = (const float*)d_in[16];
    const float* ln2w   = (const float*)d_in[17];
    const float* ln2b   = (const float*)d_in[18];
    const float* w_in_  = (const float*)d_in[19];
    const float* w_fdw  = (const float*)d_in[20];
    const float* w_out_ = (const float*)d_in[21];
    const float* w_h1   = (const float*)d_in[22];
    const float* w_h2   = (const float*)d_in[23];

    float* out = (float*)d_out;

    auto needB = [&](long nb) -> size_t {
        return (size_t)nb * NP * (64 * 4 + 64 * 2 + 256 * 2 + 192 * 2) + (16u << 20);
    };
    int bInner;
    if (ws_size >= needB(4)) bInner = 4;
    else if (ws_size >= needB(1)) bInner = 1;
    else {
        diag_kernel<<<1, 64, 0, stream>>>(out, (float)(ws_size >> 20));
        return;
    }
    const long nb = bInner;

    char* p = (char*)d_ws;
    auto alloc = [&](size_t bytes) -> char* {
        char* r = p; p += (bytes + 255) & ~(size_t)255; return r;
    };
    float* X      = (float*)alloc((size_t)nb * 64 * NP * 4);
    u16*   XN     = (u16*)alloc((size_t)nb * 64 * NP * 2);
    u16*   Y      = (u16*)alloc((size_t)nb * 256 * NP * 2);
    u16*   Dq     = (u16*)alloc((size_t)nb * 192 * NP * 2);
    float* part   = (float*)alloc((size_t)nb * 8 * 80 * QKCH * 4);
    u16*   rc2wb  = (u16*)alloc((size_t)nb * 8192 * 2);
    float* means  = (float*)alloc((size_t)nb * 256 * 4);
    float* ecam   = (float*)alloc((size_t)nb * 128 * 4);
    u16*   fq_bf  = (u16*)alloc((size_t)4 * 192 * 64 * 2);
    float* fqB    = (float*)alloc((size_t)4 * 192 * 4);
    u16*   ff_bf  = (u16*)alloc((size_t)4 * 256 * 64 * 2);
    float* ffB    = (float*)alloc((size_t)4 * 256 * 4);
    u16*   wir_bf = (u16*)alloc(8192 * 2);
    u16*   wvi_bf = (u16*)alloc(8192 * 2);
    u16*   wfu_bf = (u16*)alloc(32768 * 2);
    u16*   wout_bf= (u16*)alloc(32768 * 2);
    u16*   wtap   = (u16*)alloc(9 * 2048 * 2);
    u16*   Hbf    = Y;  // head scratch reuses Y

    dim3 blk(256);

    // one-time weight prep
    fold_ln<<<dim3(28), dim3(64), 0, stream>>>(w_qkv, ln1w, ln1b, w_in_, ln2w, ln2b,
                                               fq_bf, fqB, ff_bf, ffB);
    cvt_f2b<<<dim3(8), blk, 0, stream>>>(w_ir, wir_bf, 8192);
    cvt_f2b<<<dim3(8), blk, 0, stream>>>(w_vi, wvi_bf, 8192);
    cvt_f2b<<<dim3(32), blk, 0, stream>>>(w_fu, wfu_bf, 32768);
    cvt_f2b<<<dim3(32), blk, 0, stream>>>(w_out_, wout_bf, 32768);
    prep_wtap<<<dim3(9), blk, 0, stream>>>(w_h1, wtap);

    for (int b0 = 0; b0 < 4; b0 += bInner) {
        const float* inpB    = inp + (long)b0 * NP;
        const float* baseB   = base + (long)b0 * 64 * NP;
        const float* detailB = detail + (long)b0 * 64 * NP;
        float* out0  = out + (long)b0 * NP;
        float* outX0 = out + 262144 + (long)b0 * 64 * NP;

        // ---- CIIM ----
        gemm_mfma<1, 1, 0, 0, 0, 0, 0><<<dim3(2, 256, nb), blk, 0, stream>>>(
            baseB, 64 * NP, wir_bf, 0, nullptr, nullptr, 0, Y, 256 * NP,
            nullptr, 0, nullptr, nullptr, nullptr, nullptr, 64);
        gemm_mfma<1, 1, 0, 0, 0, 0, 0><<<dim3(2, 256, nb), blk, 0, stream>>>(
            detailB, 64 * NP, wvi_bf, 0, nullptr, nullptr, 0, Y + 128 * NP, 256 * NP,
            nullptr, 0, nullptr, nullptr, nullptr, nullptr, 64);
        chanreduce_bf<<<dim3(256, nb), blk, 0, stream>>>(Y, 256 * NP, means, 256, 1.f / NP);
        gemm_mfma<0, 1, 0, 0, 1, 0, 0><<<dim3(2, 256, nb), blk, 0, stream>>>(
            Y, 256 * NP, wfu_bf, 0, b_fu, nullptr, 0, Dq, 192 * NP,
            nullptr, 0, nullptr, nullptr, nullptr, nullptr, 256);
        ciim_dw_strip<<<dim3(16, 64, nb), blk, 0, stream>>>(
            Dq, 192 * NP, means, w_dwc, b_dwc, XN, 64 * NP);
        outsh4<<<dim3(64, 128, nb), blk, 0, stream>>>(
            XN, 64 * NP, baseB, 64 * NP, detailB, Y, 256 * NP);
        chanreduce_bf<<<dim3(128, nb), blk, 0, stream>>>(Y, 256 * NP, ecam, 128, 1.f / NP);
        rc2w_build<<<dim3(nb * 32), blk, 0, stream>>>(ecam, eca_w, w_rc2, rc2wb);
        // rc2 GEMM + dual store to out-x0 + fused LN -> XN
        gemm_mfma<0, 0, 0, 1, 0, 1, 0><<<dim3(1, 256, nb), blk, 0, stream>>>(
            Y, 256 * NP, rc2wb, 8192, nullptr, nullptr, 0, X, 64 * NP,
            outX0, 64 * NP, XN, nullptr, nullptr, nullptr, 128);

        // ---- transformer blocks ----
        for (int i = 0; i < 4; ++i) {
            gemm_mfma<0, 1, 0, 0, 1, 0, 0><<<dim3(3, 256, nb), blk, 0, stream>>>(
                XN, 64 * NP, fq_bf + (long)i * 192 * 64, 0, fqB + i * 192, nullptr, 0,
                Y, 256 * NP, nullptr, 0, nullptr, nullptr, nullptr, nullptr, 64);
            dw3x3_strip<<<dim3(16, 192, nb), blk, 0, stream>>>(
                Y, 256 * NP, w_qdw + (long)i * 192 * 9, Dq, 192 * NP);
            qk_dot<<<dim3(QKCH, 8, nb), blk, 0, stream>>>(Dq, 192 * NP, part);
            // pv GEMM: weff built in prologue; resid X; fused LN -> XN
            gemm_mfma<0, 0, 1, 0, 0, 1, 1><<<dim3(1, 256, nb), blk, 0, stream>>>(
                Dq + 128 * NP, 192 * NP, nullptr, 0, nullptr, X, 64 * NP,
                X, 64 * NP, nullptr, 0, XN, part, temp + i * 8,
                w_proj + (long)i * 4096, 64);
            gemm_mfma<0, 1, 0, 0, 1, 0, 0><<<dim3(4, 256, nb), blk, 0, stream>>>(
                XN, 64 * NP, ff_bf + (long)i * 256 * 64, 0, ffB + i * 256, nullptr, 0,
                Y, 256 * NP, nullptr, 0, nullptr, nullptr, nullptr, nullptr, 64);
            ffn_dw_glu_strip<<<dim3(16, 128, nb), blk, 0, stream>>>(
                Y, 256 * NP, w_fdw + (long)i * 256 * 9, Dq, 192 * NP);
            if (i < 3) {
                gemm_mfma<0, 0, 1, 0, 0, 1, 0><<<dim3(1, 256, nb), blk, 0, stream>>>(
                    Dq, 192 * NP, wout_bf + (long)i * 8192, 0, nullptr, X, 64 * NP,
                    X, 64 * NP, nullptr, 0, XN, nullptr, nullptr, nullptr, 128);
            } else {
                gemm_mfma<0, 0, 1, 0, 0, 0, 0><<<dim3(1, 256, nb), blk, 0, stream>>>(
                    Dq, 192 * NP, wout_bf + (long)i * 8192, 0, nullptr, X, 64 * NP,
                    X, 64 * NP, nullptr, 0, nullptr, nullptr, nullptr, nullptr, 128);
            }
        }

        // ---- head ----
        head1_mfma<<<dim3(16, 16, nb), blk, 0, stream>>>(X, wtap, Hbf);
        head_conv2<<<dim3(256, nb), blk, 0, stream>>>(Hbf, w_h2, inpB, out0);
    }
}

// Round 10
// 2491.460 us; speedup vs baseline: 1.3944x; 1.1393x over previous
//
#include <hip/hip_runtime.h>
#include <hip/hip_bf16.h>
#include <math.h>

#define NP 65536L
#define HHH 256
#define WWW 256
#define QKCH 32

typedef unsigned short u16;
typedef unsigned short ushort8_t __attribute__((ext_vector_type(8)));
typedef short s16x8 __attribute__((ext_vector_type(8)));
typedef float f32x4 __attribute__((ext_vector_type(4)));

__device__ __forceinline__ float bf2f(u16 u) { return __uint_as_float(((unsigned)u) << 16); }
__device__ __forceinline__ u16 f2bf(float f) {
    __hip_bfloat16 h = __float2bfloat16(f);
    return *reinterpret_cast<u16*>(&h);
}
__device__ __forceinline__ float sigmoidf_(float x) { return 1.f / (1.f + __expf(-x)); }
__device__ __forceinline__ float gelu_exact(float x) {
    return 0.5f * x * (1.f + erff(x * 0.70710678118654752f));
}

__global__ void diag_kernel(float* out, float v) {
    if (threadIdx.x == 0 && blockIdx.x == 0) out[0] = v;
}

// one-shot weight prep: bf16 casts of 4 weight tensors + wtap rearrange.
// grid (89): blocks 0..79 cvt (4 el/thread over 81920), 80..88 wtap taps.
__global__ __launch_bounds__(256) void prep_misc(
    const float* __restrict__ wir, const float* __restrict__ wvi,
    const float* __restrict__ wfu, const float* __restrict__ wout,
    const float* __restrict__ wh1,
    u16* __restrict__ dir, u16* __restrict__ dvi,
    u16* __restrict__ dfu, u16* __restrict__ dout,
    u16* __restrict__ wtap)
{
    int bid = blockIdx.x;
    if (bid < 80) {
        long e = (long)bid * 1024 + threadIdx.x * 4;
        const float* src; u16* dst; long off;
        if (e < 8192)       { src = wir;  dst = dir;  off = 0; }
        else if (e < 16384) { src = wvi;  dst = dvi;  off = 8192; }
        else if (e < 49152) { src = wfu;  dst = dfu;  off = 16384; }
        else                { src = wout; dst = dout; off = 49152; }
        long i = e - off;
        float4 v = *(const float4*)(src + i);
        ushort4 o;
        o.x = f2bf(v.x); o.y = f2bf(v.y); o.z = f2bf(v.z); o.w = f2bf(v.w);
        *(ushort4*)(dst + i) = o;
    } else {
        int tap = bid - 80;
        for (int e = threadIdx.x; e < 2048; e += 256)
            wtap[tap * 2048 + e] = f2bf(wh1[(long)e * 9 + tap]);
    }
}

// fold LN gamma/beta into qkv / ffn-in weights; bf16 weights + fp32 bias.
__global__ void fold_ln(
    const float* __restrict__ wqkv, const float* __restrict__ ln1w, const float* __restrict__ ln1b,
    const float* __restrict__ win,  const float* __restrict__ ln2w, const float* __restrict__ ln2b,
    u16* __restrict__ fq, float* __restrict__ fqB,
    u16* __restrict__ ff, float* __restrict__ ffB)
{
    int g = blockIdx.x;
    int i = g / 7, r = g % 7;
    const float *wsrc, *lg, *lb;
    u16* wd; float* Bd;
    int obase;
    if (r < 3) {
        wsrc = wqkv + (long)i * 192 * 64; lg = ln1w + i * 64; lb = ln1b + i * 64;
        wd = fq + (long)i * 192 * 64; Bd = fqB + i * 192; obase = r * 64;
    } else {
        wsrc = win + (long)i * 256 * 64; lg = ln2w + i * 64; lb = ln2b + i * 64;
        wd = ff + (long)i * 256 * 64; Bd = ffB + i * 256; obase = (r - 3) * 64;
    }
    int o = obase + threadIdx.x;
    float Bv = 0.f;
    for (int c = 0; c < 64; ++c) {
        float wv = wsrc[(long)o * 64 + c];
        wd[(long)o * 64 + c] = f2bf(wv * lg[c]);
        Bv += wv * lb[c];
    }
    Bd[o] = Bv;
}

// ---------------------------------------------------------------------------
// CIIM input GEMMs (ir + vi in one dispatch) + fused per-channel means atomic.
// grid (4, 256, nb): x<2 -> base*w_ir -> Y[x*64..], x>=2 -> detail*w_vi.
// ---------------------------------------------------------------------------
__global__ __launch_bounds__(256) void gemm_irvi(
    const float* __restrict__ base, const float* __restrict__ detail,
    const u16* __restrict__ wir, const u16* __restrict__ wvi,
    u16* __restrict__ Y, float* __restrict__ means)
{
    __shared__ u16 XT[256][72];
    __shared__ u16 WT[64][72];
    __shared__ float red[4][64];
    int xsel = blockIdx.x, b = blockIdx.z;
    long P0 = (long)blockIdx.y * 256;
    int tid = threadIdx.x, lane = tid & 63, wave = tid >> 6;
    int rl = lane & 15, rg = lane >> 4;
    const float* in = ((xsel < 2) ? base : detail) + (long)b * 64 * NP;
    const u16* wsel = (xsel < 2) ? wir : wvi;
    int orow0 = (xsel & 1) * 64;
    int ochan0 = xsel * 64;

    {   // stage weights [64][64]
        int o = tid >> 2, cs = (tid & 3) * 16;
        const u16* src = wsel + (long)(orow0 + o) * 64 + cs;
        *(ushort8_t*)&WT[o][cs] = *(const ushort8_t*)src;
        *(ushort8_t*)&WT[o][cs + 8] = *(const ushort8_t*)(src + 8);
    }
    {   // stage X fp32 -> bf16 transposed [256 px][64 c]
        int c0 = (tid & 7) * 8;
        int pt = (tid >> 3) * 8;
        u16 rr[8][8];
#pragma unroll
        for (int i = 0; i < 8; ++i) {
            const float* sp = in + (long)(c0 + i) * NP + P0 + pt;
            float4 a = *(const float4*)sp;
            float4 b4 = *(const float4*)(sp + 4);
            rr[i][0] = f2bf(a.x); rr[i][1] = f2bf(a.y);
            rr[i][2] = f2bf(a.z); rr[i][3] = f2bf(a.w);
            rr[i][4] = f2bf(b4.x); rr[i][5] = f2bf(b4.y);
            rr[i][6] = f2bf(b4.z); rr[i][7] = f2bf(b4.w);
        }
#pragma unroll
        for (int j = 0; j < 8; ++j) {
            ushort8_t v;
#pragma unroll
            for (int i = 0; i < 8; ++i) v[i] = rr[i][j];
            *(ushort8_t*)&XT[pt + j][c0] = v;
        }
    }
    __syncthreads();
    f32x4 acc[4][4];
#pragma unroll
    for (int m = 0; m < 4; ++m)
#pragma unroll
        for (int n = 0; n < 4; ++n) acc[m][n] = (f32x4){0.f, 0.f, 0.f, 0.f};
#pragma unroll
    for (int ks = 0; ks < 2; ++ks) {
        int kc = ks * 32 + rg * 8;
        s16x8 a[4], bb[4];
#pragma unroll
        for (int m = 0; m < 4; ++m) a[m] = *(const s16x8*)&WT[m * 16 + rl][kc];
#pragma unroll
        for (int n = 0; n < 4; ++n) bb[n] = *(const s16x8*)&XT[wave * 64 + n * 16 + rl][kc];
#pragma unroll
        for (int m = 0; m < 4; ++m)
#pragma unroll
            for (int n = 0; n < 4; ++n)
                acc[m][n] = __builtin_amdgcn_mfma_f32_16x16x32_bf16(a[m], bb[n], acc[m][n], 0, 0, 0);
    }
    // stores + per-channel partial sums
    float csum[4][4];
#pragma unroll
    for (int m = 0; m < 4; ++m)
#pragma unroll
        for (int r = 0; r < 4; ++r) csum[m][r] = 0.f;
#pragma unroll
    for (int m = 0; m < 4; ++m)
#pragma unroll
        for (int n = 0; n < 4; ++n) {
            long px = P0 + wave * 64 + n * 16 + rl;
#pragma unroll
            for (int r = 0; r < 4; ++r) {
                int oo = ochan0 + m * 16 + rg * 4 + r;
                float v = acc[m][n][r];
                Y[((long)b * 256 + oo) * NP + px] = f2bf(v);
                csum[m][r] += v;
            }
        }
#pragma unroll
    for (int m = 0; m < 4; ++m)
#pragma unroll
        for (int r = 0; r < 4; ++r) {
            float s = csum[m][r];
            s += __shfl_xor(s, 1); s += __shfl_xor(s, 2);
            s += __shfl_xor(s, 4); s += __shfl_xor(s, 8);
            if (rl == 0) red[wave][m * 16 + rg * 4 + r] = s;
        }
    __syncthreads();
    if (tid < 64) {
        float v = red[0][tid] + red[1][tid] + red[2][tid] + red[3][tid];
        atomicAdd(&means[b * 256 + ochan0 + tid], v * (1.f / NP));
    }
}

// plain MFMA GEMM (used for the fuse conv): in bf16, out bf16, bias.
// grid (Cout/64, 256, nb)
__global__ __launch_bounds__(256) void gemm_plain(
    const u16* __restrict__ in, long inBS,
    const u16* __restrict__ wbf,
    const float* __restrict__ bias,
    u16* __restrict__ outp, long outBS, int Cin)
{
    __shared__ u16 XT[256][72];
    __shared__ u16 WT[64][72];
    int b = blockIdx.z;
    int oBase = blockIdx.x * 64;
    long P0 = (long)blockIdx.y * 256;
    int tid = threadIdx.x, lane = tid & 63, wave = tid >> 6;
    int rl = lane & 15, rg = lane >> 4;
    const u16* inB = in + (long)b * inBS;
    f32x4 acc[4][4];
#pragma unroll
    for (int m = 0; m < 4; ++m)
#pragma unroll
        for (int n = 0; n < 4; ++n) acc[m][n] = (f32x4){0.f, 0.f, 0.f, 0.f};
    for (int ck = 0; ck < Cin; ck += 64) {
        if (ck) __syncthreads();
        {
            int o = tid >> 2, cs = (tid & 3) * 16;
            const u16* src = wbf + (long)(oBase + o) * Cin + ck + cs;
            *(ushort8_t*)&WT[o][cs] = *(const ushort8_t*)src;
            *(ushort8_t*)&WT[o][cs + 8] = *(const ushort8_t*)(src + 8);
        }
        {
            int c0 = (tid & 7) * 8;
            int pt = (tid >> 3) * 8;
            ushort8_t r[8];
#pragma unroll
            for (int i = 0; i < 8; ++i)
                r[i] = *(const ushort8_t*)(inB + (long)(ck + c0 + i) * NP + P0 + pt);
#pragma unroll
            for (int j = 0; j < 8; ++j) {
                ushort8_t v;
#pragma unroll
                for (int i = 0; i < 8; ++i) v[i] = r[i][j];
                *(ushort8_t*)&XT[pt + j][c0] = v;
            }
        }
        __syncthreads();
#pragma unroll
        for (int ks = 0; ks < 2; ++ks) {
            int kc = ks * 32 + rg * 8;
            s16x8 a[4], bb[4];
#pragma unroll
            for (int m = 0; m < 4; ++m) a[m] = *(const s16x8*)&WT[m * 16 + rl][kc];
#pragma unroll
            for (int n = 0; n < 4; ++n) bb[n] = *(const s16x8*)&XT[wave * 64 + n * 16 + rl][kc];
#pragma unroll
            for (int m = 0; m < 4; ++m)
#pragma unroll
                for (int n = 0; n < 4; ++n)
                    acc[m][n] = __builtin_amdgcn_mfma_f32_16x16x32_bf16(a[m], bb[n], acc[m][n], 0, 0, 0);
        }
    }
#pragma unroll
    for (int m = 0; m < 4; ++m) {
#pragma unroll
        for (int n = 0; n < 4; ++n) {
            long px = P0 + wave * 64 + n * 16 + rl;
#pragma unroll
            for (int r = 0; r < 4; ++r) {
                int oo = oBase + m * 16 + rg * 4 + r;
                outp[(long)b * outBS + (long)oo * NP + px] = f2bf(acc[m][n][r] + bias[oo]);
            }
        }
    }
}

// ---------------------------------------------------------------------------
// Fused GEMM -> X(fp32) -> LN -> LDS -> second GEMM -> Y(bf16).
// First gemm: M=64, Cin in {64,128}. WEFF: build weff in prologue (Cin=64).
// M2 in {0,192,256}: 0 = no second gemm (plain out store only).
// grid (256, nb).
// ---------------------------------------------------------------------------
template<int WEFF, int RESID, int DUAL, int M2>
__global__ __launch_bounds__(256) void gemm_fused(
    const u16* __restrict__ in, long inBS,
    const u16* __restrict__ w1, long w1BS,
    const float* __restrict__ residX,
    float* __restrict__ Xout,
    float* __restrict__ out2,
    const u16* __restrict__ w2, const float* __restrict__ bias2,
    u16* __restrict__ Yout,
    const float* __restrict__ part, const float* __restrict__ temp,
    const float* __restrict__ wproj,
    int Cin)
{
    __shared__ u16 XT[256][72] __attribute__((aligned(16)));
    __shared__ u16 WT[64][72] __attribute__((aligned(16)));
    int b = blockIdx.z;
    long P0 = (long)blockIdx.x * 256;
    int tid = threadIdx.x, lane = tid & 63, wave = tid >> 6;
    int rl = lane & 15, rg = lane >> 4;
    const u16* inB = in + (long)b * inBS;

    if constexpr (WEFF) {
        float* SgF = (float*)&XT[0][0];
        float* attF = SgF + 640;
        for (int e = tid; e < 640; e += 256) {
            int h = e / 80, k = e % 80;
            const float* pp = part + (((long)b * 8 + h) * 80 + k) * QKCH;
            float s = 0.f;
#pragma unroll
            for (int c = 0; c < QKCH; ++c) s += pp[c];
            SgF[e] = s;
        }
        __syncthreads();
        if (tid < 64) {
            int h = tid >> 3, iq = tid & 7;
            float nqv = fmaxf(sqrtf(SgF[h * 80 + 64 + iq]), 1e-12f);
            float tp = temp[h];
            float row[8], mx = -1e30f;
#pragma unroll
            for (int jj = 0; jj < 8; ++jj) {
                float nkv = fmaxf(sqrtf(SgF[h * 80 + 72 + jj]), 1e-12f);
                row[jj] = SgF[h * 80 + iq * 8 + jj] / (nqv * nkv) * tp;
                mx = fmaxf(mx, row[jj]);
            }
            float sum = 0.f;
#pragma unroll
            for (int jj = 0; jj < 8; ++jj) { row[jj] = __expf(row[jj] - mx); sum += row[jj]; }
            float rinv = 1.f / sum;
#pragma unroll
            for (int jj = 0; jj < 8; ++jj) attF[(h * 8 + iq) * 8 + jj] = row[jj] * rinv;
        }
        __syncthreads();
        {
            int o = tid >> 2;
            int cv0 = (tid & 3) * 16;
#pragma unroll
            for (int cv = 0; cv < 16; ++cv) {
                int c = cv0 + cv;
                int h = c >> 3, jj = c & 7;
                float s = 0.f;
#pragma unroll
                for (int i = 0; i < 8; ++i)
                    s = fmaf(wproj[o * 64 + h * 8 + i], attF[(h * 8 + i) * 8 + jj], s);
                WT[o][c] = f2bf(s);
            }
        }
        __syncthreads();
    }

    f32x4 acc[4][4];
#pragma unroll
    for (int m = 0; m < 4; ++m)
#pragma unroll
        for (int n = 0; n < 4; ++n) acc[m][n] = (f32x4){0.f, 0.f, 0.f, 0.f};

    for (int ck = 0; ck < Cin; ck += 64) {
        if (ck) __syncthreads();
        if constexpr (!WEFF) {
            int o = tid >> 2, cs = (tid & 3) * 16;
            const u16* src = w1 + (long)b * w1BS + (long)o * Cin + ck + cs;
            *(ushort8_t*)&WT[o][cs] = *(const ushort8_t*)src;
            *(ushort8_t*)&WT[o][cs + 8] = *(const ushort8_t*)(src + 8);
        }
        {
            int c0 = (tid & 7) * 8;
            int pt = (tid >> 3) * 8;
            ushort8_t r[8];
#pragma unroll
            for (int i = 0; i < 8; ++i)
                r[i] = *(const ushort8_t*)(inB + (long)(ck + c0 + i) * NP + P0 + pt);
#pragma unroll
            for (int j = 0; j < 8; ++j) {
                ushort8_t v;
#pragma unroll
                for (int i = 0; i < 8; ++i) v[i] = r[i][j];
                *(ushort8_t*)&XT[pt + j][c0] = v;
            }
        }
        __syncthreads();
#pragma unroll
        for (int ks = 0; ks < 2; ++ks) {
            int kc = ks * 32 + rg * 8;
            s16x8 a[4], bb[4];
#pragma unroll
            for (int m = 0; m < 4; ++m) a[m] = *(const s16x8*)&WT[m * 16 + rl][kc];
#pragma unroll
            for (int n = 0; n < 4; ++n) bb[n] = *(const s16x8*)&XT[wave * 64 + n * 16 + rl][kc];
#pragma unroll
            for (int m = 0; m < 4; ++m)
#pragma unroll
                for (int n = 0; n < 4; ++n)
                    acc[m][n] = __builtin_amdgcn_mfma_f32_16x16x32_bf16(a[m], bb[n], acc[m][n], 0, 0, 0);
        }
    }

    // epilogue 1: resid + X store (+dual)
#pragma unroll
    for (int m = 0; m < 4; ++m)
#pragma unroll
        for (int n = 0; n < 4; ++n) {
            long px = P0 + wave * 64 + n * 16 + rl;
#pragma unroll
            for (int r = 0; r < 4; ++r) {
                int oo = m * 16 + rg * 4 + r;
                float t = acc[m][n][r];
                if constexpr (RESID) t += residX[((long)b * 64 + oo) * NP + px];
                acc[m][n][r] = t;
                Xout[((long)b * 64 + oo) * NP + px] = t;
                if constexpr (DUAL) out2[((long)b * 64 + oo) * NP + px] = t;
            }
        }

    if constexpr (M2 > 0) {
        // per-pixel LN stats (64 ch spread over m,r regs x rg lane groups)
        float muA[4], invA[4];
#pragma unroll
        for (int n = 0; n < 4; ++n) {
            float s = 0.f, s2 = 0.f;
#pragma unroll
            for (int m = 0; m < 4; ++m)
#pragma unroll
                for (int r = 0; r < 4; ++r) {
                    float t = acc[m][n][r];
                    s += t; s2 = fmaf(t, t, s2);
                }
            s += __shfl_xor(s, 16);  s += __shfl_xor(s, 32);
            s2 += __shfl_xor(s2, 16); s2 += __shfl_xor(s2, 32);
            float mu = s * (1.f / 64.f);
            float var = fmaxf(s2 * (1.f / 64.f) - mu * mu, 0.f);
            muA[n] = mu;
            invA[n] = rsqrtf(var + 1e-5f);
        }
        __syncthreads();  // all waves done reading XT
        // write normalized activations to XT [px][ch]
#pragma unroll
        for (int m = 0; m < 4; ++m)
#pragma unroll
            for (int n = 0; n < 4; ++n) {
                int pxl = wave * 64 + n * 16 + rl;
#pragma unroll
                for (int r = 0; r < 4; ++r)
                    XT[pxl][m * 16 + rg * 4 + r] = f2bf((acc[m][n][r] - muA[n]) * invA[n]);
            }
        __syncthreads();
        // second gemm: M2 channels in chunks of 64, K=64
        for (int mc = 0; mc < M2 / 64; ++mc) {
            if (mc) __syncthreads();
            {
                int o = tid >> 2, cs = (tid & 3) * 16;
                const u16* src = w2 + (long)(mc * 64 + o) * 64 + cs;
                *(ushort8_t*)&WT[o][cs] = *(const ushort8_t*)src;
                *(ushort8_t*)&WT[o][cs + 8] = *(const ushort8_t*)(src + 8);
            }
            __syncthreads();
            f32x4 a2[4][4];
#pragma unroll
            for (int m = 0; m < 4; ++m)
#pragma unroll
                for (int n = 0; n < 4; ++n) a2[m][n] = (f32x4){0.f, 0.f, 0.f, 0.f};
#pragma unroll
            for (int ks = 0; ks < 2; ++ks) {
                int kc = ks * 32 + rg * 8;
                s16x8 a[4], bb[4];
#pragma unroll
                for (int m = 0; m < 4; ++m) a[m] = *(const s16x8*)&WT[m * 16 + rl][kc];
#pragma unroll
                for (int n = 0; n < 4; ++n) bb[n] = *(const s16x8*)&XT[wave * 64 + n * 16 + rl][kc];
#pragma unroll
                for (int m = 0; m < 4; ++m)
#pragma unroll
                    for (int n = 0; n < 4; ++n)
                        a2[m][n] = __builtin_amdgcn_mfma_f32_16x16x32_bf16(a[m], bb[n], a2[m][n], 0, 0, 0);
            }
#pragma unroll
            for (int m = 0; m < 4; ++m) {
#pragma unroll
                for (int n = 0; n < 4; ++n) {
                    long px = P0 + wave * 64 + n * 16 + rl;
#pragma unroll
                    for (int r = 0; r < 4; ++r) {
                        int oo = mc * 64 + m * 16 + rg * 4 + r;
                        Yout[((long)b * 256 + oo) * NP + px] = f2bf(a2[m][n][r] + bias2[oo]);
                    }
                }
            }
        }
    }
}

// stage one LDS row (16 px) of a bf16 channel strip
__device__ __forceinline__ void stage_row(float (*S)[260], const u16* __restrict__ src,
                                          int y0, int j, int px)
{
    int row = y0 - 1 + j;
    if (row >= 0 && row < HHH) {
        ushort8_t a = *(const ushort8_t*)(src + row * WWW + px);
        ushort8_t b = *(const ushort8_t*)(src + row * WWW + px + 8);
#pragma unroll
        for (int e = 0; e < 8; ++e) { S[j][1 + px + e] = bf2f(a[e]); S[j][9 + px + e] = bf2f(b[e]); }
    } else {
#pragma unroll
        for (int e = 0; e < 16; ++e) S[j][1 + px + e] = 0.f;
    }
}
__device__ __forceinline__ float conv9(const float (*S)[260], int r, int col,
                                       const float* __restrict__ w9)
{
    float a = 0.f;
#pragma unroll
    for (int ky = 0; ky < 3; ++ky)
#pragma unroll
        for (int kx = 0; kx < 3; ++kx)
            a = fmaf(w9[ky * 3 + kx], S[r + ky][col + kx], a);
    return a;
}

// depthwise 3x3, 16-row strips. grid (16, C, nb)
__global__ __launch_bounds__(256) void dw3x3_strip(
    const u16* __restrict__ in, long inBS, const float* __restrict__ w,
    u16* __restrict__ out, long outBS)
{
    int strip = blockIdx.x, c = blockIdx.y, b = blockIdx.z;
    int y0 = strip * 16, tid = threadIdx.x;
    __shared__ float S[18][260];
    const u16* src = in + (long)b * inBS + (long)c * NP;
    int j = tid >> 4, px = (tid & 15) * 16;
    stage_row(S, src, y0, j, px);
    if (tid < 32) stage_row(S, src, y0, 16 + (tid >> 4), px);
    if (tid < 18) { S[tid][0] = 0.f; S[tid][257] = 0.f; }
    __syncthreads();
    float w9[9];
#pragma unroll
    for (int k = 0; k < 9; ++k) w9[k] = w[c * 9 + k];
    u16* dst = out + (long)b * outBS + (long)c * NP;
#pragma unroll
    for (int r = 0; r < 16; ++r)
        dst[(y0 + r) * WWW + tid] = f2bf(conv9(S, r, tid, w9));
}

// ffn: dw3x3 on (c, c+128) + gelu(y1)*y2, strips. grid (16, 128, nb)
__global__ __launch_bounds__(256) void ffn_dw_glu_strip(
    const u16* __restrict__ y, long yBS, const float* __restrict__ w,
    u16* __restrict__ g, long gBS)
{
    int strip = blockIdx.x, c = blockIdx.y, b = blockIdx.z;
    int y0 = strip * 16, tid = threadIdx.x;
    __shared__ float S1[18][260];
    __shared__ float S2[18][260];
    const u16* s1 = y + (long)b * yBS + (long)c * NP;
    const u16* s2 = y + (long)b * yBS + (long)(c + 128) * NP;
    int j = tid >> 4, px = (tid & 15) * 16;
    stage_row(S1, s1, y0, j, px);
    if (tid < 32) stage_row(S1, s1, y0, 16 + (tid >> 4), px);
    stage_row(S2, s2, y0, j, px);
    if (tid < 32) stage_row(S2, s2, y0, 16 + (tid >> 4), px);
    if (tid < 18) { S1[tid][0] = S1[tid][257] = 0.f; S2[tid][0] = S2[tid][257] = 0.f; }
    __syncthreads();
    float w1[9], w2[9];
#pragma unroll
    for (int k = 0; k < 9; ++k) { w1[k] = w[c * 9 + k]; w2[k] = w[(c + 128) * 9 + k]; }
    u16* dst = g + (long)b * gBS + (long)c * NP;
#pragma unroll
    for (int r = 0; r < 16; ++r) {
        float a1 = conv9(S1, r, tid, w1);
        float a2 = conv9(S2, r, tid, w2);
        dst[(y0 + r) * WWW + tid] = f2bf(gelu_exact(a1) * a2);
    }
}

// CIIM grouped dw conv, strips. grid (16, 64, nb)
__global__ __launch_bounds__(256) void ciim_dw_strip(
    const u16* __restrict__ fuse, long fBS, const float* __restrict__ means,
    const float* __restrict__ wdw, const float* __restrict__ bdw,
    u16* __restrict__ hl, long hlBS)
{
    int strip = blockIdx.x, c = blockIdx.y, b = blockIdx.z;
    int y0 = strip * 16, tid = threadIdx.x;
    __shared__ float S[18][260];
    float acc[16];
    float bias = bdw[c];
#pragma unroll
    for (int r = 0; r < 16; ++r) acc[r] = bias;
    for (int j6 = 0; j6 < 6; ++j6) {
        int ic = 6 * c + j6;
        const float* w9p = wdw + (c * 6 + j6) * 9;
        float w9[9];
#pragma unroll
        for (int k = 0; k < 9; ++k) w9[k] = w9p[k];
        if (ic < 128) {
            __syncthreads();
            const u16* src = fuse + (long)b * fBS + (long)ic * NP;
            int j = tid >> 4, px = (tid & 15) * 16;
            stage_row(S, src, y0, j, px);
            if (tid < 32) stage_row(S, src, y0, 16 + (tid >> 4), px);
            if (tid < 18) { S[tid][0] = 0.f; S[tid][257] = 0.f; }
            __syncthreads();
#pragma unroll
            for (int r = 0; r < 16; ++r) acc[r] += conv9(S, r, tid, w9);
        } else {
            float mv = means[b * 256 + ic - 128];
#pragma unroll
            for (int r = 0; r < 16; ++r) {
                int row = y0 + r;
                float ws = 0.f;
#pragma unroll
                for (int ky = 0; ky < 3; ++ky) {
                    int yy = row + ky - 1;
                    if (yy < 0 || yy >= HHH) continue;
#pragma unroll
                    for (int kx = 0; kx < 3; ++kx) {
                        int xx = tid + kx - 1;
                        if (xx < 0 || xx >= WWW) continue;
                        ws += w9[ky * 3 + kx];
                    }
                }
                acc[r] += mv * ws;
            }
        }
    }
    u16* dst = hl + (long)b * hlBS + (long)c * NP;
#pragma unroll
    for (int r = 0; r < 16; ++r) dst[(y0 + r) * WWW + tid] = f2bf(acc[r]);
}

// gating + concat + channel shuffle + ecam atomic. grid (64, 128, nb)
__global__ __launch_bounds__(256) void outsh4(
    const u16* __restrict__ hl, long hlBS,
    const float* __restrict__ low, long lBS,
    const float* __restrict__ high,
    u16* __restrict__ outb, long oBS,
    float* __restrict__ ecam)
{
    long p = ((long)blockIdx.x * 256 + threadIdx.x) * 4;
    int cn = blockIdx.y, b = blockIdx.z;
    int co = (cn & 31) * 4 + (cn >> 5);
    const u16* hp;
    const float* sp;
    if (co < 64) {
        hp = hl + (long)b * hlBS + (long)co * NP + p;
        sp = low + (long)b * lBS + (long)co * NP + p;
    } else {
        hp = hl + (long)b * hlBS + (long)(co - 64) * NP + p;
        sp = high + (long)b * lBS + (long)(co - 64) * NP + p;
    }
    ushort4 hu = *(const ushort4*)hp;
    float4 sv = *(const float4*)sp;
    float hv[4] = {bf2f(hu.x), bf2f(hu.y), bf2f(hu.z), bf2f(hu.w)};
    float s4[4] = {sv.x, sv.y, sv.z, sv.w};
    ushort4 ovec;
    u16* ov = (u16*)&ovec;
    float psum = 0.f;
#pragma unroll
    for (int k = 0; k < 4; ++k) {
        float gg = (co < 64) ? sigmoidf_(gelu_exact(hv[k])) : sigmoidf_(fmaxf(hv[k], 0.f));
        float val = gg * s4[k];
        ov[k] = f2bf(val);
        psum += val;
    }
    *(ushort4*)((u16*)outb + (long)b * oBS + (long)cn * NP + p) = ovec;
    // block reduce -> one atomic
    __shared__ float red[256];
    red[threadIdx.x] = psum;
    __syncthreads();
    for (int st = 128; st > 0; st >>= 1) {
        if (threadIdx.x < st) red[threadIdx.x] += red[threadIdx.x + st];
        __syncthreads();
    }
    if (threadIdx.x == 0) atomicAdd(&ecam[b * 128 + cn], red[0] * (1.f / NP));
}

// scaled rc2 weights (bf16). grid (nb*32)
__global__ __launch_bounds__(256) void rc2w_build(
    const float* __restrict__ ecam, const float* __restrict__ ecaw,
    const float* __restrict__ wrc2, u16* __restrict__ wout)
{
    int idx = blockIdx.x * 256 + threadIdx.x;
    int c = idx & 127, o = (idx >> 7) & 63, b = idx >> 13;
    float y = sigmoidf_(ecam[b * 128 + c] * ecaw[c]);
    wout[idx] = f2bf(wrc2[o * 128 + c] * y);
}

// q.k dots + sumsq norms over pixel chunks. grid (QKCH, 8, nb)
__global__ __launch_bounds__(256) void qk_dot(
    const u16* __restrict__ D, long dBS, float* __restrict__ part)
{
    int chunk = blockIdx.x, h = blockIdx.y, b = blockIdx.z;
    int tid = threadIdx.x, lane = tid & 63, wave = tid >> 6;
    const u16* q = D + (long)b * dBS + (long)(h * 8) * NP;
    const u16* k = q + 64 * NP;
    float dots[64], nq[8], nk[8];
#pragma unroll
    for (int a = 0; a < 64; ++a) dots[a] = 0.f;
#pragma unroll
    for (int a = 0; a < 8; ++a) { nq[a] = 0.f; nk[a] = 0.f; }
    long p = (long)chunk * 2048 + tid * 8;
    {
        ushort8_t qv[8], kv[8];
#pragma unroll
        for (int i = 0; i < 8; ++i) qv[i] = *(const ushort8_t*)(q + (long)i * NP + p);
#pragma unroll
        for (int i = 0; i < 8; ++i) kv[i] = *(const ushort8_t*)(k + (long)i * NP + p);
#pragma unroll
        for (int e = 0; e < 8; ++e) {
            float qe[8], ke[8];
#pragma unroll
            for (int i = 0; i < 8; ++i) { qe[i] = bf2f(qv[i][e]); ke[i] = bf2f(kv[i][e]); }
#pragma unroll
            for (int i = 0; i < 8; ++i) {
                nq[i] = fmaf(qe[i], qe[i], nq[i]);
                nk[i] = fmaf(ke[i], ke[i], nk[i]);
#pragma unroll
                for (int jj = 0; jj < 8; ++jj)
                    dots[i * 8 + jj] = fmaf(qe[i], ke[jj], dots[i * 8 + jj]);
            }
        }
    }
    __shared__ float red[4][80];
#pragma unroll
    for (int a = 0; a < 64; ++a) {
        float v = dots[a];
#pragma unroll
        for (int o = 32; o > 0; o >>= 1) v += __shfl_xor(v, o);
        if (lane == 0) red[wave][a] = v;
    }
#pragma unroll
    for (int a = 0; a < 8; ++a) {
        float v1 = nq[a], v2 = nk[a];
#pragma unroll
        for (int o = 32; o > 0; o >>= 1) { v1 += __shfl_xor(v1, o); v2 += __shfl_xor(v2, o); }
        if (lane == 0) { red[wave][64 + a] = v1; red[wave][72 + a] = v2; }
    }
    __syncthreads();
    if (tid < 80) {
        float v = red[0][tid] + red[1][tid] + red[2][tid] + red[3][tid];
        part[(((long)b * 8 + h) * 80 + tid) * QKCH + chunk] = v;
    }
}

// head: conv1 (MFMA, overlapping 16x16 H tiles, stride 14) + leaky
// + conv2 (32->1) on 14x14 interior + inp + sigmoid. grid (19, 19, nb)
__global__ __launch_bounds__(256) void head_fused(
    const float* __restrict__ X, const u16* __restrict__ wtap,
    const float* __restrict__ wh2, const float* __restrict__ inp,
    float* __restrict__ out)
{
    __shared__ u16 P[18][18][72] __attribute__((aligned(16)));
    __shared__ u16 Hl[16][16][40] __attribute__((aligned(16)));
    __shared__ float w2t[288];
    int ty = blockIdx.x, tx = blockIdx.y, b = blockIdx.z;
    int tid = threadIdx.x, lane = tid & 63, wave = tid >> 6;
    int rl = lane & 15, rg = lane >> 4;
    int oy = ty * 14 - 2, ox = tx * 14 - 2;  // patch origin
    for (int idx = tid; idx < 288; idx += 256)
        w2t[(idx % 9) * 32 + idx / 9] = wh2[idx];
    {
        int lane5 = tid & 31;
        int cbase = tid >> 5;
#pragma unroll
        for (int cg = 0; cg < 8; ++cg) {
            int c = cg * 8 + cbase;
            const float* src = X + ((long)b * 64 + c) * NP;
            for (int it = 0; it < 11; ++it) {
                int px = lane5 + it * 32;
                if (px < 324) {
                    int row = px / 18, col = px % 18;
                    int gy = oy + row, gx = ox + col;
                    float v = (gy >= 0 && gy < HHH && gx >= 0 && gx < WWW)
                                  ? src[gy * WWW + gx] : 0.f;
                    P[row][col][c] = f2bf(v);
                }
            }
        }
    }
    __syncthreads();
    f32x4 acc[2][4];
#pragma unroll
    for (int m = 0; m < 2; ++m)
#pragma unroll
        for (int n = 0; n < 4; ++n) acc[m][n] = (f32x4){0.f, 0.f, 0.f, 0.f};
#pragma unroll
    for (int tap = 0; tap < 9; ++tap) {
        int ky = tap / 3, kx = tap % 3;
#pragma unroll
        for (int ks = 0; ks < 2; ++ks) {
            int kc = ks * 32 + rg * 8;
            s16x8 a0 = *(const s16x8*)(wtap + tap * 2048 + (long)(0 + rl) * 64 + kc);
            s16x8 a1 = *(const s16x8*)(wtap + tap * 2048 + (long)(16 + rl) * 64 + kc);
#pragma unroll
            for (int n = 0; n < 4; ++n) {
                int py = wave * 4 + n;
                s16x8 bb = *(const s16x8*)&P[py + ky][kx + rl][kc];
                acc[0][n] = __builtin_amdgcn_mfma_f32_16x16x32_bf16(a0, bb, acc[0][n], 0, 0, 0);
                acc[1][n] = __builtin_amdgcn_mfma_f32_16x16x32_bf16(a1, bb, acc[1][n], 0, 0, 0);
            }
        }
    }
    // H tile (leaky), zero outside image
#pragma unroll
    for (int m = 0; m < 2; ++m)
#pragma unroll
        for (int n = 0; n < 4; ++n) {
            int py = wave * 4 + n;
            int gy = ty * 14 - 1 + py, gx = tx * 14 - 1 + rl;
            bool ok = (gy >= 0 && gy < HHH && gx >= 0 && gx < WWW);
#pragma unroll
            for (int r = 0; r < 4; ++r) {
                int o = m * 16 + rg * 4 + r;
                float v = acc[m][n][r];
                v = v > 0.f ? v : 0.01f * v;
                Hl[py][rl][o] = ok ? f2bf(v) : (u16)0;
            }
        }
    __syncthreads();
    // conv2 on 14x14 interior
    if (tid < 196) {
        int r = tid / 14, c = tid % 14;
        int gy = ty * 14 + r, gx = tx * 14 + c;
        if (gy < HHH && gx < WWW) {
            float acc2 = 0.f;
#pragma unroll
            for (int tap = 0; tap < 9; ++tap) {
                int hy = r + tap / 3, hx = c + tap % 3;
#pragma unroll
                for (int cg = 0; cg < 4; ++cg) {
                    ushort8_t hv = *(const ushort8_t*)&Hl[hy][hx][cg * 8];
#pragma unroll
                    for (int e = 0; e < 8; ++e)
                        acc2 = fmaf(w2t[tap * 32 + cg * 8 + e], bf2f(hv[e]), acc2);
                }
            }
            float v = acc2 + inp[(long)b * NP + gy * WWW + gx];
            out[(long)b * NP + gy * WWW + gx] = 1.f / (1.f + expf(-v));
        }
    }
}

// ---------------------------------------------------------------------------
extern "C" void kernel_launch(void* const* d_in, const int* in_sizes, int n_in,
                              void* d_out, int out_size, void* d_ws, size_t ws_size,
                              hipStream_t stream)
{
    const float* inp    = (const float*)d_in[0];
    const float* base   = (const float*)d_in[1];
    const float* detail = (const float*)d_in[2];
    const float* w_ir   = (const float*)d_in[3];
    const float* w_vi   = (const float*)d_in[4];
    const float* w_fu   = (const float*)d_in[5];
    const float* b_fu   = (const float*)d_in[6];
    const float* w_dwc  = (const float*)d_in[7];
    const float* b_dwc  = (const float*)d_in[8];
    const float* eca_w  = (const float*)d_in[9];
    const float* w_rc2  = (const float*)d_in[10];
    const float* ln1w   = (const float*)d_in[11];
    const float* ln1b   = (const float*)d_in[12];
    const float* w_qkv  = (const float*)d_in[13];
    const float* w_qdw  = (const float*)d_in[14];
    const float* temp   = (const float*)d_in[15];
    const float* w_proj = (const float*)d_in[16];
    const float* ln2w   = (const float*)d_in[17];
    const float* ln2b   = (const float*)d_in[18];
    const float* w_in_  = (const float*)d_in[19];
    const float* w_fdw  = (const float*)d_in[20];
    const float* w_out_ = (const float*)d_in[21];
    const float* w_h1   = (const float*)d_in[22];
    const float* w_h2   = (const float*)d_in[23];

    float* out = (float*)d_out;

    auto needB = [&](long nb) -> size_t {
        return (size_t)nb * NP * (64 * 4 + 256 * 2 + 192 * 2) + (16u << 20);
    };
    int bInner;
    if (ws_size >= needB(4)) bInner = 4;
    else if (ws_size >= needB(1)) bInner = 1;
    else {
        diag_kernel<<<1, 64, 0, stream>>>(out, (float)(ws_size >> 20));
        return;
    }
    const long nb = bInner;

    char* p = (char*)d_ws;
    auto alloc = [&](size_t bytes) -> char* {
        char* r = p; p += (bytes + 255) & ~(size_t)255; return r;
    };
    float* X      = (float*)alloc((size_t)nb * 64 * NP * 4);
    u16*   Y      = (u16*)alloc((size_t)nb * 256 * NP * 2);
    u16*   Dq     = (u16*)alloc((size_t)nb * 192 * NP * 2);
    float* part   = (float*)alloc((size_t)nb * 8 * 80 * QKCH * 4);
    float* means  = (float*)alloc((size_t)nb * 384 * 4);   // means[256] + ecam[128] per b
    float* ecam   = means + nb * 256;
    u16*   rc2wb  = (u16*)alloc((size_t)nb * 8192 * 2);
    u16*   fq_bf  = (u16*)alloc((size_t)4 * 192 * 64 * 2);
    float* fqB    = (float*)alloc((size_t)4 * 192 * 4);
    u16*   ff_bf  = (u16*)alloc((size_t)4 * 256 * 64 * 2);
    float* ffB    = (float*)alloc((size_t)4 * 256 * 4);
    u16*   wir_bf = (u16*)alloc(8192 * 2);
    u16*   wvi_bf = (u16*)alloc(8192 * 2);
    u16*   wfu_bf = (u16*)alloc(32768 * 2);
    u16*   wout_bf= (u16*)alloc(32768 * 2);
    u16*   wtap   = (u16*)alloc(9 * 2048 * 2);

    dim3 blk(256);

    fold_ln<<<dim3(28), dim3(64), 0, stream>>>(w_qkv, ln1w, ln1b, w_in_, ln2w, ln2b,
                                               fq_bf, fqB, ff_bf, ffB);
    prep_misc<<<dim3(89), blk, 0, stream>>>(w_ir, w_vi, w_fu, w_out_, w_h1,
                                            wir_bf, wvi_bf, wfu_bf, wout_bf, wtap);

    for (int b0 = 0; b0 < 4; b0 += bInner) {
        const float* inpB    = inp + (long)b0 * NP;
        const float* baseB   = base + (long)b0 * 64 * NP;
        const float* detailB = detail + (long)b0 * 64 * NP;
        float* out0  = out + (long)b0 * NP;
        float* outX0 = out + 262144 + (long)b0 * 64 * NP;

        // ---- CIIM ----
        hipMemsetAsync(means, 0, (size_t)nb * 384 * 4, stream);
        gemm_irvi<<<dim3(4, 256, nb), blk, 0, stream>>>(
            baseB, detailB, wir_bf, wvi_bf, Y, means);
        gemm_plain<<<dim3(2, 256, nb), blk, 0, stream>>>(
            Y, 256 * NP, wfu_bf, b_fu, Dq, 192 * NP, 256);
        ciim_dw_strip<<<dim3(16, 64, nb), blk, 0, stream>>>(
            Dq, 192 * NP, means, w_dwc, b_dwc, Dq + 128 * NP, 192 * NP);
        outsh4<<<dim3(64, 128, nb), blk, 0, stream>>>(
            Dq + 128 * NP, 192 * NP, baseB, 64 * NP, detailB, Y, 256 * NP, ecam);
        rc2w_build<<<dim3(nb * 32), blk, 0, stream>>>(ecam, eca_w, w_rc2, rc2wb);
        // rc2 gemm (dual->outX0) + LN + qkv gemm (block 0)
        gemm_fused<0, 0, 1, 192><<<dim3(256, 1, nb), blk, 0, stream>>>(
            Y, 256 * NP, rc2wb, 8192, nullptr, X, outX0,
            fq_bf, fqB, Y, nullptr, nullptr, nullptr, 128);

        // ---- transformer blocks ----
        for (int i = 0; i < 4; ++i) {
            dw3x3_strip<<<dim3(16, 192, nb), blk, 0, stream>>>(
                Y, 256 * NP, w_qdw + (long)i * 192 * 9, Dq, 192 * NP);
            qk_dot<<<dim3(QKCH, 8, nb), blk, 0, stream>>>(Dq, 192 * NP, part);
            // pv gemm (weff prologue, resid X) + LN + ffn-in gemm
            gemm_fused<1, 1, 0, 256><<<dim3(256, 1, nb), blk, 0, stream>>>(
                Dq + 128 * NP, 192 * NP, nullptr, 0, X, X, nullptr,
                ff_bf + (long)i * 256 * 64, ffB + i * 256, Y,
                part, temp + i * 8, w_proj + (long)i * 4096, 64);
            ffn_dw_glu_strip<<<dim3(16, 128, nb), blk, 0, stream>>>(
                Y, 256 * NP, w_fdw + (long)i * 256 * 9, Dq, 192 * NP);
            if (i < 3) {
                // ffn-out gemm (resid X) + LN + next block's qkv gemm
                gemm_fused<0, 1, 0, 192><<<dim3(256, 1, nb), blk, 0, stream>>>(
                    Dq, 192 * NP, wout_bf + (long)i * 8192, 0, X, X, nullptr,
                    fq_bf + (long)(i + 1) * 192 * 64, fqB + (i + 1) * 192, Y,
                    nullptr, nullptr, nullptr, 128);
            } else {
                gemm_fused<0, 1, 0, 0><<<dim3(256, 1, nb), blk, 0, stream>>>(
                    Dq, 192 * NP, wout_bf + (long)i * 8192, 0, X, X, nullptr,
                    nullptr, nullptr, nullptr, nullptr, nullptr, nullptr, 128);
            }
        }

        // ---- head ----
        head_fused<<<dim3(19, 19, nb), blk, 0, stream>>>(X, wtap, w_h2, inpB, out0);
    }
}

// Round 11
// 2449.311 us; speedup vs baseline: 1.4184x; 1.0172x over previous
//
#include <hip/hip_runtime.h>
#include <hip/hip_bf16.h>
#include <math.h>

#define NP 65536L
#define HHH 256
#define WWW 256
#define QKCH 32

typedef unsigned short u16;
typedef unsigned short ushort8_t __attribute__((ext_vector_type(8)));
typedef short s16x8 __attribute__((ext_vector_type(8)));
typedef float f32x4 __attribute__((ext_vector_type(4)));

__device__ __forceinline__ float bf2f(u16 u) { return __uint_as_float(((unsigned)u) << 16); }
__device__ __forceinline__ u16 f2bf(float f) {
    __hip_bfloat16 h = __float2bfloat16(f);
    return *reinterpret_cast<u16*>(&h);
}
__device__ __forceinline__ float sigmoidf_(float x) { return 1.f / (1.f + __expf(-x)); }
__device__ __forceinline__ float gelu_exact(float x) {
    return 0.5f * x * (1.f + erff(x * 0.70710678118654752f));
}

__global__ void diag_kernel(float* out, float v) {
    if (threadIdx.x == 0 && blockIdx.x == 0) out[0] = v;
}

// one-shot weight prep: bf16 casts of 4 weight tensors + wtap rearrange.
__global__ __launch_bounds__(256) void prep_misc(
    const float* __restrict__ wir, const float* __restrict__ wvi,
    const float* __restrict__ wfu, const float* __restrict__ wout,
    const float* __restrict__ wh1,
    u16* __restrict__ dir, u16* __restrict__ dvi,
    u16* __restrict__ dfu, u16* __restrict__ dout,
    u16* __restrict__ wtap)
{
    int bid = blockIdx.x;
    if (bid < 80) {
        long e = (long)bid * 1024 + threadIdx.x * 4;
        const float* src; u16* dst; long off;
        if (e < 8192)       { src = wir;  dst = dir;  off = 0; }
        else if (e < 16384) { src = wvi;  dst = dvi;  off = 8192; }
        else if (e < 49152) { src = wfu;  dst = dfu;  off = 16384; }
        else                { src = wout; dst = dout; off = 49152; }
        long i = e - off;
        float4 v = *(const float4*)(src + i);
        ushort4 o;
        o.x = f2bf(v.x); o.y = f2bf(v.y); o.z = f2bf(v.z); o.w = f2bf(v.w);
        *(ushort4*)(dst + i) = o;
    } else {
        int tap = bid - 80;
        for (int e = threadIdx.x; e < 2048; e += 256)
            wtap[tap * 2048 + e] = f2bf(wh1[(long)e * 9 + tap]);
    }
}

// fold LN gamma/beta into qkv / ffn-in weights; bf16 weights + fp32 bias.
__global__ void fold_ln(
    const float* __restrict__ wqkv, const float* __restrict__ ln1w, const float* __restrict__ ln1b,
    const float* __restrict__ win,  const float* __restrict__ ln2w, const float* __restrict__ ln2b,
    u16* __restrict__ fq, float* __restrict__ fqB,
    u16* __restrict__ ff, float* __restrict__ ffB)
{
    int g = blockIdx.x;
    int i = g / 7, r = g % 7;
    const float *wsrc, *lg, *lb;
    u16* wd; float* Bd;
    int obase;
    if (r < 3) {
        wsrc = wqkv + (long)i * 192 * 64; lg = ln1w + i * 64; lb = ln1b + i * 64;
        wd = fq + (long)i * 192 * 64; Bd = fqB + i * 192; obase = r * 64;
    } else {
        wsrc = win + (long)i * 256 * 64; lg = ln2w + i * 64; lb = ln2b + i * 64;
        wd = ff + (long)i * 256 * 64; Bd = ffB + i * 256; obase = (r - 3) * 64;
    }
    int o = obase + threadIdx.x;
    float Bv = 0.f;
    for (int c = 0; c < 64; ++c) {
        float wv = wsrc[(long)o * 64 + c];
        wd[(long)o * 64 + c] = f2bf(wv * lg[c]);
        Bv += wv * lb[c];
    }
    Bd[o] = Bv;
}

// ---------------------------------------------------------------------------
// CIIM input GEMMs (ir + vi in one dispatch) + fused per-channel means atomic.
// grid (4, 256, nb). 256-px tiles (not the hot kernel).
// ---------------------------------------------------------------------------
__global__ __launch_bounds__(256) void gemm_irvi(
    const float* __restrict__ base, const float* __restrict__ detail,
    const u16* __restrict__ wir, const u16* __restrict__ wvi,
    u16* __restrict__ Y, float* __restrict__ means)
{
    __shared__ u16 XT[256][72];
    __shared__ u16 WT[64][72];
    __shared__ float red[4][64];
    int xsel = blockIdx.x, b = blockIdx.z;
    long P0 = (long)blockIdx.y * 256;
    int tid = threadIdx.x, lane = tid & 63, wave = tid >> 6;
    int rl = lane & 15, rg = lane >> 4;
    const float* in = ((xsel < 2) ? base : detail) + (long)b * 64 * NP;
    const u16* wsel = (xsel < 2) ? wir : wvi;
    int orow0 = (xsel & 1) * 64;
    int ochan0 = xsel * 64;

    {
        int o = tid >> 2, cs = (tid & 3) * 16;
        const u16* src = wsel + (long)(orow0 + o) * 64 + cs;
        *(ushort8_t*)&WT[o][cs] = *(const ushort8_t*)src;
        *(ushort8_t*)&WT[o][cs + 8] = *(const ushort8_t*)(src + 8);
    }
    {
        int c0 = (tid & 7) * 8;
        int pt = (tid >> 3) * 8;
        u16 rr[8][8];
#pragma unroll
        for (int i = 0; i < 8; ++i) {
            const float* sp = in + (long)(c0 + i) * NP + P0 + pt;
            float4 a = *(const float4*)sp;
            float4 b4 = *(const float4*)(sp + 4);
            rr[i][0] = f2bf(a.x); rr[i][1] = f2bf(a.y);
            rr[i][2] = f2bf(a.z); rr[i][3] = f2bf(a.w);
            rr[i][4] = f2bf(b4.x); rr[i][5] = f2bf(b4.y);
            rr[i][6] = f2bf(b4.z); rr[i][7] = f2bf(b4.w);
        }
#pragma unroll
        for (int j = 0; j < 8; ++j) {
            ushort8_t v;
#pragma unroll
            for (int i = 0; i < 8; ++i) v[i] = rr[i][j];
            *(ushort8_t*)&XT[pt + j][c0] = v;
        }
    }
    __syncthreads();
    f32x4 acc[4][4];
#pragma unroll
    for (int m = 0; m < 4; ++m)
#pragma unroll
        for (int n = 0; n < 4; ++n) acc[m][n] = (f32x4){0.f, 0.f, 0.f, 0.f};
#pragma unroll
    for (int ks = 0; ks < 2; ++ks) {
        int kc = ks * 32 + rg * 8;
        s16x8 a[4], bb[4];
#pragma unroll
        for (int m = 0; m < 4; ++m) a[m] = *(const s16x8*)&WT[m * 16 + rl][kc];
#pragma unroll
        for (int n = 0; n < 4; ++n) bb[n] = *(const s16x8*)&XT[wave * 64 + n * 16 + rl][kc];
#pragma unroll
        for (int m = 0; m < 4; ++m)
#pragma unroll
            for (int n = 0; n < 4; ++n)
                acc[m][n] = __builtin_amdgcn_mfma_f32_16x16x32_bf16(a[m], bb[n], acc[m][n], 0, 0, 0);
    }
    float csum[4][4];
#pragma unroll
    for (int m = 0; m < 4; ++m)
#pragma unroll
        for (int r = 0; r < 4; ++r) csum[m][r] = 0.f;
#pragma unroll
    for (int m = 0; m < 4; ++m)
#pragma unroll
        for (int n = 0; n < 4; ++n) {
            long px = P0 + wave * 64 + n * 16 + rl;
#pragma unroll
            for (int r = 0; r < 4; ++r) {
                int oo = ochan0 + m * 16 + rg * 4 + r;
                float v = acc[m][n][r];
                Y[((long)b * 256 + oo) * NP + px] = f2bf(v);
                csum[m][r] += v;
            }
        }
#pragma unroll
    for (int m = 0; m < 4; ++m)
#pragma unroll
        for (int r = 0; r < 4; ++r) {
            float s = csum[m][r];
            s += __shfl_xor(s, 1); s += __shfl_xor(s, 2);
            s += __shfl_xor(s, 4); s += __shfl_xor(s, 8);
            if (rl == 0) red[wave][m * 16 + rg * 4 + r] = s;
        }
    __syncthreads();
    if (tid < 64) {
        float v = red[0][tid] + red[1][tid] + red[2][tid] + red[3][tid];
        atomicAdd(&means[b * 256 + ochan0 + tid], v * (1.f / NP));
    }
}

// plain MFMA GEMM (fuse conv). grid (Cout/64, 256, nb)
__global__ __launch_bounds__(256) void gemm_plain(
    const u16* __restrict__ in, long inBS,
    const u16* __restrict__ wbf,
    const float* __restrict__ bias,
    u16* __restrict__ outp, long outBS, int Cin)
{
    __shared__ u16 XT[256][72];
    __shared__ u16 WT[64][72];
    int b = blockIdx.z;
    int oBase = blockIdx.x * 64;
    long P0 = (long)blockIdx.y * 256;
    int tid = threadIdx.x, lane = tid & 63, wave = tid >> 6;
    int rl = lane & 15, rg = lane >> 4;
    const u16* inB = in + (long)b * inBS;
    f32x4 acc[4][4];
#pragma unroll
    for (int m = 0; m < 4; ++m)
#pragma unroll
        for (int n = 0; n < 4; ++n) acc[m][n] = (f32x4){0.f, 0.f, 0.f, 0.f};
    for (int ck = 0; ck < Cin; ck += 64) {
        if (ck) __syncthreads();
        {
            int o = tid >> 2, cs = (tid & 3) * 16;
            const u16* src = wbf + (long)(oBase + o) * Cin + ck + cs;
            *(ushort8_t*)&WT[o][cs] = *(const ushort8_t*)src;
            *(ushort8_t*)&WT[o][cs + 8] = *(const ushort8_t*)(src + 8);
        }
        {
            int c0 = (tid & 7) * 8;
            int pt = (tid >> 3) * 8;
            ushort8_t r[8];
#pragma unroll
            for (int i = 0; i < 8; ++i)
                r[i] = *(const ushort8_t*)(inB + (long)(ck + c0 + i) * NP + P0 + pt);
#pragma unroll
            for (int j = 0; j < 8; ++j) {
                ushort8_t v;
#pragma unroll
                for (int i = 0; i < 8; ++i) v[i] = r[i][j];
                *(ushort8_t*)&XT[pt + j][c0] = v;
            }
        }
        __syncthreads();
#pragma unroll
        for (int ks = 0; ks < 2; ++ks) {
            int kc = ks * 32 + rg * 8;
            s16x8 a[4], bb[4];
#pragma unroll
            for (int m = 0; m < 4; ++m) a[m] = *(const s16x8*)&WT[m * 16 + rl][kc];
#pragma unroll
            for (int n = 0; n < 4; ++n) bb[n] = *(const s16x8*)&XT[wave * 64 + n * 16 + rl][kc];
#pragma unroll
            for (int m = 0; m < 4; ++m)
#pragma unroll
                for (int n = 0; n < 4; ++n)
                    acc[m][n] = __builtin_amdgcn_mfma_f32_16x16x32_bf16(a[m], bb[n], acc[m][n], 0, 0, 0);
        }
    }
#pragma unroll
    for (int m = 0; m < 4; ++m) {
#pragma unroll
        for (int n = 0; n < 4; ++n) {
            long px = P0 + wave * 64 + n * 16 + rl;
#pragma unroll
            for (int r = 0; r < 4; ++r) {
                int oo = oBase + m * 16 + rg * 4 + r;
                outp[(long)b * outBS + (long)oo * NP + px] = f2bf(acc[m][n][r] + bias[oo]);
            }
        }
    }
}

// ---------------------------------------------------------------------------
// Fused GEMM -> X(bf16) -> LN -> LDS -> second GEMM -> Y(bf16).
// 128-px tiles for occupancy (27KB LDS -> 5 blocks/CU). grid (512, 1, nb).
// ---------------------------------------------------------------------------
template<int WEFF, int RESID, int DUAL, int M2>
__global__ __launch_bounds__(256) void gemm_fused(
    const u16* __restrict__ in, long inBS,
    const u16* __restrict__ w1, long w1BS,
    const u16* __restrict__ residX,
    u16* __restrict__ Xout,
    float* __restrict__ out2,
    const u16* __restrict__ w2, const float* __restrict__ bias2,
    u16* __restrict__ Yout,
    const float* __restrict__ part, const float* __restrict__ temp,
    const float* __restrict__ wproj,
    int Cin)
{
    __shared__ u16 XT[128][72] __attribute__((aligned(16)));
    __shared__ u16 WT[64][72] __attribute__((aligned(16)));
    int b = blockIdx.z;
    long P0 = (long)blockIdx.x * 128;
    int tid = threadIdx.x, lane = tid & 63, wave = tid >> 6;
    int rl = lane & 15, rg = lane >> 4;
    const u16* inB = in + (long)b * inBS;

    if constexpr (WEFF) {
        float* SgF = (float*)&XT[0][0];
        float* attF = SgF + 640;
        for (int e = tid; e < 640; e += 256) {
            int h = e / 80, k = e % 80;
            const float* pp = part + (((long)b * 8 + h) * 80 + k) * QKCH;
            float s = 0.f;
#pragma unroll
            for (int c = 0; c < QKCH; ++c) s += pp[c];
            SgF[e] = s;
        }
        __syncthreads();
        if (tid < 64) {
            int h = tid >> 3, iq = tid & 7;
            float nqv = fmaxf(sqrtf(SgF[h * 80 + 64 + iq]), 1e-12f);
            float tp = temp[h];
            float row[8], mx = -1e30f;
#pragma unroll
            for (int jj = 0; jj < 8; ++jj) {
                float nkv = fmaxf(sqrtf(SgF[h * 80 + 72 + jj]), 1e-12f);
                row[jj] = SgF[h * 80 + iq * 8 + jj] / (nqv * nkv) * tp;
                mx = fmaxf(mx, row[jj]);
            }
            float sum = 0.f;
#pragma unroll
            for (int jj = 0; jj < 8; ++jj) { row[jj] = __expf(row[jj] - mx); sum += row[jj]; }
            float rinv = 1.f / sum;
#pragma unroll
            for (int jj = 0; jj < 8; ++jj) attF[(h * 8 + iq) * 8 + jj] = row[jj] * rinv;
        }
        __syncthreads();
        {
            int o = tid >> 2;
            int cv0 = (tid & 3) * 16;
#pragma unroll
            for (int cv = 0; cv < 16; ++cv) {
                int c = cv0 + cv;
                int h = c >> 3, jj = c & 7;
                float s = 0.f;
#pragma unroll
                for (int i = 0; i < 8; ++i)
                    s = fmaf(wproj[o * 64 + h * 8 + i], attF[(h * 8 + i) * 8 + jj], s);
                WT[o][c] = f2bf(s);
            }
        }
        __syncthreads();
    }

    f32x4 acc[4][2];
#pragma unroll
    for (int m = 0; m < 4; ++m)
#pragma unroll
        for (int n = 0; n < 2; ++n) acc[m][n] = (f32x4){0.f, 0.f, 0.f, 0.f};

    for (int ck = 0; ck < Cin; ck += 64) {
        if (ck) __syncthreads();
        if constexpr (!WEFF) {
            int o = tid >> 2, cs = (tid & 3) * 16;
            const u16* src = w1 + (long)b * w1BS + (long)o * Cin + ck + cs;
            *(ushort8_t*)&WT[o][cs] = *(const ushort8_t*)src;
            *(ushort8_t*)&WT[o][cs + 8] = *(const ushort8_t*)(src + 8);
        }
        if (tid < 128) {   // stage X chunk transposed: [128 px][64 c]
            int c0 = (tid & 7) * 8;
            int pt = (tid >> 3) * 8;
            ushort8_t r[8];
#pragma unroll
            for (int i = 0; i < 8; ++i)
                r[i] = *(const ushort8_t*)(inB + (long)(ck + c0 + i) * NP + P0 + pt);
#pragma unroll
            for (int j = 0; j < 8; ++j) {
                ushort8_t v;
#pragma unroll
                for (int i = 0; i < 8; ++i) v[i] = r[i][j];
                *(ushort8_t*)&XT[pt + j][c0] = v;
            }
        }
        __syncthreads();
#pragma unroll
        for (int ks = 0; ks < 2; ++ks) {
            int kc = ks * 32 + rg * 8;
            s16x8 a[4], bb[2];
#pragma unroll
            for (int m = 0; m < 4; ++m) a[m] = *(const s16x8*)&WT[m * 16 + rl][kc];
#pragma unroll
            for (int n = 0; n < 2; ++n) bb[n] = *(const s16x8*)&XT[wave * 32 + n * 16 + rl][kc];
#pragma unroll
            for (int m = 0; m < 4; ++m)
#pragma unroll
                for (int n = 0; n < 2; ++n)
                    acc[m][n] = __builtin_amdgcn_mfma_f32_16x16x32_bf16(a[m], bb[n], acc[m][n], 0, 0, 0);
        }
    }

    // epilogue 1: resid + X store (bf16) (+dual fp32)
#pragma unroll
    for (int m = 0; m < 4; ++m)
#pragma unroll
        for (int n = 0; n < 2; ++n) {
            long px = P0 + wave * 32 + n * 16 + rl;
#pragma unroll
            for (int r = 0; r < 4; ++r) {
                int oo = m * 16 + rg * 4 + r;
                float t = acc[m][n][r];
                if constexpr (RESID) t += bf2f(residX[((long)b * 64 + oo) * NP + px]);
                acc[m][n][r] = t;
                Xout[((long)b * 64 + oo) * NP + px] = f2bf(t);
                if constexpr (DUAL) out2[((long)b * 64 + oo) * NP + px] = t;
            }
        }

    if constexpr (M2 > 0) {
        float muA[2], invA[2];
#pragma unroll
        for (int n = 0; n < 2; ++n) {
            float s = 0.f, s2 = 0.f;
#pragma unroll
            for (int m = 0; m < 4; ++m)
#pragma unroll
                for (int r = 0; r < 4; ++r) {
                    float t = acc[m][n][r];
                    s += t; s2 = fmaf(t, t, s2);
                }
            s += __shfl_xor(s, 16);  s += __shfl_xor(s, 32);
            s2 += __shfl_xor(s2, 16); s2 += __shfl_xor(s2, 32);
            float mu = s * (1.f / 64.f);
            float var = fmaxf(s2 * (1.f / 64.f) - mu * mu, 0.f);
            muA[n] = mu;
            invA[n] = rsqrtf(var + 1e-5f);
        }
        __syncthreads();
#pragma unroll
        for (int m = 0; m < 4; ++m)
#pragma unroll
            for (int n = 0; n < 2; ++n) {
                int pxl = wave * 32 + n * 16 + rl;
#pragma unroll
                for (int r = 0; r < 4; ++r)
                    XT[pxl][m * 16 + rg * 4 + r] = f2bf((acc[m][n][r] - muA[n]) * invA[n]);
            }
        __syncthreads();
        for (int mc = 0; mc < M2 / 64; ++mc) {
            if (mc) __syncthreads();
            {
                int o = tid >> 2, cs = (tid & 3) * 16;
                const u16* src = w2 + (long)(mc * 64 + o) * 64 + cs;
                *(ushort8_t*)&WT[o][cs] = *(const ushort8_t*)src;
                *(ushort8_t*)&WT[o][cs + 8] = *(const ushort8_t*)(src + 8);
            }
            __syncthreads();
            f32x4 a2[4][2];
#pragma unroll
            for (int m = 0; m < 4; ++m)
#pragma unroll
                for (int n = 0; n < 2; ++n) a2[m][n] = (f32x4){0.f, 0.f, 0.f, 0.f};
#pragma unroll
            for (int ks = 0; ks < 2; ++ks) {
                int kc = ks * 32 + rg * 8;
                s16x8 a[4], bb[2];
#pragma unroll
                for (int m = 0; m < 4; ++m) a[m] = *(const s16x8*)&WT[m * 16 + rl][kc];
#pragma unroll
                for (int n = 0; n < 2; ++n) bb[n] = *(const s16x8*)&XT[wave * 32 + n * 16 + rl][kc];
#pragma unroll
                for (int m = 0; m < 4; ++m)
#pragma unroll
                    for (int n = 0; n < 2; ++n)
                        a2[m][n] = __builtin_amdgcn_mfma_f32_16x16x32_bf16(a[m], bb[n], a2[m][n], 0, 0, 0);
            }
#pragma unroll
            for (int m = 0; m < 4; ++m) {
#pragma unroll
                for (int n = 0; n < 2; ++n) {
                    long px = P0 + wave * 32 + n * 16 + rl;
#pragma unroll
                    for (int r = 0; r < 4; ++r) {
                        int oo = mc * 64 + m * 16 + rg * 4 + r;
                        Yout[((long)b * 256 + oo) * NP + px] = f2bf(a2[m][n][r] + bias2[oo]);
                    }
                }
            }
        }
    }
}

// stage one LDS row (16 px) of a bf16 channel strip
__device__ __forceinline__ void stage_row(float (*S)[260], const u16* __restrict__ src,
                                          int y0, int j, int px)
{
    int row = y0 - 1 + j;
    if (row >= 0 && row < HHH) {
        ushort8_t a = *(const ushort8_t*)(src + row * WWW + px);
        ushort8_t b = *(const ushort8_t*)(src + row * WWW + px + 8);
#pragma unroll
        for (int e = 0; e < 8; ++e) { S[j][1 + px + e] = bf2f(a[e]); S[j][9 + px + e] = bf2f(b[e]); }
    } else {
#pragma unroll
        for (int e = 0; e < 16; ++e) S[j][1 + px + e] = 0.f;
    }
}
__device__ __forceinline__ float conv9(const float (*S)[260], int r, int col,
                                       const float* __restrict__ w9)
{
    float a = 0.f;
#pragma unroll
    for (int ky = 0; ky < 3; ++ky)
#pragma unroll
        for (int kx = 0; kx < 3; ++kx)
            a = fmaf(w9[ky * 3 + kx], S[r + ky][col + kx], a);
    return a;
}

// depthwise 3x3, 16-row strips, vectorized 4px x 4row stores. grid (16, C, nb)
__global__ __launch_bounds__(256) void dw3x3_strip(
    const u16* __restrict__ in, long inBS, const float* __restrict__ w,
    u16* __restrict__ out, long outBS)
{
    int strip = blockIdx.x, c = blockIdx.y, b = blockIdx.z;
    int y0 = strip * 16, tid = threadIdx.x;
    __shared__ float S[18][260];
    const u16* src = in + (long)b * inBS + (long)c * NP;
    int j = tid >> 4, px = (tid & 15) * 16;
    stage_row(S, src, y0, j, px);
    if (tid < 32) stage_row(S, src, y0, 16 + (tid >> 4), px);
    if (tid < 18) { S[tid][0] = 0.f; S[tid][257] = 0.f; }
    __syncthreads();
    float w9[9];
#pragma unroll
    for (int k = 0; k < 9; ++k) w9[k] = w[c * 9 + k];
    u16* dst = out + (long)b * outBS + (long)c * NP;
    int px4 = (tid & 63) * 4;
    int r0 = (tid >> 6) * 4;
#pragma unroll
    for (int r = 0; r < 4; ++r) {
        int row = r0 + r;
        ushort4 ovec;
        u16* ov = (u16*)&ovec;
#pragma unroll
        for (int e = 0; e < 4; ++e) ov[e] = f2bf(conv9(S, row, px4 + e, w9));
        *(ushort4*)&dst[(y0 + row) * WWW + px4] = ovec;
    }
}

// ffn: dw3x3 on (c, c+128) + gelu(y1)*y2, strips, vectorized. grid (16, 128, nb)
__global__ __launch_bounds__(256) void ffn_dw_glu_strip(
    const u16* __restrict__ y, long yBS, const float* __restrict__ w,
    u16* __restrict__ g, long gBS)
{
    int strip = blockIdx.x, c = blockIdx.y, b = blockIdx.z;
    int y0 = strip * 16, tid = threadIdx.x;
    __shared__ float S1[18][260];
    __shared__ float S2[18][260];
    const u16* s1 = y + (long)b * yBS + (long)c * NP;
    const u16* s2 = y + (long)b * yBS + (long)(c + 128) * NP;
    int j = tid >> 4, px = (tid & 15) * 16;
    stage_row(S1, s1, y0, j, px);
    if (tid < 32) stage_row(S1, s1, y0, 16 + (tid >> 4), px);
    stage_row(S2, s2, y0, j, px);
    if (tid < 32) stage_row(S2, s2, y0, 16 + (tid >> 4), px);
    if (tid < 18) { S1[tid][0] = S1[tid][257] = 0.f; S2[tid][0] = S2[tid][257] = 0.f; }
    __syncthreads();
    float w1[9], w2[9];
#pragma unroll
    for (int k = 0; k < 9; ++k) { w1[k] = w[c * 9 + k]; w2[k] = w[(c + 128) * 9 + k]; }
    u16* dst = g + (long)b * gBS + (long)c * NP;
    int px4 = (tid & 63) * 4;
    int r0 = (tid >> 6) * 4;
#pragma unroll
    for (int r = 0; r < 4; ++r) {
        int row = r0 + r;
        ushort4 ovec;
        u16* ov = (u16*)&ovec;
#pragma unroll
        for (int e = 0; e < 4; ++e) {
            float a1 = conv9(S1, row, px4 + e, w1);
            float a2 = conv9(S2, row, px4 + e, w2);
            ov[e] = f2bf(gelu_exact(a1) * a2);
        }
        *(ushort4*)&dst[(y0 + row) * WWW + px4] = ovec;
    }
}

// CIIM grouped dw conv, strips, vectorized. grid (16, 64, nb)
__global__ __launch_bounds__(256) void ciim_dw_strip(
    const u16* __restrict__ fuse, long fBS, const float* __restrict__ means,
    const float* __restrict__ wdw, const float* __restrict__ bdw,
    u16* __restrict__ hl, long hlBS)
{
    int strip = blockIdx.x, c = blockIdx.y, b = blockIdx.z;
    int y0 = strip * 16, tid = threadIdx.x;
    __shared__ float S[18][260];
    int px4 = (tid & 63) * 4;
    int r0 = (tid >> 6) * 4;
    float acc[4][4];
    float bias = bdw[c];
#pragma unroll
    for (int r = 0; r < 4; ++r)
#pragma unroll
        for (int e = 0; e < 4; ++e) acc[r][e] = bias;
    for (int j6 = 0; j6 < 6; ++j6) {
        int ic = 6 * c + j6;
        const float* w9p = wdw + (c * 6 + j6) * 9;
        float w9[9];
#pragma unroll
        for (int k = 0; k < 9; ++k) w9[k] = w9p[k];
        if (ic < 128) {
            __syncthreads();
            const u16* src = fuse + (long)b * fBS + (long)ic * NP;
            int j = tid >> 4, px = (tid & 15) * 16;
            stage_row(S, src, y0, j, px);
            if (tid < 32) stage_row(S, src, y0, 16 + (tid >> 4), px);
            if (tid < 18) { S[tid][0] = 0.f; S[tid][257] = 0.f; }
            __syncthreads();
#pragma unroll
            for (int r = 0; r < 4; ++r)
#pragma unroll
                for (int e = 0; e < 4; ++e) acc[r][e] += conv9(S, r0 + r, px4 + e, w9);
        } else {
            float mv = means[b * 256 + ic - 128];
#pragma unroll
            for (int r = 0; r < 4; ++r) {
                int row = y0 + r0 + r;
#pragma unroll
                for (int e = 0; e < 4; ++e) {
                    int xc = px4 + e;
                    float ws = 0.f;
#pragma unroll
                    for (int ky = 0; ky < 3; ++ky) {
                        int yy = row + ky - 1;
                        if (yy < 0 || yy >= HHH) continue;
#pragma unroll
                        for (int kx = 0; kx < 3; ++kx) {
                            int xx = xc + kx - 1;
                            if (xx < 0 || xx >= WWW) continue;
                            ws += w9[ky * 3 + kx];
                        }
                    }
                    acc[r][e] += mv * ws;
                }
            }
        }
    }
    u16* dst = hl + (long)b * hlBS + (long)c * NP;
#pragma unroll
    for (int r = 0; r < 4; ++r) {
        ushort4 ovec;
        u16* ov = (u16*)&ovec;
#pragma unroll
        for (int e = 0; e < 4; ++e) ov[e] = f2bf(acc[r][e]);
        *(ushort4*)&dst[(y0 + r0 + r) * WWW + px4] = ovec;
    }
}

// gating + concat + channel shuffle + ecam atomic. grid (64, 128, nb)
__global__ __launch_bounds__(256) void outsh4(
    const u16* __restrict__ hl, long hlBS,
    const float* __restrict__ low, long lBS,
    const float* __restrict__ high,
    u16* __restrict__ outb, long oBS,
    float* __restrict__ ecam)
{
    long p = ((long)blockIdx.x * 256 + threadIdx.x) * 4;
    int cn = blockIdx.y, b = blockIdx.z;
    int co = (cn & 31) * 4 + (cn >> 5);
    const u16* hp;
    const float* sp;
    if (co < 64) {
        hp = hl + (long)b * hlBS + (long)co * NP + p;
        sp = low + (long)b * lBS + (long)co * NP + p;
    } else {
        hp = hl + (long)b * hlBS + (long)(co - 64) * NP + p;
        sp = high + (long)b * lBS + (long)(co - 64) * NP + p;
    }
    ushort4 hu = *(const ushort4*)hp;
    float4 sv = *(const float4*)sp;
    float hv[4] = {bf2f(hu.x), bf2f(hu.y), bf2f(hu.z), bf2f(hu.w)};
    float s4[4] = {sv.x, sv.y, sv.z, sv.w};
    ushort4 ovec;
    u16* ov = (u16*)&ovec;
    float psum = 0.f;
#pragma unroll
    for (int k = 0; k < 4; ++k) {
        float gg = (co < 64) ? sigmoidf_(gelu_exact(hv[k])) : sigmoidf_(fmaxf(hv[k], 0.f));
        float val = gg * s4[k];
        ov[k] = f2bf(val);
        psum += val;
    }
    *(ushort4*)((u16*)outb + (long)b * oBS + (long)cn * NP + p) = ovec;
    __shared__ float red[256];
    red[threadIdx.x] = psum;
    __syncthreads();
    for (int st = 128; st > 0; st >>= 1) {
        if (threadIdx.x < st) red[threadIdx.x] += red[threadIdx.x + st];
        __syncthreads();
    }
    if (threadIdx.x == 0) atomicAdd(&ecam[b * 128 + cn], red[0] * (1.f / NP));
}

// scaled rc2 weights (bf16). grid (nb*32)
__global__ __launch_bounds__(256) void rc2w_build(
    const float* __restrict__ ecam, const float* __restrict__ ecaw,
    const float* __restrict__ wrc2, u16* __restrict__ wout)
{
    int idx = blockIdx.x * 256 + threadIdx.x;
    int c = idx & 127, o = (idx >> 7) & 63, b = idx >> 13;
    float y = sigmoidf_(ecam[b * 128 + c] * ecaw[c]);
    wout[idx] = f2bf(wrc2[o * 128 + c] * y);
}

// q.k dots + sumsq norms over pixel chunks. grid (QKCH, 8, nb)
__global__ __launch_bounds__(256) void qk_dot(
    const u16* __restrict__ D, long dBS, float* __restrict__ part)
{
    int chunk = blockIdx.x, h = blockIdx.y, b = blockIdx.z;
    int tid = threadIdx.x, lane = tid & 63, wave = tid >> 6;
    const u16* q = D + (long)b * dBS + (long)(h * 8) * NP;
    const u16* k = q + 64 * NP;
    float dots[64], nq[8], nk[8];
#pragma unroll
    for (int a = 0; a < 64; ++a) dots[a] = 0.f;
#pragma unroll
    for (int a = 0; a < 8; ++a) { nq[a] = 0.f; nk[a] = 0.f; }
    long p = (long)chunk * 2048 + tid * 8;
    {
        ushort8_t qv[8], kv[8];
#pragma unroll
        for (int i = 0; i < 8; ++i) qv[i] = *(const ushort8_t*)(q + (long)i * NP + p);
#pragma unroll
        for (int i = 0; i < 8; ++i) kv[i] = *(const ushort8_t*)(k + (long)i * NP + p);
#pragma unroll
        for (int e = 0; e < 8; ++e) {
            float qe[8], ke[8];
#pragma unroll
            for (int i = 0; i < 8; ++i) { qe[i] = bf2f(qv[i][e]); ke[i] = bf2f(kv[i][e]); }
#pragma unroll
            for (int i = 0; i < 8; ++i) {
                nq[i] = fmaf(qe[i], qe[i], nq[i]);
                nk[i] = fmaf(ke[i], ke[i], nk[i]);
#pragma unroll
                for (int jj = 0; jj < 8; ++jj)
                    dots[i * 8 + jj] = fmaf(qe[i], ke[jj], dots[i * 8 + jj]);
            }
        }
    }
    __shared__ float red[4][80];
#pragma unroll
    for (int a = 0; a < 64; ++a) {
        float v = dots[a];
#pragma unroll
        for (int o = 32; o > 0; o >>= 1) v += __shfl_xor(v, o);
        if (lane == 0) red[wave][a] = v;
    }
#pragma unroll
    for (int a = 0; a < 8; ++a) {
        float v1 = nq[a], v2 = nk[a];
#pragma unroll
        for (int o = 32; o > 0; o >>= 1) { v1 += __shfl_xor(v1, o); v2 += __shfl_xor(v2, o); }
        if (lane == 0) { red[wave][64 + a] = v1; red[wave][72 + a] = v2; }
    }
    __syncthreads();
    if (tid < 80) {
        float v = red[0][tid] + red[1][tid] + red[2][tid] + red[3][tid];
        part[(((long)b * 8 + h) * 80 + tid) * QKCH + chunk] = v;
    }
}

// head: conv1 (MFMA) + leaky + conv2 + inp + sigmoid. X is bf16. grid (19,19,nb)
__global__ __launch_bounds__(256) void head_fused(
    const u16* __restrict__ X, const u16* __restrict__ wtap,
    const float* __restrict__ wh2, const float* __restrict__ inp,
    float* __restrict__ out)
{
    __shared__ u16 P[18][18][72] __attribute__((aligned(16)));
    __shared__ u16 Hl[16][16][40] __attribute__((aligned(16)));
    __shared__ float w2t[288];
    int ty = blockIdx.x, tx = blockIdx.y, b = blockIdx.z;
    int tid = threadIdx.x, lane = tid & 63, wave = tid >> 6;
    int rl = lane & 15, rg = lane >> 4;
    int oy = ty * 14 - 2, ox = tx * 14 - 2;
    for (int idx = tid; idx < 288; idx += 256)
        w2t[(idx % 9) * 32 + idx / 9] = wh2[idx];
    {
        int lane5 = tid & 31;
        int cbase = tid >> 5;
#pragma unroll
        for (int cg = 0; cg < 8; ++cg) {
            int c = cg * 8 + cbase;
            const u16* src = X + ((long)b * 64 + c) * NP;
            for (int it = 0; it < 11; ++it) {
                int px = lane5 + it * 32;
                if (px < 324) {
                    int row = px / 18, col = px % 18;
                    int gy = oy + row, gx = ox + col;
                    u16 v = (gy >= 0 && gy < HHH && gx >= 0 && gx < WWW)
                                ? src[gy * WWW + gx] : (u16)0;
                    P[row][col][c] = v;
                }
            }
        }
    }
    __syncthreads();
    f32x4 acc[2][4];
#pragma unroll
    for (int m = 0; m < 2; ++m)
#pragma unroll
        for (int n = 0; n < 4; ++n) acc[m][n] = (f32x4){0.f, 0.f, 0.f, 0.f};
#pragma unroll
    for (int tap = 0; tap < 9; ++tap) {
        int ky = tap / 3, kx = tap % 3;
#pragma unroll
        for (int ks = 0; ks < 2; ++ks) {
            int kc = ks * 32 + rg * 8;
            s16x8 a0 = *(const s16x8*)(wtap + tap * 2048 + (long)(0 + rl) * 64 + kc);
            s16x8 a1 = *(const s16x8*)(wtap + tap * 2048 + (long)(16 + rl) * 64 + kc);
#pragma unroll
            for (int n = 0; n < 4; ++n) {
                int py = wave * 4 + n;
                s16x8 bb = *(const s16x8*)&P[py + ky][kx + rl][kc];
                acc[0][n] = __builtin_amdgcn_mfma_f32_16x16x32_bf16(a0, bb, acc[0][n], 0, 0, 0);
                acc[1][n] = __builtin_amdgcn_mfma_f32_16x16x32_bf16(a1, bb, acc[1][n], 0, 0, 0);
            }
        }
    }
#pragma unroll
    for (int m = 0; m < 2; ++m)
#pragma unroll
        for (int n = 0; n < 4; ++n) {
            int py = wave * 4 + n;
            int gy = ty * 14 - 1 + py, gx = tx * 14 - 1 + rl;
            bool ok = (gy >= 0 && gy < HHH && gx >= 0 && gx < WWW);
#pragma unroll
            for (int r = 0; r < 4; ++r) {
                int o = m * 16 + rg * 4 + r;
                float v = acc[m][n][r];
                v = v > 0.f ? v : 0.01f * v;
                Hl[py][rl][o] = ok ? f2bf(v) : (u16)0;
            }
        }
    __syncthreads();
    if (tid < 196) {
        int r = tid / 14, c = tid % 14;
        int gy = ty * 14 + r, gx = tx * 14 + c;
        if (gy < HHH && gx < WWW) {
            float acc2 = 0.f;
#pragma unroll
            for (int tap = 0; tap < 9; ++tap) {
                int hy = r + tap / 3, hx = c + tap % 3;
#pragma unroll
                for (int cg = 0; cg < 4; ++cg) {
                    ushort8_t hv = *(const ushort8_t*)&Hl[hy][hx][cg * 8];
#pragma unroll
                    for (int e = 0; e < 8; ++e)
                        acc2 = fmaf(w2t[tap * 32 + cg * 8 + e], bf2f(hv[e]), acc2);
                }
            }
            float v = acc2 + inp[(long)b * NP + gy * WWW + gx];
            out[(long)b * NP + gy * WWW + gx] = 1.f / (1.f + expf(-v));
        }
    }
}

// ---------------------------------------------------------------------------
extern "C" void kernel_launch(void* const* d_in, const int* in_sizes, int n_in,
                              void* d_out, int out_size, void* d_ws, size_t ws_size,
                              hipStream_t stream)
{
    const float* inp    = (const float*)d_in[0];
    const float* base   = (const float*)d_in[1];
    const float* detail = (const float*)d_in[2];
    const float* w_ir   = (const float*)d_in[3];
    const float* w_vi   = (const float*)d_in[4];
    const float* w_fu   = (const float*)d_in[5];
    const float* b_fu   = (const float*)d_in[6];
    const float* w_dwc  = (const float*)d_in[7];
    const float* b_dwc  = (const float*)d_in[8];
    const float* eca_w  = (const float*)d_in[9];
    const float* w_rc2  = (const float*)d_in[10];
    const float* ln1w   = (const float*)d_in[11];
    const float* ln1b   = (const float*)d_in[12];
    const float* w_qkv  = (const float*)d_in[13];
    const float* w_qdw  = (const float*)d_in[14];
    const float* temp   = (const float*)d_in[15];
    const float* w_proj = (const float*)d_in[16];
    const float* ln2w   = (const float*)d_in[17];
    const float* ln2b   = (const float*)d_in[18];
    const float* w_in_  = (const float*)d_in[19];
    const float* w_fdw  = (const float*)d_in[20];
    const float* w_out_ = (const float*)d_in[21];
    const float* w_h1   = (const float*)d_in[22];
    const float* w_h2   = (const float*)d_in[23];

    float* out = (float*)d_out;

    auto needB = [&](long nb) -> size_t {
        return (size_t)nb * NP * (64 * 2 + 256 * 2 + 192 * 2) + (16u << 20);
    };
    int bInner;
    if (ws_size >= needB(4)) bInner = 4;
    else if (ws_size >= needB(1)) bInner = 1;
    else {
        diag_kernel<<<1, 64, 0, stream>>>(out, (float)(ws_size >> 20));
        return;
    }
    const long nb = bInner;

    char* p = (char*)d_ws;
    auto alloc = [&](size_t bytes) -> char* {
        char* r = p; p += (bytes + 255) & ~(size_t)255; return r;
    };
    u16*   X      = (u16*)alloc((size_t)nb * 64 * NP * 2);   // bf16 residual spine
    u16*   Y      = (u16*)alloc((size_t)nb * 256 * NP * 2);
    u16*   Dq     = (u16*)alloc((size_t)nb * 192 * NP * 2);
    float* part   = (float*)alloc((size_t)nb * 8 * 80 * QKCH * 4);
    float* means  = (float*)alloc((size_t)nb * 384 * 4);
    float* ecam   = means + nb * 256;
    u16*   rc2wb  = (u16*)alloc((size_t)nb * 8192 * 2);
    u16*   fq_bf  = (u16*)alloc((size_t)4 * 192 * 64 * 2);
    float* fqB    = (float*)alloc((size_t)4 * 192 * 4);
    u16*   ff_bf  = (u16*)alloc((size_t)4 * 256 * 64 * 2);
    float* ffB    = (float*)alloc((size_t)4 * 256 * 4);
    u16*   wir_bf = (u16*)alloc(8192 * 2);
    u16*   wvi_bf = (u16*)alloc(8192 * 2);
    u16*   wfu_bf = (u16*)alloc(32768 * 2);
    u16*   wout_bf= (u16*)alloc(32768 * 2);
    u16*   wtap   = (u16*)alloc(9 * 2048 * 2);

    dim3 blk(256);

    fold_ln<<<dim3(28), dim3(64), 0, stream>>>(w_qkv, ln1w, ln1b, w_in_, ln2w, ln2b,
                                               fq_bf, fqB, ff_bf, ffB);
    prep_misc<<<dim3(89), blk, 0, stream>>>(w_ir, w_vi, w_fu, w_out_, w_h1,
                                            wir_bf, wvi_bf, wfu_bf, wout_bf, wtap);

    for (int b0 = 0; b0 < 4; b0 += bInner) {
        const float* inpB    = inp + (long)b0 * NP;
        const float* baseB   = base + (long)b0 * 64 * NP;
        const float* detailB = detail + (long)b0 * 64 * NP;
        float* out0  = out + (long)b0 * NP;
        float* outX0 = out + 262144 + (long)b0 * 64 * NP;

        // ---- CIIM ----
        hipMemsetAsync(means, 0, (size_t)nb * 384 * 4, stream);
        gemm_irvi<<<dim3(4, 256, nb), blk, 0, stream>>>(
            baseB, detailB, wir_bf, wvi_bf, Y, means);
        gemm_plain<<<dim3(2, 256, nb), blk, 0, stream>>>(
            Y, 256 * NP, wfu_bf, b_fu, Dq, 192 * NP, 256);
        ciim_dw_strip<<<dim3(16, 64, nb), blk, 0, stream>>>(
            Dq, 192 * NP, means, w_dwc, b_dwc, Dq + 128 * NP, 192 * NP);
        outsh4<<<dim3(64, 128, nb), blk, 0, stream>>>(
            Dq + 128 * NP, 192 * NP, baseB, 64 * NP, detailB, Y, 256 * NP, ecam);
        rc2w_build<<<dim3(nb * 32), blk, 0, stream>>>(ecam, eca_w, w_rc2, rc2wb);
        // rc2 gemm (dual->outX0 fp32) + LN + qkv gemm (block 0)
        gemm_fused<0, 0, 1, 192><<<dim3(512, 1, nb), blk, 0, stream>>>(
            Y, 256 * NP, rc2wb, 8192, nullptr, X, outX0,
            fq_bf, fqB, Y, nullptr, nullptr, nullptr, 128);

        // ---- transformer blocks ----
        for (int i = 0; i < 4; ++i) {
            dw3x3_strip<<<dim3(16, 192, nb), blk, 0, stream>>>(
                Y, 256 * NP, w_qdw + (long)i * 192 * 9, Dq, 192 * NP);
            qk_dot<<<dim3(QKCH, 8, nb), blk, 0, stream>>>(Dq, 192 * NP, part);
            // pv gemm (weff prologue, resid X) + LN + ffn-in gemm
            gemm_fused<1, 1, 0, 256><<<dim3(512, 1, nb), blk, 0, stream>>>(
                Dq + 128 * NP, 192 * NP, nullptr, 0, X, X, nullptr,
                ff_bf + (long)i * 256 * 64, ffB + i * 256, Y,
                part, temp + i * 8, w_proj + (long)i * 4096, 64);
            ffn_dw_glu_strip<<<dim3(16, 128, nb), blk, 0, stream>>>(
                Y, 256 * NP, w_fdw + (long)i * 256 * 9, Dq, 192 * NP);
            if (i < 3) {
                gemm_fused<0, 1, 0, 192><<<dim3(512, 1, nb), blk, 0, stream>>>(
                    Dq, 192 * NP, wout_bf + (long)i * 8192, 0, X, X, nullptr,
                    fq_bf + (long)(i + 1) * 192 * 64, fqB + (i + 1) * 192, Y,
                    nullptr, nullptr, nullptr, 128);
            } else {
                gemm_fused<0, 1, 0, 0><<<dim3(512, 1, nb), blk, 0, stream>>>(
                    Dq, 192 * NP, wout_bf + (long)i * 8192, 0, X, X, nullptr,
                    nullptr, nullptr, nullptr, nullptr, nullptr, nullptr, 128);
            }
        }

        // ---- head ----
        head_fused<<<dim3(19, 19, nb), blk, 0, stream>>>(X, wtap, w_h2, inpB, out0);
    }
}

// Round 12
// 1760.850 us; speedup vs baseline: 1.9730x; 1.3910x over previous
//
#include <hip/hip_runtime.h>
#include <hip/hip_bf16.h>
#include <math.h>

#define NP 65536L
#define HHH 256
#define WWW 256
#define QKCH 32

typedef unsigned short u16;
typedef unsigned short ushort8_t __attribute__((ext_vector_type(8)));
typedef short s16x8 __attribute__((ext_vector_type(8)));
typedef float f32x4 __attribute__((ext_vector_type(4)));

__device__ __forceinline__ float bf2f(u16 u) { return __uint_as_float(((unsigned)u) << 16); }
__device__ __forceinline__ u16 f2bf(float f) {
    __hip_bfloat16 h = __float2bfloat16(f);
    return *reinterpret_cast<u16*>(&h);
}
__device__ __forceinline__ float sigmoidf_(float x) { return 1.f / (1.f + __expf(-x)); }
__device__ __forceinline__ float gelu_exact(float x) {
    return 0.5f * x * (1.f + erff(x * 0.70710678118654752f));
}

__global__ void diag_kernel(float* out, float v) {
    if (threadIdx.x == 0 && blockIdx.x == 0) out[0] = v;
}

// one-shot weight prep: bf16 casts of 4 weight tensors + wtap rearrange.
__global__ __launch_bounds__(256) void prep_misc(
    const float* __restrict__ wir, const float* __restrict__ wvi,
    const float* __restrict__ wfu, const float* __restrict__ wout,
    const float* __restrict__ wh1,
    u16* __restrict__ dir, u16* __restrict__ dvi,
    u16* __restrict__ dfu, u16* __restrict__ dout,
    u16* __restrict__ wtap)
{
    int bid = blockIdx.x;
    if (bid < 80) {
        long e = (long)bid * 1024 + threadIdx.x * 4;
        const float* src; u16* dst; long off;
        if (e < 8192)       { src = wir;  dst = dir;  off = 0; }
        else if (e < 16384) { src = wvi;  dst = dvi;  off = 8192; }
        else if (e < 49152) { src = wfu;  dst = dfu;  off = 16384; }
        else                { src = wout; dst = dout; off = 49152; }
        long i = e - off;
        float4 v = *(const float4*)(src + i);
        ushort4 o;
        o.x = f2bf(v.x); o.y = f2bf(v.y); o.z = f2bf(v.z); o.w = f2bf(v.w);
        *(ushort4*)(dst + i) = o;
    } else {
        int tap = bid - 80;
        for (int e = threadIdx.x; e < 2048; e += 256)
            wtap[tap * 2048 + e] = f2bf(wh1[(long)e * 9 + tap]);
    }
}

// fold LN gamma/beta into qkv / ffn-in weights; bf16 weights + fp32 bias.
__global__ void fold_ln(
    const float* __restrict__ wqkv, const float* __restrict__ ln1w, const float* __restrict__ ln1b,
    const float* __restrict__ win,  const float* __restrict__ ln2w, const float* __restrict__ ln2b,
    u16* __restrict__ fq, float* __restrict__ fqB,
    u16* __restrict__ ff, float* __restrict__ ffB)
{
    int g = blockIdx.x;
    int i = g / 7, r = g % 7;
    const float *wsrc, *lg, *lb;
    u16* wd; float* Bd;
    int obase;
    if (r < 3) {
        wsrc = wqkv + (long)i * 192 * 64; lg = ln1w + i * 64; lb = ln1b + i * 64;
        wd = fq + (long)i * 192 * 64; Bd = fqB + i * 192; obase = r * 64;
    } else {
        wsrc = win + (long)i * 256 * 64; lg = ln2w + i * 64; lb = ln2b + i * 64;
        wd = ff + (long)i * 256 * 64; Bd = ffB + i * 256; obase = (r - 3) * 64;
    }
    int o = obase + threadIdx.x;
    float Bv = 0.f;
    for (int c = 0; c < 64; ++c) {
        float wv = wsrc[(long)o * 64 + c];
        wd[(long)o * 64 + c] = f2bf(wv * lg[c]);
        Bv += wv * lb[c];
    }
    Bd[o] = Bv;
}

// ---------------------------------------------------------------------------
// CIIM input GEMMs (ir + vi in one dispatch) + fused per-channel means atomic.
// grid (4, 256, nb).
// ---------------------------------------------------------------------------
__global__ __launch_bounds__(256) void gemm_irvi(
    const float* __restrict__ base, const float* __restrict__ detail,
    const u16* __restrict__ wir, const u16* __restrict__ wvi,
    u16* __restrict__ Y, float* __restrict__ means)
{
    __shared__ u16 XT[256][72];
    __shared__ u16 WT[64][72];
    __shared__ float red[4][64];
    int xsel = blockIdx.x, b = blockIdx.z;
    long P0 = (long)blockIdx.y * 256;
    int tid = threadIdx.x, lane = tid & 63, wave = tid >> 6;
    int rl = lane & 15, rg = lane >> 4;
    const float* in = ((xsel < 2) ? base : detail) + (long)b * 64 * NP;
    const u16* wsel = (xsel < 2) ? wir : wvi;
    int orow0 = (xsel & 1) * 64;
    int ochan0 = xsel * 64;

    {
        int o = tid >> 2, cs = (tid & 3) * 16;
        const u16* src = wsel + (long)(orow0 + o) * 64 + cs;
        *(ushort8_t*)&WT[o][cs] = *(const ushort8_t*)src;
        *(ushort8_t*)&WT[o][cs + 8] = *(const ushort8_t*)(src + 8);
    }
    {
        int c0 = (tid & 7) * 8;
        int pt = (tid >> 3) * 8;
        u16 rr[8][8];
#pragma unroll
        for (int i = 0; i < 8; ++i) {
            const float* sp = in + (long)(c0 + i) * NP + P0 + pt;
            float4 a = *(const float4*)sp;
            float4 b4 = *(const float4*)(sp + 4);
            rr[i][0] = f2bf(a.x); rr[i][1] = f2bf(a.y);
            rr[i][2] = f2bf(a.z); rr[i][3] = f2bf(a.w);
            rr[i][4] = f2bf(b4.x); rr[i][5] = f2bf(b4.y);
            rr[i][6] = f2bf(b4.z); rr[i][7] = f2bf(b4.w);
        }
#pragma unroll
        for (int j = 0; j < 8; ++j) {
            ushort8_t v;
#pragma unroll
            for (int i = 0; i < 8; ++i) v[i] = rr[i][j];
            *(ushort8_t*)&XT[pt + j][c0] = v;
        }
    }
    __syncthreads();
    f32x4 acc[4][4];
#pragma unroll
    for (int m = 0; m < 4; ++m)
#pragma unroll
        for (int n = 0; n < 4; ++n) acc[m][n] = (f32x4){0.f, 0.f, 0.f, 0.f};
#pragma unroll
    for (int ks = 0; ks < 2; ++ks) {
        int kc = ks * 32 + rg * 8;
        s16x8 a[4], bb[4];
#pragma unroll
        for (int m = 0; m < 4; ++m) a[m] = *(const s16x8*)&WT[m * 16 + rl][kc];
#pragma unroll
        for (int n = 0; n < 4; ++n) bb[n] = *(const s16x8*)&XT[wave * 64 + n * 16 + rl][kc];
#pragma unroll
        for (int m = 0; m < 4; ++m)
#pragma unroll
            for (int n = 0; n < 4; ++n)
                acc[m][n] = __builtin_amdgcn_mfma_f32_16x16x32_bf16(a[m], bb[n], acc[m][n], 0, 0, 0);
    }
    float csum[4][4];
#pragma unroll
    for (int m = 0; m < 4; ++m)
#pragma unroll
        for (int r = 0; r < 4; ++r) csum[m][r] = 0.f;
#pragma unroll
    for (int m = 0; m < 4; ++m)
#pragma unroll
        for (int n = 0; n < 4; ++n) {
            long px = P0 + wave * 64 + n * 16 + rl;
#pragma unroll
            for (int r = 0; r < 4; ++r) {
                int oo = ochan0 + m * 16 + rg * 4 + r;
                float v = acc[m][n][r];
                Y[((long)b * 256 + oo) * NP + px] = f2bf(v);
                csum[m][r] += v;
            }
        }
#pragma unroll
    for (int m = 0; m < 4; ++m)
#pragma unroll
        for (int r = 0; r < 4; ++r) {
            float s = csum[m][r];
            s += __shfl_xor(s, 1); s += __shfl_xor(s, 2);
            s += __shfl_xor(s, 4); s += __shfl_xor(s, 8);
            if (rl == 0) red[wave][m * 16 + rg * 4 + r] = s;
        }
    __syncthreads();
    if (tid < 64) {
        float v = red[0][tid] + red[1][tid] + red[2][tid] + red[3][tid];
        atomicAdd(&means[b * 256 + ochan0 + tid], v * (1.f / NP));
    }
}

// plain MFMA GEMM (fuse conv). grid (Cout/64, 256, nb)
__global__ __launch_bounds__(256) void gemm_plain(
    const u16* __restrict__ in, long inBS,
    const u16* __restrict__ wbf,
    const float* __restrict__ bias,
    u16* __restrict__ outp, long outBS, int Cin)
{
    __shared__ u16 XT[256][72];
    __shared__ u16 WT[64][72];
    int b = blockIdx.z;
    int oBase = blockIdx.x * 64;
    long P0 = (long)blockIdx.y * 256;
    int tid = threadIdx.x, lane = tid & 63, wave = tid >> 6;
    int rl = lane & 15, rg = lane >> 4;
    const u16* inB = in + (long)b * inBS;
    f32x4 acc[4][4];
#pragma unroll
    for (int m = 0; m < 4; ++m)
#pragma unroll
        for (int n = 0; n < 4; ++n) acc[m][n] = (f32x4){0.f, 0.f, 0.f, 0.f};
    for (int ck = 0; ck < Cin; ck += 64) {
        if (ck) __syncthreads();
        {
            int o = tid >> 2, cs = (tid & 3) * 16;
            const u16* src = wbf + (long)(oBase + o) * Cin + ck + cs;
            *(ushort8_t*)&WT[o][cs] = *(const ushort8_t*)src;
            *(ushort8_t*)&WT[o][cs + 8] = *(const ushort8_t*)(src + 8);
        }
        {
            int c0 = (tid & 7) * 8;
            int pt = (tid >> 3) * 8;
            ushort8_t r[8];
#pragma unroll
            for (int i = 0; i < 8; ++i)
                r[i] = *(const ushort8_t*)(inB + (long)(ck + c0 + i) * NP + P0 + pt);
#pragma unroll
            for (int j = 0; j < 8; ++j) {
                ushort8_t v;
#pragma unroll
                for (int i = 0; i < 8; ++i) v[i] = r[i][j];
                *(ushort8_t*)&XT[pt + j][c0] = v;
            }
        }
        __syncthreads();
#pragma unroll
        for (int ks = 0; ks < 2; ++ks) {
            int kc = ks * 32 + rg * 8;
            s16x8 a[4], bb[4];
#pragma unroll
            for (int m = 0; m < 4; ++m) a[m] = *(const s16x8*)&WT[m * 16 + rl][kc];
#pragma unroll
            for (int n = 0; n < 4; ++n) bb[n] = *(const s16x8*)&XT[wave * 64 + n * 16 + rl][kc];
#pragma unroll
            for (int m = 0; m < 4; ++m)
#pragma unroll
                for (int n = 0; n < 4; ++n)
                    acc[m][n] = __builtin_amdgcn_mfma_f32_16x16x32_bf16(a[m], bb[n], acc[m][n], 0, 0, 0);
        }
    }
#pragma unroll
    for (int m = 0; m < 4; ++m) {
#pragma unroll
        for (int n = 0; n < 4; ++n) {
            long px = P0 + wave * 64 + n * 16 + rl;
#pragma unroll
            for (int r = 0; r < 4; ++r) {
                int oo = oBase + m * 16 + rg * 4 + r;
                outp[(long)b * outBS + (long)oo * NP + px] = f2bf(acc[m][n][r] + bias[oo]);
            }
        }
    }
}

// ---------------------------------------------------------------------------
// Fused GEMM -> X(bf16) -> LN -> LDS -> second GEMM -> Y(bf16).
// 128-px tiles. grid (512, 1, nb).
// ---------------------------------------------------------------------------
template<int WEFF, int RESID, int DUAL, int M2>
__global__ __launch_bounds__(256) void gemm_fused(
    const u16* __restrict__ in, long inBS,
    const u16* __restrict__ w1, long w1BS,
    const u16* __restrict__ residX,
    u16* __restrict__ Xout,
    float* __restrict__ out2,
    const u16* __restrict__ w2, const float* __restrict__ bias2,
    u16* __restrict__ Yout,
    const float* __restrict__ part, const float* __restrict__ temp,
    const float* __restrict__ wproj,
    int Cin)
{
    __shared__ u16 XT[128][72] __attribute__((aligned(16)));
    __shared__ u16 WT[64][72] __attribute__((aligned(16)));
    int b = blockIdx.z;
    long P0 = (long)blockIdx.x * 128;
    int tid = threadIdx.x, lane = tid & 63, wave = tid >> 6;
    int rl = lane & 15, rg = lane >> 4;
    const u16* inB = in + (long)b * inBS;

    if constexpr (WEFF) {
        float* SgF = (float*)&XT[0][0];
        float* attF = SgF + 640;
        for (int e = tid; e < 640; e += 256) {
            int h = e / 80, k = e % 80;
            const float* pp = part + (((long)b * 8 + h) * 80 + k) * QKCH;
            float s = 0.f;
#pragma unroll
            for (int c = 0; c < QKCH; ++c) s += pp[c];
            SgF[e] = s;
        }
        __syncthreads();
        if (tid < 64) {
            int h = tid >> 3, iq = tid & 7;
            float nqv = fmaxf(sqrtf(SgF[h * 80 + 64 + iq]), 1e-12f);
            float tp = temp[h];
            float row[8], mx = -1e30f;
#pragma unroll
            for (int jj = 0; jj < 8; ++jj) {
                float nkv = fmaxf(sqrtf(SgF[h * 80 + 72 + jj]), 1e-12f);
                row[jj] = SgF[h * 80 + iq * 8 + jj] / (nqv * nkv) * tp;
                mx = fmaxf(mx, row[jj]);
            }
            float sum = 0.f;
#pragma unroll
            for (int jj = 0; jj < 8; ++jj) { row[jj] = __expf(row[jj] - mx); sum += row[jj]; }
            float rinv = 1.f / sum;
#pragma unroll
            for (int jj = 0; jj < 8; ++jj) attF[(h * 8 + iq) * 8 + jj] = row[jj] * rinv;
        }
        __syncthreads();
        {
            int o = tid >> 2;
            int cv0 = (tid & 3) * 16;
#pragma unroll
            for (int cv = 0; cv < 16; ++cv) {
                int c = cv0 + cv;
                int h = c >> 3, jj = c & 7;
                float s = 0.f;
#pragma unroll
                for (int i = 0; i < 8; ++i)
                    s = fmaf(wproj[o * 64 + h * 8 + i], attF[(h * 8 + i) * 8 + jj], s);
                WT[o][c] = f2bf(s);
            }
        }
        __syncthreads();
    }

    f32x4 acc[4][2];
#pragma unroll
    for (int m = 0; m < 4; ++m)
#pragma unroll
        for (int n = 0; n < 2; ++n) acc[m][n] = (f32x4){0.f, 0.f, 0.f, 0.f};

    for (int ck = 0; ck < Cin; ck += 64) {
        if (ck) __syncthreads();
        if constexpr (!WEFF) {
            int o = tid >> 2, cs = (tid & 3) * 16;
            const u16* src = w1 + (long)b * w1BS + (long)o * Cin + ck + cs;
            *(ushort8_t*)&WT[o][cs] = *(const ushort8_t*)src;
            *(ushort8_t*)&WT[o][cs + 8] = *(const ushort8_t*)(src + 8);
        }
        if (tid < 128) {
            int c0 = (tid & 7) * 8;
            int pt = (tid >> 3) * 8;
            ushort8_t r[8];
#pragma unroll
            for (int i = 0; i < 8; ++i)
                r[i] = *(const ushort8_t*)(inB + (long)(ck + c0 + i) * NP + P0 + pt);
#pragma unroll
            for (int j = 0; j < 8; ++j) {
                ushort8_t v;
#pragma unroll
                for (int i = 0; i < 8; ++i) v[i] = r[i][j];
                *(ushort8_t*)&XT[pt + j][c0] = v;
            }
        }
        __syncthreads();
#pragma unroll
        for (int ks = 0; ks < 2; ++ks) {
            int kc = ks * 32 + rg * 8;
            s16x8 a[4], bb[2];
#pragma unroll
            for (int m = 0; m < 4; ++m) a[m] = *(const s16x8*)&WT[m * 16 + rl][kc];
#pragma unroll
            for (int n = 0; n < 2; ++n) bb[n] = *(const s16x8*)&XT[wave * 32 + n * 16 + rl][kc];
#pragma unroll
            for (int m = 0; m < 4; ++m)
#pragma unroll
                for (int n = 0; n < 2; ++n)
                    acc[m][n] = __builtin_amdgcn_mfma_f32_16x16x32_bf16(a[m], bb[n], acc[m][n], 0, 0, 0);
        }
    }

    // epilogue 1: resid + X store (bf16) (+dual fp32)
#pragma unroll
    for (int m = 0; m < 4; ++m)
#pragma unroll
        for (int n = 0; n < 2; ++n) {
            long px = P0 + wave * 32 + n * 16 + rl;
#pragma unroll
            for (int r = 0; r < 4; ++r) {
                int oo = m * 16 + rg * 4 + r;
                float t = acc[m][n][r];
                if constexpr (RESID) t += bf2f(residX[((long)b * 64 + oo) * NP + px]);
                acc[m][n][r] = t;
                Xout[((long)b * 64 + oo) * NP + px] = f2bf(t);
                if constexpr (DUAL) out2[((long)b * 64 + oo) * NP + px] = t;
            }
        }

    if constexpr (M2 > 0) {
        float muA[2], invA[2];
#pragma unroll
        for (int n = 0; n < 2; ++n) {
            float s = 0.f, s2 = 0.f;
#pragma unroll
            for (int m = 0; m < 4; ++m)
#pragma unroll
                for (int r = 0; r < 4; ++r) {
                    float t = acc[m][n][r];
                    s += t; s2 = fmaf(t, t, s2);
                }
            s += __shfl_xor(s, 16);  s += __shfl_xor(s, 32);
            s2 += __shfl_xor(s2, 16); s2 += __shfl_xor(s2, 32);
            float mu = s * (1.f / 64.f);
            float var = fmaxf(s2 * (1.f / 64.f) - mu * mu, 0.f);
            muA[n] = mu;
            invA[n] = rsqrtf(var + 1e-5f);
        }
        __syncthreads();
#pragma unroll
        for (int m = 0; m < 4; ++m)
#pragma unroll
            for (int n = 0; n < 2; ++n) {
                int pxl = wave * 32 + n * 16 + rl;
#pragma unroll
                for (int r = 0; r < 4; ++r)
                    XT[pxl][m * 16 + rg * 4 + r] = f2bf((acc[m][n][r] - muA[n]) * invA[n]);
            }
        __syncthreads();
        for (int mc = 0; mc < M2 / 64; ++mc) {
            if (mc) __syncthreads();
            {
                int o = tid >> 2, cs = (tid & 3) * 16;
                const u16* src = w2 + (long)(mc * 64 + o) * 64 + cs;
                *(ushort8_t*)&WT[o][cs] = *(const ushort8_t*)src;
                *(ushort8_t*)&WT[o][cs + 8] = *(const ushort8_t*)(src + 8);
            }
            __syncthreads();
            f32x4 a2[4][2];
#pragma unroll
            for (int m = 0; m < 4; ++m)
#pragma unroll
                for (int n = 0; n < 2; ++n) a2[m][n] = (f32x4){0.f, 0.f, 0.f, 0.f};
#pragma unroll
            for (int ks = 0; ks < 2; ++ks) {
                int kc = ks * 32 + rg * 8;
                s16x8 a[4], bb[2];
#pragma unroll
                for (int m = 0; m < 4; ++m) a[m] = *(const s16x8*)&WT[m * 16 + rl][kc];
#pragma unroll
                for (int n = 0; n < 2; ++n) bb[n] = *(const s16x8*)&XT[wave * 32 + n * 16 + rl][kc];
#pragma unroll
                for (int m = 0; m < 4; ++m)
#pragma unroll
                    for (int n = 0; n < 2; ++n)
                        a2[m][n] = __builtin_amdgcn_mfma_f32_16x16x32_bf16(a[m], bb[n], a2[m][n], 0, 0, 0);
            }
#pragma unroll
            for (int m = 0; m < 4; ++m) {
#pragma unroll
                for (int n = 0; n < 2; ++n) {
                    long px = P0 + wave * 32 + n * 16 + rl;
#pragma unroll
                    for (int r = 0; r < 4; ++r) {
                        int oo = mc * 64 + m * 16 + rg * 4 + r;
                        Yout[((long)b * 256 + oo) * NP + px] = f2bf(a2[m][n][r] + bias2[oo]);
                    }
                }
            }
        }
    }
}

// stage one LDS row (16 px) of a bf16 channel strip
__device__ __forceinline__ void stage_row(float (*S)[260], const u16* __restrict__ src,
                                          int y0, int j, int px)
{
    int row = y0 - 1 + j;
    if (row >= 0 && row < HHH) {
        ushort8_t a = *(const ushort8_t*)(src + row * WWW + px);
        ushort8_t b = *(const ushort8_t*)(src + row * WWW + px + 8);
#pragma unroll
        for (int e = 0; e < 8; ++e) { S[j][1 + px + e] = bf2f(a[e]); S[j][9 + px + e] = bf2f(b[e]); }
    } else {
#pragma unroll
        for (int e = 0; e < 16; ++e) S[j][1 + px + e] = 0.f;
    }
}
__device__ __forceinline__ float conv9(const float (*S)[260], int r, int col,
                                       const float* __restrict__ w9)
{
    float a = 0.f;
#pragma unroll
    for (int ky = 0; ky < 3; ++ky)
#pragma unroll
        for (int kx = 0; kx < 3; ++kx)
            a = fmaf(w9[ky * 3 + kx], S[r + ky][col + kx], a);
    return a;
}

// depthwise 3x3, 16-row strips, vectorized stores, split output routing.
// c < csplit -> out1[c] (BS1); c >= csplit -> out2[obase2 + c - csplit] (BS2).
// grid (16, C, nb)
__global__ __launch_bounds__(256) void dw3x3_strip(
    const u16* __restrict__ in, long inBS, const float* __restrict__ w,
    u16* __restrict__ out1, long out1BS,
    u16* __restrict__ out2, long out2BS, int obase2, int csplit)
{
    int strip = blockIdx.x, c = blockIdx.y, b = blockIdx.z;
    int y0 = strip * 16, tid = threadIdx.x;
    __shared__ float S[18][260];
    const u16* src = in + (long)b * inBS + (long)c * NP;
    int j = tid >> 4, px = (tid & 15) * 16;
    stage_row(S, src, y0, j, px);
    if (tid < 32) stage_row(S, src, y0, 16 + (tid >> 4), px);
    if (tid < 18) { S[tid][0] = 0.f; S[tid][257] = 0.f; }
    __syncthreads();
    float w9[9];
#pragma unroll
    for (int k = 0; k < 9; ++k) w9[k] = w[c * 9 + k];
    u16* dst = (c < csplit)
                   ? out1 + (long)b * out1BS + (long)c * NP
                   : out2 + (long)b * out2BS + (long)(obase2 + c - csplit) * NP;
    int px4 = (tid & 63) * 4;
    int r0 = (tid >> 6) * 4;
#pragma unroll
    for (int r = 0; r < 4; ++r) {
        int row = r0 + r;
        ushort4 ovec;
        u16* ov = (u16*)&ovec;
#pragma unroll
        for (int e = 0; e < 4; ++e) ov[e] = f2bf(conv9(S, row, px4 + e, w9));
        *(ushort4*)&dst[(y0 + row) * WWW + px4] = ovec;
    }
}

// ffn: dw3x3 on (c, c+128) + gelu(y1)*y2, strips, vectorized. grid (16, 128, nb)
__global__ __launch_bounds__(256) void ffn_dw_glu_strip(
    const u16* __restrict__ y, long yBS, const float* __restrict__ w,
    u16* __restrict__ g, long gBS)
{
    int strip = blockIdx.x, c = blockIdx.y, b = blockIdx.z;
    int y0 = strip * 16, tid = threadIdx.x;
    __shared__ float S1[18][260];
    __shared__ float S2[18][260];
    const u16* s1 = y + (long)b * yBS + (long)c * NP;
    const u16* s2 = y + (long)b * yBS + (long)(c + 128) * NP;
    int j = tid >> 4, px = (tid & 15) * 16;
    stage_row(S1, s1, y0, j, px);
    if (tid < 32) stage_row(S1, s1, y0, 16 + (tid >> 4), px);
    stage_row(S2, s2, y0, j, px);
    if (tid < 32) stage_row(S2, s2, y0, 16 + (tid >> 4), px);
    if (tid < 18) { S1[tid][0] = S1[tid][257] = 0.f; S2[tid][0] = S2[tid][257] = 0.f; }
    __syncthreads();
    float w1[9], w2[9];
#pragma unroll
    for (int k = 0; k < 9; ++k) { w1[k] = w[c * 9 + k]; w2[k] = w[(c + 128) * 9 + k]; }
    u16* dst = g + (long)b * gBS + (long)c * NP;
    int px4 = (tid & 63) * 4;
    int r0 = (tid >> 6) * 4;
#pragma unroll
    for (int r = 0; r < 4; ++r) {
        int row = r0 + r;
        ushort4 ovec;
        u16* ov = (u16*)&ovec;
#pragma unroll
        for (int e = 0; e < 4; ++e) {
            float a1 = conv9(S1, row, px4 + e, w1);
            float a2 = conv9(S2, row, px4 + e, w2);
            ov[e] = f2bf(gelu_exact(a1) * a2);
        }
        *(ushort4*)&dst[(y0 + row) * WWW + px4] = ovec;
    }
}

// CIIM grouped dw conv, strips, vectorized. grid (16, 64, nb)
__global__ __launch_bounds__(256) void ciim_dw_strip(
    const u16* __restrict__ fuse, long fBS, const float* __restrict__ means,
    const float* __restrict__ wdw, const float* __restrict__ bdw,
    u16* __restrict__ hl, long hlBS)
{
    int strip = blockIdx.x, c = blockIdx.y, b = blockIdx.z;
    int y0 = strip * 16, tid = threadIdx.x;
    __shared__ float S[18][260];
    int px4 = (tid & 63) * 4;
    int r0 = (tid >> 6) * 4;
    float acc[4][4];
    float bias = bdw[c];
#pragma unroll
    for (int r = 0; r < 4; ++r)
#pragma unroll
        for (int e = 0; e < 4; ++e) acc[r][e] = bias;
    for (int j6 = 0; j6 < 6; ++j6) {
        int ic = 6 * c + j6;
        const float* w9p = wdw + (c * 6 + j6) * 9;
        float w9[9];
#pragma unroll
        for (int k = 0; k < 9; ++k) w9[k] = w9p[k];
        if (ic < 128) {
            __syncthreads();
            const u16* src = fuse + (long)b * fBS + (long)ic * NP;
            int j = tid >> 4, px = (tid & 15) * 16;
            stage_row(S, src, y0, j, px);
            if (tid < 32) stage_row(S, src, y0, 16 + (tid >> 4), px);
            if (tid < 18) { S[tid][0] = 0.f; S[tid][257] = 0.f; }
            __syncthreads();
#pragma unroll
            for (int r = 0; r < 4; ++r)
#pragma unroll
                for (int e = 0; e < 4; ++e) acc[r][e] += conv9(S, r0 + r, px4 + e, w9);
        } else {
            float mv = means[b * 256 + ic - 128];
#pragma unroll
            for (int r = 0; r < 4; ++r) {
                int row = y0 + r0 + r;
#pragma unroll
                for (int e = 0; e < 4; ++e) {
                    int xc = px4 + e;
                    float ws = 0.f;
#pragma unroll
                    for (int ky = 0; ky < 3; ++ky) {
                        int yy = row + ky - 1;
                        if (yy < 0 || yy >= HHH) continue;
#pragma unroll
                        for (int kx = 0; kx < 3; ++kx) {
                            int xx = xc + kx - 1;
                            if (xx < 0 || xx >= WWW) continue;
                            ws += w9[ky * 3 + kx];
                        }
                    }
                    acc[r][e] += mv * ws;
                }
            }
        }
    }
    u16* dst = hl + (long)b * hlBS + (long)c * NP;
#pragma unroll
    for (int r = 0; r < 4; ++r) {
        ushort4 ovec;
        u16* ov = (u16*)&ovec;
#pragma unroll
        for (int e = 0; e < 4; ++e) ov[e] = f2bf(acc[r][e]);
        *(ushort4*)&dst[(y0 + r0 + r) * WWW + px4] = ovec;
    }
}

// gating + concat + channel shuffle + ecam atomic. grid (64, 128, nb)
__global__ __launch_bounds__(256) void outsh4(
    const u16* __restrict__ hl, long hlBS,
    const float* __restrict__ low, long lBS,
    const float* __restrict__ high,
    u16* __restrict__ outb, long oBS,
    float* __restrict__ ecam)
{
    long p = ((long)blockIdx.x * 256 + threadIdx.x) * 4;
    int cn = blockIdx.y, b = blockIdx.z;
    int co = (cn & 31) * 4 + (cn >> 5);
    const u16* hp;
    const float* sp;
    if (co < 64) {
        hp = hl + (long)b * hlBS + (long)co * NP + p;
        sp = low + (long)b * lBS + (long)co * NP + p;
    } else {
        hp = hl + (long)b * hlBS + (long)(co - 64) * NP + p;
        sp = high + (long)b * lBS + (long)(co - 64) * NP + p;
    }
    ushort4 hu = *(const ushort4*)hp;
    float4 sv = *(const float4*)sp;
    float hv[4] = {bf2f(hu.x), bf2f(hu.y), bf2f(hu.z), bf2f(hu.w)};
    float s4[4] = {sv.x, sv.y, sv.z, sv.w};
    ushort4 ovec;
    u16* ov = (u16*)&ovec;
    float psum = 0.f;
#pragma unroll
    for (int k = 0; k < 4; ++k) {
        float gg = (co < 64) ? sigmoidf_(gelu_exact(hv[k])) : sigmoidf_(fmaxf(hv[k], 0.f));
        float val = gg * s4[k];
        ov[k] = f2bf(val);
        psum += val;
    }
    *(ushort4*)((u16*)outb + (long)b * oBS + (long)cn * NP + p) = ovec;
    __shared__ float red[256];
    red[threadIdx.x] = psum;
    __syncthreads();
    for (int st = 128; st > 0; st >>= 1) {
        if (threadIdx.x < st) red[threadIdx.x] += red[threadIdx.x + st];
        __syncthreads();
    }
    if (threadIdx.x == 0) atomicAdd(&ecam[b * 128 + cn], red[0] * (1.f / NP));
}

// scaled rc2 weights (bf16). grid (nb*32)
__global__ __launch_bounds__(256) void rc2w_build(
    const float* __restrict__ ecam, const float* __restrict__ ecaw,
    const float* __restrict__ wrc2, u16* __restrict__ wout)
{
    int idx = blockIdx.x * 256 + threadIdx.x;
    int c = idx & 127, o = (idx >> 7) & 63, b = idx >> 13;
    float y = sigmoidf_(ecam[b * 128 + c] * ecaw[c]);
    wout[idx] = f2bf(wrc2[o * 128 + c] * y);
}

// q.k dots + sumsq norms over pixel chunks. grid (QKCH, 8, nb)
__global__ __launch_bounds__(256) void qk_dot(
    const u16* __restrict__ D, long dBS, float* __restrict__ part)
{
    int chunk = blockIdx.x, h = blockIdx.y, b = blockIdx.z;
    int tid = threadIdx.x, lane = tid & 63, wave = tid >> 6;
    const u16* q = D + (long)b * dBS + (long)(h * 8) * NP;
    const u16* k = q + 64 * NP;
    float dots[64], nq[8], nk[8];
#pragma unroll
    for (int a = 0; a < 64; ++a) dots[a] = 0.f;
#pragma unroll
    for (int a = 0; a < 8; ++a) { nq[a] = 0.f; nk[a] = 0.f; }
    long p = (long)chunk * 2048 + tid * 8;
    {
        ushort8_t qv[8], kv[8];
#pragma unroll
        for (int i = 0; i < 8; ++i) qv[i] = *(const ushort8_t*)(q + (long)i * NP + p);
#pragma unroll
        for (int i = 0; i < 8; ++i) kv[i] = *(const ushort8_t*)(k + (long)i * NP + p);
#pragma unroll
        for (int e = 0; e < 8; ++e) {
            float qe[8], ke[8];
#pragma unroll
            for (int i = 0; i < 8; ++i) { qe[i] = bf2f(qv[i][e]); ke[i] = bf2f(kv[i][e]); }
#pragma unroll
            for (int i = 0; i < 8; ++i) {
                nq[i] = fmaf(qe[i], qe[i], nq[i]);
                nk[i] = fmaf(ke[i], ke[i], nk[i]);
#pragma unroll
                for (int jj = 0; jj < 8; ++jj)
                    dots[i * 8 + jj] = fmaf(qe[i], ke[jj], dots[i * 8 + jj]);
            }
        }
    }
    __shared__ float red[4][80];
#pragma unroll
    for (int a = 0; a < 64; ++a) {
        float v = dots[a];
#pragma unroll
        for (int o = 32; o > 0; o >>= 1) v += __shfl_xor(v, o);
        if (lane == 0) red[wave][a] = v;
    }
#pragma unroll
    for (int a = 0; a < 8; ++a) {
        float v1 = nq[a], v2 = nk[a];
#pragma unroll
        for (int o = 32; o > 0; o >>= 1) { v1 += __shfl_xor(v1, o); v2 += __shfl_xor(v2, o); }
        if (lane == 0) { red[wave][64 + a] = v1; red[wave][72 + a] = v2; }
    }
    __syncthreads();
    if (tid < 80) {
        float v = red[0][tid] + red[1][tid] + red[2][tid] + red[3][tid];
        part[(((long)b * 8 + h) * 80 + tid) * QKCH + chunk] = v;
    }
}

// head: conv1 (MFMA) + leaky + conv2 + inp + sigmoid. X is bf16. grid (19,19,nb)
__global__ __launch_bounds__(256) void head_fused(
    const u16* __restrict__ X, const u16* __restrict__ wtap,
    const float* __restrict__ wh2, const float* __restrict__ inp,
    float* __restrict__ out)
{
    __shared__ u16 P[18][18][72] __attribute__((aligned(16)));
    __shared__ u16 Hl[16][16][40] __attribute__((aligned(16)));
    __shared__ float w2t[288];
    int ty = blockIdx.x, tx = blockIdx.y, b = blockIdx.z;
    int tid = threadIdx.x, lane = tid & 63, wave = tid >> 6;
    int rl = lane & 15, rg = lane >> 4;
    int oy = ty * 14 - 2, ox = tx * 14 - 2;
    for (int idx = tid; idx < 288; idx += 256)
        w2t[(idx % 9) * 32 + idx / 9] = wh2[idx];
    {
        int lane5 = tid & 31;
        int cbase = tid >> 5;
#pragma unroll
        for (int cg = 0; cg < 8; ++cg) {
            int c = cg * 8 + cbase;
            const u16* src = X + ((long)b * 64 + c) * NP;
            for (int it = 0; it < 11; ++it) {
                int px = lane5 + it * 32;
                if (px < 324) {
                    int row = px / 18, col = px % 18;
                    int gy = oy + row, gx = ox + col;
                    u16 v = (gy >= 0 && gy < HHH && gx >= 0 && gx < WWW)
                                ? src[gy * WWW + gx] : (u16)0;
                    P[row][col][c] = v;
                }
            }
        }
    }
    __syncthreads();
    f32x4 acc[2][4];
#pragma unroll
    for (int m = 0; m < 2; ++m)
#pragma unroll
        for (int n = 0; n < 4; ++n) acc[m][n] = (f32x4){0.f, 0.f, 0.f, 0.f};
#pragma unroll
    for (int tap = 0; tap < 9; ++tap) {
        int ky = tap / 3, kx = tap % 3;
#pragma unroll
        for (int ks = 0; ks < 2; ++ks) {
            int kc = ks * 32 + rg * 8;
            s16x8 a0 = *(const s16x8*)(wtap + tap * 2048 + (long)(0 + rl) * 64 + kc);
            s16x8 a1 = *(const s16x8*)(wtap + tap * 2048 + (long)(16 + rl) * 64 + kc);
#pragma unroll
            for (int n = 0; n < 4; ++n) {
                int py = wave * 4 + n;
                s16x8 bb = *(const s16x8*)&P[py + ky][kx + rl][kc];
                acc[0][n] = __builtin_amdgcn_mfma_f32_16x16x32_bf16(a0, bb, acc[0][n], 0, 0, 0);
                acc[1][n] = __builtin_amdgcn_mfma_f32_16x16x32_bf16(a1, bb, acc[1][n], 0, 0, 0);
            }
        }
    }
#pragma unroll
    for (int m = 0; m < 2; ++m)
#pragma unroll
        for (int n = 0; n < 4; ++n) {
            int py = wave * 4 + n;
            int gy = ty * 14 - 1 + py, gx = tx * 14 - 1 + rl;
            bool ok = (gy >= 0 && gy < HHH && gx >= 0 && gx < WWW);
#pragma unroll
            for (int r = 0; r < 4; ++r) {
                int o = m * 16 + rg * 4 + r;
                float v = acc[m][n][r];
                v = v > 0.f ? v : 0.01f * v;
                Hl[py][rl][o] = ok ? f2bf(v) : (u16)0;
            }
        }
    __syncthreads();
    if (tid < 196) {
        int r = tid / 14, c = tid % 14;
        int gy = ty * 14 + r, gx = tx * 14 + c;
        if (gy < HHH && gx < WWW) {
            float acc2 = 0.f;
#pragma unroll
            for (int tap = 0; tap < 9; ++tap) {
                int hy = r + tap / 3, hx = c + tap % 3;
#pragma unroll
                for (int cg = 0; cg < 4; ++cg) {
                    ushort8_t hv = *(const ushort8_t*)&Hl[hy][hx][cg * 8];
#pragma unroll
                    for (int e = 0; e < 8; ++e)
                        acc2 = fmaf(w2t[tap * 32 + cg * 8 + e], bf2f(hv[e]), acc2);
                }
            }
            float v = acc2 + inp[(long)b * NP + gy * WWW + gx];
            out[(long)b * NP + gy * WWW + gx] = 1.f / (1.f + expf(-v));
        }
    }
}

// ---------------------------------------------------------------------------
extern "C" void kernel_launch(void* const* d_in, const int* in_sizes, int n_in,
                              void* d_out, int out_size, void* d_ws, size_t ws_size,
                              hipStream_t stream)
{
    const float* inp    = (const float*)d_in[0];
    const float* base   = (const float*)d_in[1];
    const float* detail = (const float*)d_in[2];
    const float* w_ir   = (const float*)d_in[3];
    const float* w_vi   = (const float*)d_in[4];
    const float* w_fu   = (const float*)d_in[5];
    const float* b_fu   = (const float*)d_in[6];
    const float* w_dwc  = (const float*)d_in[7];
    const float* b_dwc  = (const float*)d_in[8];
    const float* eca_w  = (const float*)d_in[9];
    const float* w_rc2  = (const float*)d_in[10];
    const float* ln1w   = (const float*)d_in[11];
    const float* ln1b   = (const float*)d_in[12];
    const float* w_qkv  = (const float*)d_in[13];
    const float* w_qdw  = (const float*)d_in[14];
    const float* temp   = (const float*)d_in[15];
    const float* w_proj = (const float*)d_in[16];
    const float* ln2w   = (const float*)d_in[17];
    const float* ln2b   = (const float*)d_in[18];
    const float* w_in_  = (const float*)d_in[19];
    const float* w_fdw  = (const float*)d_in[20];
    const float* w_out_ = (const float*)d_in[21];
    const float* w_h1   = (const float*)d_in[22];
    const float* w_h2   = (const float*)d_in[23];

    float* out = (float*)d_out;

    // per-image big buffers: X 64ch bf16 + Y 256ch bf16 + Dq 128ch bf16
    auto needB = [&](long nb) -> size_t {
        return (size_t)nb * NP * (64 * 2 + 256 * 2 + 128 * 2) + (4u << 20);
    };
    int bInner;
    if (ws_size >= needB(4)) bInner = 4;
    else if (ws_size >= needB(2)) bInner = 2;
    else if (ws_size >= needB(1)) bInner = 1;
    else {
        diag_kernel<<<1, 64, 0, stream>>>(out, (float)(ws_size >> 20));
        return;
    }
    const long nb = bInner;

    char* p = (char*)d_ws;
    auto alloc = [&](size_t bytes) -> char* {
        char* r = p; p += (bytes + 255) & ~(size_t)255; return r;
    };
    u16*   X      = (u16*)alloc((size_t)nb * 64 * NP * 2);
    u16*   Y      = (u16*)alloc((size_t)nb * 256 * NP * 2);
    u16*   Dq     = (u16*)alloc((size_t)nb * 128 * NP * 2);
    float* part   = (float*)alloc((size_t)nb * 8 * 80 * QKCH * 4);
    float* means  = (float*)alloc((size_t)nb * 384 * 4);
    float* ecam   = means + nb * 256;
    u16*   rc2wb  = (u16*)alloc((size_t)nb * 8192 * 2);
    u16*   fq_bf  = (u16*)alloc((size_t)4 * 192 * 64 * 2);
    float* fqB    = (float*)alloc((size_t)4 * 192 * 4);
    u16*   ff_bf  = (u16*)alloc((size_t)4 * 256 * 64 * 2);
    float* ffB    = (float*)alloc((size_t)4 * 256 * 4);
    u16*   wir_bf = (u16*)alloc(8192 * 2);
    u16*   wvi_bf = (u16*)alloc(8192 * 2);
    u16*   wfu_bf = (u16*)alloc(32768 * 2);
    u16*   wout_bf= (u16*)alloc(32768 * 2);
    u16*   wtap   = (u16*)alloc(9 * 2048 * 2);

    dim3 blk(256);

    fold_ln<<<dim3(28), dim3(64), 0, stream>>>(w_qkv, ln1w, ln1b, w_in_, ln2w, ln2b,
                                               fq_bf, fqB, ff_bf, ffB);
    prep_misc<<<dim3(89), blk, 0, stream>>>(w_ir, w_vi, w_fu, w_out_, w_h1,
                                            wir_bf, wvi_bf, wfu_bf, wout_bf, wtap);

    for (int b0 = 0; b0 < 4; b0 += bInner) {
        const float* inpB    = inp + (long)b0 * NP;
        const float* baseB   = base + (long)b0 * 64 * NP;
        const float* detailB = detail + (long)b0 * 64 * NP;
        float* out0  = out + (long)b0 * NP;
        float* outX0 = out + 262144 + (long)b0 * 64 * NP;

        // ---- CIIM ----
        hipMemsetAsync(means, 0, (size_t)nb * 384 * 4, stream);
        gemm_irvi<<<dim3(4, 256, nb), blk, 0, stream>>>(
            baseB, detailB, wir_bf, wvi_bf, Y, means);
        // fuse conv: Y[0:256] -> Dq[0:128]
        gemm_plain<<<dim3(2, 256, nb), blk, 0, stream>>>(
            Y, 256 * NP, wfu_bf, b_fu, Dq, 128 * NP, 256);
        // grouped dw: Dq[0:128] (+means) -> hl in Y[128:192] (dead region)
        ciim_dw_strip<<<dim3(16, 64, nb), blk, 0, stream>>>(
            Dq, 128 * NP, means, w_dwc, b_dwc, Y + 128 * NP, 256 * NP);
        // gating/shuffle: hl=Y[128:192] + base/detail -> Y[0:128], ecam
        outsh4<<<dim3(64, 128, nb), blk, 0, stream>>>(
            Y + 128 * NP, 256 * NP, baseB, 64 * NP, detailB, Y, 256 * NP, ecam);
        rc2w_build<<<dim3(nb * 32), blk, 0, stream>>>(ecam, eca_w, w_rc2, rc2wb);
        // rc2 gemm (reads Y[0:128], dual->outX0 fp32) + LN + qkv -> Y[0:192]
        gemm_fused<0, 0, 1, 192><<<dim3(512, 1, nb), blk, 0, stream>>>(
            Y, 256 * NP, rc2wb, 8192, nullptr, X, outX0,
            fq_bf, fqB, Y, nullptr, nullptr, nullptr, 128);

        // ---- transformer blocks ----
        for (int i = 0; i < 4; ++i) {
            // dw on Y[0:192]: q,k -> Dq[0:128]; v -> Y[192:256]
            dw3x3_strip<<<dim3(16, 192, nb), blk, 0, stream>>>(
                Y, 256 * NP, w_qdw + (long)i * 192 * 9,
                Dq, 128 * NP, Y, 256 * NP, 192, 128);
            qk_dot<<<dim3(QKCH, 8, nb), blk, 0, stream>>>(Dq, 128 * NP, part);
            // pv gemm (weff prologue, v from Y[192:256], resid X) + LN + ffn-in -> Y[0:256]
            gemm_fused<1, 1, 0, 256><<<dim3(512, 1, nb), blk, 0, stream>>>(
                Y + 192 * NP, 256 * NP, nullptr, 0, X, X, nullptr,
                ff_bf + (long)i * 256 * 64, ffB + i * 256, Y,
                part, temp + i * 8, w_proj + (long)i * 4096, 64);
            // ffn dw+glu: Y[0:256] -> Dq[0:128]
            ffn_dw_glu_strip<<<dim3(16, 128, nb), blk, 0, stream>>>(
                Y, 256 * NP, w_fdw + (long)i * 256 * 9, Dq, 128 * NP);
            if (i < 3) {
                // ffn-out (reads Dq, resid X) + LN + next qkv -> Y[0:192]
                gemm_fused<0, 1, 0, 192><<<dim3(512, 1, nb), blk, 0, stream>>>(
                    Dq, 128 * NP, wout_bf + (long)i * 8192, 0, X, X, nullptr,
                    fq_bf + (long)(i + 1) * 192 * 64, fqB + (i + 1) * 192, Y,
                    nullptr, nullptr, nullptr, 128);
            } else {
                gemm_fused<0, 1, 0, 0><<<dim3(512, 1, nb), blk, 0, stream>>>(
                    Dq, 128 * NP, wout_bf + (long)i * 8192, 0, X, X, nullptr,
                    nullptr, nullptr, nullptr, nullptr, nullptr, nullptr, 128);
            }
        }

        // ---- head ----
        head_fused<<<dim3(19, 19, nb), blk, 0, stream>>>(X, wtap, w_h2, inpB, out0);
    }
}

// Round 13
// 1635.755 us; speedup vs baseline: 2.1238x; 1.0765x over previous
//
#include <hip/hip_runtime.h>
#include <hip/hip_bf16.h>
#include <math.h>

#define NP 65536L
#define HHH 256
#define WWW 256
#define QKCH 32

typedef unsigned short u16;
typedef unsigned short ushort8_t __attribute__((ext_vector_type(8)));
typedef short s16x8 __attribute__((ext_vector_type(8)));
typedef float f32x4 __attribute__((ext_vector_type(4)));

__device__ __forceinline__ float bf2f(u16 u) { return __uint_as_float(((unsigned)u) << 16); }
__device__ __forceinline__ u16 f2bf(float f) {
    __hip_bfloat16 h = __float2bfloat16(f);
    return *reinterpret_cast<u16*>(&h);
}
__device__ __forceinline__ float sigmoidf_(float x) { return 1.f / (1.f + __expf(-x)); }
__device__ __forceinline__ float gelu_exact(float x) {
    return 0.5f * x * (1.f + erff(x * 0.70710678118654752f));
}

__global__ void diag_kernel(float* out, float v) {
    if (threadIdx.x == 0 && blockIdx.x == 0) out[0] = v;
}

// one-shot weight prep: bf16 casts of 4 weight tensors + wtap rearrange.
__global__ __launch_bounds__(256) void prep_misc(
    const float* __restrict__ wir, const float* __restrict__ wvi,
    const float* __restrict__ wfu, const float* __restrict__ wout,
    const float* __restrict__ wh1,
    u16* __restrict__ dir, u16* __restrict__ dvi,
    u16* __restrict__ dfu, u16* __restrict__ dout,
    u16* __restrict__ wtap)
{
    int bid = blockIdx.x;
    if (bid < 80) {
        long e = (long)bid * 1024 + threadIdx.x * 4;
        const float* src; u16* dst; long off;
        if (e < 8192)       { src = wir;  dst = dir;  off = 0; }
        else if (e < 16384) { src = wvi;  dst = dvi;  off = 8192; }
        else if (e < 49152) { src = wfu;  dst = dfu;  off = 16384; }
        else                { src = wout; dst = dout; off = 49152; }
        long i = e - off;
        float4 v = *(const float4*)(src + i);
        ushort4 o;
        o.x = f2bf(v.x); o.y = f2bf(v.y); o.z = f2bf(v.z); o.w = f2bf(v.w);
        *(ushort4*)(dst + i) = o;
    } else {
        int tap = bid - 80;
        for (int e = threadIdx.x; e < 2048; e += 256)
            wtap[tap * 2048 + e] = f2bf(wh1[(long)e * 9 + tap]);
    }
}

// fold LN gamma/beta into qkv / ffn-in weights; bf16 weights + fp32 bias.
__global__ void fold_ln(
    const float* __restrict__ wqkv, const float* __restrict__ ln1w, const float* __restrict__ ln1b,
    const float* __restrict__ win,  const float* __restrict__ ln2w, const float* __restrict__ ln2b,
    u16* __restrict__ fq, float* __restrict__ fqB,
    u16* __restrict__ ff, float* __restrict__ ffB)
{
    int g = blockIdx.x;
    int i = g / 7, r = g % 7;
    const float *wsrc, *lg, *lb;
    u16* wd; float* Bd;
    int obase;
    if (r < 3) {
        wsrc = wqkv + (long)i * 192 * 64; lg = ln1w + i * 64; lb = ln1b + i * 64;
        wd = fq + (long)i * 192 * 64; Bd = fqB + i * 192; obase = r * 64;
    } else {
        wsrc = win + (long)i * 256 * 64; lg = ln2w + i * 64; lb = ln2b + i * 64;
        wd = ff + (long)i * 256 * 64; Bd = ffB + i * 256; obase = (r - 3) * 64;
    }
    int o = obase + threadIdx.x;
    float Bv = 0.f;
    for (int c = 0; c < 64; ++c) {
        float wv = wsrc[(long)o * 64 + c];
        wd[(long)o * 64 + c] = f2bf(wv * lg[c]);
        Bv += wv * lb[c];
    }
    Bd[o] = Bv;
}

// ---------------------------------------------------------------------------
// CIIM input GEMMs (ir + vi in one dispatch) + fused per-channel means atomic.
// grid (4, 256, nb).
// ---------------------------------------------------------------------------
__global__ __launch_bounds__(256) void gemm_irvi(
    const float* __restrict__ base, const float* __restrict__ detail,
    const u16* __restrict__ wir, const u16* __restrict__ wvi,
    u16* __restrict__ Y, float* __restrict__ means)
{
    __shared__ u16 XT[256][72];
    __shared__ u16 WT[64][72];
    __shared__ float red[4][64];
    int xsel = blockIdx.x, b = blockIdx.z;
    long P0 = (long)blockIdx.y * 256;
    int tid = threadIdx.x, lane = tid & 63, wave = tid >> 6;
    int rl = lane & 15, rg = lane >> 4;
    const float* in = ((xsel < 2) ? base : detail) + (long)b * 64 * NP;
    const u16* wsel = (xsel < 2) ? wir : wvi;
    int orow0 = (xsel & 1) * 64;
    int ochan0 = xsel * 64;

    {
        int o = tid >> 2, cs = (tid & 3) * 16;
        const u16* src = wsel + (long)(orow0 + o) * 64 + cs;
        *(ushort8_t*)&WT[o][cs] = *(const ushort8_t*)src;
        *(ushort8_t*)&WT[o][cs + 8] = *(const ushort8_t*)(src + 8);
    }
    {
        int c0 = (tid & 7) * 8;
        int pt = (tid >> 3) * 8;
        u16 rr[8][8];
#pragma unroll
        for (int i = 0; i < 8; ++i) {
            const float* sp = in + (long)(c0 + i) * NP + P0 + pt;
            float4 a = *(const float4*)sp;
            float4 b4 = *(const float4*)(sp + 4);
            rr[i][0] = f2bf(a.x); rr[i][1] = f2bf(a.y);
            rr[i][2] = f2bf(a.z); rr[i][3] = f2bf(a.w);
            rr[i][4] = f2bf(b4.x); rr[i][5] = f2bf(b4.y);
            rr[i][6] = f2bf(b4.z); rr[i][7] = f2bf(b4.w);
        }
#pragma unroll
        for (int j = 0; j < 8; ++j) {
            ushort8_t v;
#pragma unroll
            for (int i = 0; i < 8; ++i) v[i] = rr[i][j];
            *(ushort8_t*)&XT[pt + j][c0] = v;
        }
    }
    __syncthreads();
    f32x4 acc[4][4];
#pragma unroll
    for (int m = 0; m < 4; ++m)
#pragma unroll
        for (int n = 0; n < 4; ++n) acc[m][n] = (f32x4){0.f, 0.f, 0.f, 0.f};
#pragma unroll
    for (int ks = 0; ks < 2; ++ks) {
        int kc = ks * 32 + rg * 8;
        s16x8 a[4], bb[4];
#pragma unroll
        for (int m = 0; m < 4; ++m) a[m] = *(const s16x8*)&WT[m * 16 + rl][kc];
#pragma unroll
        for (int n = 0; n < 4; ++n) bb[n] = *(const s16x8*)&XT[wave * 64 + n * 16 + rl][kc];
#pragma unroll
        for (int m = 0; m < 4; ++m)
#pragma unroll
            for (int n = 0; n < 4; ++n)
                acc[m][n] = __builtin_amdgcn_mfma_f32_16x16x32_bf16(a[m], bb[n], acc[m][n], 0, 0, 0);
    }
    float csum[4][4];
#pragma unroll
    for (int m = 0; m < 4; ++m)
#pragma unroll
        for (int r = 0; r < 4; ++r) csum[m][r] = 0.f;
#pragma unroll
    for (int m = 0; m < 4; ++m)
#pragma unroll
        for (int n = 0; n < 4; ++n) {
            long px = P0 + wave * 64 + n * 16 + rl;
#pragma unroll
            for (int r = 0; r < 4; ++r) {
                int oo = ochan0 + m * 16 + rg * 4 + r;
                float v = acc[m][n][r];
                Y[((long)b * 256 + oo) * NP + px] = f2bf(v);
                csum[m][r] += v;
            }
        }
#pragma unroll
    for (int m = 0; m < 4; ++m)
#pragma unroll
        for (int r = 0; r < 4; ++r) {
            float s = csum[m][r];
            s += __shfl_xor(s, 1); s += __shfl_xor(s, 2);
            s += __shfl_xor(s, 4); s += __shfl_xor(s, 8);
            if (rl == 0) red[wave][m * 16 + rg * 4 + r] = s;
        }
    __syncthreads();
    if (tid < 64) {
        float v = red[0][tid] + red[1][tid] + red[2][tid] + red[3][tid];
        atomicAdd(&means[b * 256 + ochan0 + tid], v * (1.f / NP));
    }
}

// plain MFMA GEMM (fuse conv). grid (Cout/64, 256, nb)
__global__ __launch_bounds__(256) void gemm_plain(
    const u16* __restrict__ in, long inBS,
    const u16* __restrict__ wbf,
    const float* __restrict__ bias,
    u16* __restrict__ outp, long outBS, int Cin)
{
    __shared__ u16 XT[256][72];
    __shared__ u16 WT[64][72];
    int b = blockIdx.z;
    int oBase = blockIdx.x * 64;
    long P0 = (long)blockIdx.y * 256;
    int tid = threadIdx.x, lane = tid & 63, wave = tid >> 6;
    int rl = lane & 15, rg = lane >> 4;
    const u16* inB = in + (long)b * inBS;
    f32x4 acc[4][4];
#pragma unroll
    for (int m = 0; m < 4; ++m)
#pragma unroll
        for (int n = 0; n < 4; ++n) acc[m][n] = (f32x4){0.f, 0.f, 0.f, 0.f};
    for (int ck = 0; ck < Cin; ck += 64) {
        if (ck) __syncthreads();
        {
            int o = tid >> 2, cs = (tid & 3) * 16;
            const u16* src = wbf + (long)(oBase + o) * Cin + ck + cs;
            *(ushort8_t*)&WT[o][cs] = *(const ushort8_t*)src;
            *(ushort8_t*)&WT[o][cs + 8] = *(const ushort8_t*)(src + 8);
        }
        {
            int c0 = (tid & 7) * 8;
            int pt = (tid >> 3) * 8;
            ushort8_t r[8];
#pragma unroll
            for (int i = 0; i < 8; ++i)
                r[i] = *(const ushort8_t*)(inB + (long)(ck + c0 + i) * NP + P0 + pt);
#pragma unroll
            for (int j = 0; j < 8; ++j) {
                ushort8_t v;
#pragma unroll
                for (int i = 0; i < 8; ++i) v[i] = r[i][j];
                *(ushort8_t*)&XT[pt + j][c0] = v;
            }
        }
        __syncthreads();
#pragma unroll
        for (int ks = 0; ks < 2; ++ks) {
            int kc = ks * 32 + rg * 8;
            s16x8 a[4], bb[4];
#pragma unroll
            for (int m = 0; m < 4; ++m) a[m] = *(const s16x8*)&WT[m * 16 + rl][kc];
#pragma unroll
            for (int n = 0; n < 4; ++n) bb[n] = *(const s16x8*)&XT[wave * 64 + n * 16 + rl][kc];
#pragma unroll
            for (int m = 0; m < 4; ++m)
#pragma unroll
                for (int n = 0; n < 4; ++n)
                    acc[m][n] = __builtin_amdgcn_mfma_f32_16x16x32_bf16(a[m], bb[n], acc[m][n], 0, 0, 0);
        }
    }
#pragma unroll
    for (int m = 0; m < 4; ++m) {
#pragma unroll
        for (int n = 0; n < 4; ++n) {
            long px = P0 + wave * 64 + n * 16 + rl;
#pragma unroll
            for (int r = 0; r < 4; ++r) {
                int oo = oBase + m * 16 + rg * 4 + r;
                outp[(long)b * outBS + (long)oo * NP + px] = f2bf(acc[m][n][r] + bias[oo]);
            }
        }
    }
}

// ---------------------------------------------------------------------------
// Fused GEMM -> X -> LN -> LDS -> second GEMM -> Y(bf16).
// 128-px tiles. grid (512, 1, nb). PIXMAJ: write X pixel-major [px][c]
// (via LDS transpose; no channel-major store) for head consumption.
// ---------------------------------------------------------------------------
template<int WEFF, int RESID, int DUAL, int M2, int PIXMAJ>
__global__ __launch_bounds__(256) void gemm_fused(
    const u16* __restrict__ in, long inBS,
    const u16* __restrict__ w1, long w1BS,
    const u16* __restrict__ residX,
    u16* __restrict__ Xout,
    float* __restrict__ out2,
    const u16* __restrict__ w2, const float* __restrict__ bias2,
    u16* __restrict__ Yout,
    const float* __restrict__ part, const float* __restrict__ temp,
    const float* __restrict__ wproj,
    int Cin)
{
    __shared__ u16 XT[128][72] __attribute__((aligned(16)));
    __shared__ u16 WT[64][72] __attribute__((aligned(16)));
    int b = blockIdx.z;
    long P0 = (long)blockIdx.x * 128;
    int tid = threadIdx.x, lane = tid & 63, wave = tid >> 6;
    int rl = lane & 15, rg = lane >> 4;
    const u16* inB = in + (long)b * inBS;

    if constexpr (WEFF) {
        float* SgF = (float*)&XT[0][0];
        float* attF = SgF + 640;
        for (int e = tid; e < 640; e += 256) {
            int h = e / 80, k = e % 80;
            const float* pp = part + (((long)b * 8 + h) * 80 + k) * QKCH;
            float s = 0.f;
#pragma unroll
            for (int c = 0; c < QKCH; ++c) s += pp[c];
            SgF[e] = s;
        }
        __syncthreads();
        if (tid < 64) {
            int h = tid >> 3, iq = tid & 7;
            float nqv = fmaxf(sqrtf(SgF[h * 80 + 64 + iq]), 1e-12f);
            float tp = temp[h];
            float row[8], mx = -1e30f;
#pragma unroll
            for (int jj = 0; jj < 8; ++jj) {
                float nkv = fmaxf(sqrtf(SgF[h * 80 + 72 + jj]), 1e-12f);
                row[jj] = SgF[h * 80 + iq * 8 + jj] / (nqv * nkv) * tp;
                mx = fmaxf(mx, row[jj]);
            }
            float sum = 0.f;
#pragma unroll
            for (int jj = 0; jj < 8; ++jj) { row[jj] = __expf(row[jj] - mx); sum += row[jj]; }
            float rinv = 1.f / sum;
#pragma unroll
            for (int jj = 0; jj < 8; ++jj) attF[(h * 8 + iq) * 8 + jj] = row[jj] * rinv;
        }
        __syncthreads();
        {
            int o = tid >> 2;
            int cv0 = (tid & 3) * 16;
#pragma unroll
            for (int cv = 0; cv < 16; ++cv) {
                int c = cv0 + cv;
                int h = c >> 3, jj = c & 7;
                float s = 0.f;
#pragma unroll
                for (int i = 0; i < 8; ++i)
                    s = fmaf(wproj[o * 64 + h * 8 + i], attF[(h * 8 + i) * 8 + jj], s);
                WT[o][c] = f2bf(s);
            }
        }
        __syncthreads();
    }

    f32x4 acc[4][2];
#pragma unroll
    for (int m = 0; m < 4; ++m)
#pragma unroll
        for (int n = 0; n < 2; ++n) acc[m][n] = (f32x4){0.f, 0.f, 0.f, 0.f};

    for (int ck = 0; ck < Cin; ck += 64) {
        if (ck) __syncthreads();
        if constexpr (!WEFF) {
            int o = tid >> 2, cs = (tid & 3) * 16;
            const u16* src = w1 + (long)b * w1BS + (long)o * Cin + ck + cs;
            *(ushort8_t*)&WT[o][cs] = *(const ushort8_t*)src;
            *(ushort8_t*)&WT[o][cs + 8] = *(const ushort8_t*)(src + 8);
        }
        if (tid < 128) {
            int c0 = (tid & 7) * 8;
            int pt = (tid >> 3) * 8;
            ushort8_t r[8];
#pragma unroll
            for (int i = 0; i < 8; ++i)
                r[i] = *(const ushort8_t*)(inB + (long)(ck + c0 + i) * NP + P0 + pt);
#pragma unroll
            for (int j = 0; j < 8; ++j) {
                ushort8_t v;
#pragma unroll
                for (int i = 0; i < 8; ++i) v[i] = r[i][j];
                *(ushort8_t*)&XT[pt + j][c0] = v;
            }
        }
        __syncthreads();
#pragma unroll
        for (int ks = 0; ks < 2; ++ks) {
            int kc = ks * 32 + rg * 8;
            s16x8 a[4], bb[2];
#pragma unroll
            for (int m = 0; m < 4; ++m) a[m] = *(const s16x8*)&WT[m * 16 + rl][kc];
#pragma unroll
            for (int n = 0; n < 2; ++n) bb[n] = *(const s16x8*)&XT[wave * 32 + n * 16 + rl][kc];
#pragma unroll
            for (int m = 0; m < 4; ++m)
#pragma unroll
                for (int n = 0; n < 2; ++n)
                    acc[m][n] = __builtin_amdgcn_mfma_f32_16x16x32_bf16(a[m], bb[n], acc[m][n], 0, 0, 0);
        }
    }

    // epilogue 1: resid (+X store channel-major unless PIXMAJ) (+dual fp32)
#pragma unroll
    for (int m = 0; m < 4; ++m)
#pragma unroll
        for (int n = 0; n < 2; ++n) {
            long px = P0 + wave * 32 + n * 16 + rl;
#pragma unroll
            for (int r = 0; r < 4; ++r) {
                int oo = m * 16 + rg * 4 + r;
                float t = acc[m][n][r];
                if constexpr (RESID) t += bf2f(residX[((long)b * 64 + oo) * NP + px]);
                acc[m][n][r] = t;
                if constexpr (!PIXMAJ) Xout[((long)b * 64 + oo) * NP + px] = f2bf(t);
                if constexpr (DUAL) out2[((long)b * 64 + oo) * NP + px] = t;
            }
        }

    if constexpr (PIXMAJ) {
        __syncthreads();
#pragma unroll
        for (int m = 0; m < 4; ++m)
#pragma unroll
            for (int n = 0; n < 2; ++n) {
                int pxl = wave * 32 + n * 16 + rl;
#pragma unroll
                for (int r = 0; r < 4; ++r)
                    XT[pxl][m * 16 + rg * 4 + r] = f2bf(acc[m][n][r]);
            }
        __syncthreads();
        int pxl = tid >> 1, c0 = (tid & 1) * 32;
        u16* dst = Xout + (long)b * (64 * NP) + (P0 + pxl) * 64 + c0;
        *(ushort8_t*)(dst)      = *(const ushort8_t*)&XT[pxl][c0];
        *(ushort8_t*)(dst + 8)  = *(const ushort8_t*)&XT[pxl][c0 + 8];
        *(ushort8_t*)(dst + 16) = *(const ushort8_t*)&XT[pxl][c0 + 16];
        *(ushort8_t*)(dst + 24) = *(const ushort8_t*)&XT[pxl][c0 + 24];
    }

    if constexpr (M2 > 0) {
        float muA[2], invA[2];
#pragma unroll
        for (int n = 0; n < 2; ++n) {
            float s = 0.f, s2 = 0.f;
#pragma unroll
            for (int m = 0; m < 4; ++m)
#pragma unroll
                for (int r = 0; r < 4; ++r) {
                    float t = acc[m][n][r];
                    s += t; s2 = fmaf(t, t, s2);
                }
            s += __shfl_xor(s, 16);  s += __shfl_xor(s, 32);
            s2 += __shfl_xor(s2, 16); s2 += __shfl_xor(s2, 32);
            float mu = s * (1.f / 64.f);
            float var = fmaxf(s2 * (1.f / 64.f) - mu * mu, 0.f);
            muA[n] = mu;
            invA[n] = rsqrtf(var + 1e-5f);
        }
        __syncthreads();
#pragma unroll
        for (int m = 0; m < 4; ++m)
#pragma unroll
            for (int n = 0; n < 2; ++n) {
                int pxl = wave * 32 + n * 16 + rl;
#pragma unroll
                for (int r = 0; r < 4; ++r)
                    XT[pxl][m * 16 + rg * 4 + r] = f2bf((acc[m][n][r] - muA[n]) * invA[n]);
            }
        __syncthreads();
        for (int mc = 0; mc < M2 / 64; ++mc) {
            if (mc) __syncthreads();
            {
                int o = tid >> 2, cs = (tid & 3) * 16;
                const u16* src = w2 + (long)(mc * 64 + o) * 64 + cs;
                *(ushort8_t*)&WT[o][cs] = *(const ushort8_t*)src;
                *(ushort8_t*)&WT[o][cs + 8] = *(const ushort8_t*)(src + 8);
            }
            __syncthreads();
            f32x4 a2[4][2];
#pragma unroll
            for (int m = 0; m < 4; ++m)
#pragma unroll
                for (int n = 0; n < 2; ++n) a2[m][n] = (f32x4){0.f, 0.f, 0.f, 0.f};
#pragma unroll
            for (int ks = 0; ks < 2; ++ks) {
                int kc = ks * 32 + rg * 8;
                s16x8 a[4], bb[2];
#pragma unroll
                for (int m = 0; m < 4; ++m) a[m] = *(const s16x8*)&WT[m * 16 + rl][kc];
#pragma unroll
                for (int n = 0; n < 2; ++n) bb[n] = *(const s16x8*)&XT[wave * 32 + n * 16 + rl][kc];
#pragma unroll
                for (int m = 0; m < 4; ++m)
#pragma unroll
                    for (int n = 0; n < 2; ++n)
                        a2[m][n] = __builtin_amdgcn_mfma_f32_16x16x32_bf16(a[m], bb[n], a2[m][n], 0, 0, 0);
            }
#pragma unroll
            for (int m = 0; m < 4; ++m) {
#pragma unroll
                for (int n = 0; n < 2; ++n) {
                    long px = P0 + wave * 32 + n * 16 + rl;
#pragma unroll
                    for (int r = 0; r < 4; ++r) {
                        int oo = mc * 64 + m * 16 + rg * 4 + r;
                        Yout[((long)b * 256 + oo) * NP + px] = f2bf(a2[m][n][r] + bias2[oo]);
                    }
                }
            }
        }
    }
}

// stage one LDS row (16 px) of a bf16 channel strip
__device__ __forceinline__ void stage_row(float (*S)[260], const u16* __restrict__ src,
                                          int y0, int j, int px)
{
    int row = y0 - 1 + j;
    if (row >= 0 && row < HHH) {
        ushort8_t a = *(const ushort8_t*)(src + row * WWW + px);
        ushort8_t b = *(const ushort8_t*)(src + row * WWW + px + 8);
#pragma unroll
        for (int e = 0; e < 8; ++e) { S[j][1 + px + e] = bf2f(a[e]); S[j][9 + px + e] = bf2f(b[e]); }
    } else {
#pragma unroll
        for (int e = 0; e < 16; ++e) S[j][1 + px + e] = 0.f;
    }
}
__device__ __forceinline__ float conv9(const float (*S)[260], int r, int col,
                                       const float* __restrict__ w9)
{
    float a = 0.f;
#pragma unroll
    for (int ky = 0; ky < 3; ++ky)
#pragma unroll
        for (int kx = 0; kx < 3; ++kx)
            a = fmaf(w9[ky * 3 + kx], S[r + ky][col + kx], a);
    return a;
}

// depthwise 3x3, 16-row strips, vectorized stores, split output routing.
// grid (16, C, nb)
__global__ __launch_bounds__(256) void dw3x3_strip(
    const u16* __restrict__ in, long inBS, const float* __restrict__ w,
    u16* __restrict__ out1, long out1BS,
    u16* __restrict__ out2, long out2BS, int obase2, int csplit)
{
    int strip = blockIdx.x, c = blockIdx.y, b = blockIdx.z;
    int y0 = strip * 16, tid = threadIdx.x;
    __shared__ float S[18][260];
    const u16* src = in + (long)b * inBS + (long)c * NP;
    int j = tid >> 4, px = (tid & 15) * 16;
    stage_row(S, src, y0, j, px);
    if (tid < 32) stage_row(S, src, y0, 16 + (tid >> 4), px);
    if (tid < 18) { S[tid][0] = 0.f; S[tid][257] = 0.f; }
    __syncthreads();
    float w9[9];
#pragma unroll
    for (int k = 0; k < 9; ++k) w9[k] = w[c * 9 + k];
    u16* dst = (c < csplit)
                   ? out1 + (long)b * out1BS + (long)c * NP
                   : out2 + (long)b * out2BS + (long)(obase2 + c - csplit) * NP;
    int px4 = (tid & 63) * 4;
    int r0 = (tid >> 6) * 4;
#pragma unroll
    for (int r = 0; r < 4; ++r) {
        int row = r0 + r;
        ushort4 ovec;
        u16* ov = (u16*)&ovec;
#pragma unroll
        for (int e = 0; e < 4; ++e) ov[e] = f2bf(conv9(S, row, px4 + e, w9));
        *(ushort4*)&dst[(y0 + row) * WWW + px4] = ovec;
    }
}

// ffn: dw3x3 on (c, c+128) + gelu(y1)*y2, strips, vectorized. grid (16, 128, nb)
__global__ __launch_bounds__(256) void ffn_dw_glu_strip(
    const u16* __restrict__ y, long yBS, const float* __restrict__ w,
    u16* __restrict__ g, long gBS)
{
    int strip = blockIdx.x, c = blockIdx.y, b = blockIdx.z;
    int y0 = strip * 16, tid = threadIdx.x;
    __shared__ float S1[18][260];
    __shared__ float S2[18][260];
    const u16* s1 = y + (long)b * yBS + (long)c * NP;
    const u16* s2 = y + (long)b * yBS + (long)(c + 128) * NP;
    int j = tid >> 4, px = (tid & 15) * 16;
    stage_row(S1, s1, y0, j, px);
    if (tid < 32) stage_row(S1, s1, y0, 16 + (tid >> 4), px);
    stage_row(S2, s2, y0, j, px);
    if (tid < 32) stage_row(S2, s2, y0, 16 + (tid >> 4), px);
    if (tid < 18) { S1[tid][0] = S1[tid][257] = 0.f; S2[tid][0] = S2[tid][257] = 0.f; }
    __syncthreads();
    float w1[9], w2[9];
#pragma unroll
    for (int k = 0; k < 9; ++k) { w1[k] = w[c * 9 + k]; w2[k] = w[(c + 128) * 9 + k]; }
    u16* dst = g + (long)b * gBS + (long)c * NP;
    int px4 = (tid & 63) * 4;
    int r0 = (tid >> 6) * 4;
#pragma unroll
    for (int r = 0; r < 4; ++r) {
        int row = r0 + r;
        ushort4 ovec;
        u16* ov = (u16*)&ovec;
#pragma unroll
        for (int e = 0; e < 4; ++e) {
            float a1 = conv9(S1, row, px4 + e, w1);
            float a2 = conv9(S2, row, px4 + e, w2);
            ov[e] = f2bf(gelu_exact(a1) * a2);
        }
        *(ushort4*)&dst[(y0 + row) * WWW + px4] = ovec;
    }
}

// CIIM grouped dw conv + gating + channel shuffle + ecam atomics, strips.
// channel c -> Y[cn1] (h_map*low), Y[cn1+16] (l_map*high). grid (16, 64, nb)
__global__ __launch_bounds__(256) void ciim_dw_gate(
    const u16* __restrict__ fuse, long fBS, const float* __restrict__ means,
    const float* __restrict__ wdw, const float* __restrict__ bdw,
    const float* __restrict__ low, long lBS, const float* __restrict__ high,
    u16* __restrict__ Yout, long yBS, float* __restrict__ ecam)
{
    int strip = blockIdx.x, c = blockIdx.y, b = blockIdx.z;
    int y0 = strip * 16, tid = threadIdx.x;
    __shared__ float S[18][260];
    int px4 = (tid & 63) * 4;
    int r0 = (tid >> 6) * 4;
    float acc[4][4];
    float bias = bdw[c];
#pragma unroll
    for (int r = 0; r < 4; ++r)
#pragma unroll
        for (int e = 0; e < 4; ++e) acc[r][e] = bias;
    for (int j6 = 0; j6 < 6; ++j6) {
        int ic = 6 * c + j6;
        const float* w9p = wdw + (c * 6 + j6) * 9;
        float w9[9];
#pragma unroll
        for (int k = 0; k < 9; ++k) w9[k] = w9p[k];
        if (ic < 128) {
            __syncthreads();
            const u16* src = fuse + (long)b * fBS + (long)ic * NP;
            int j = tid >> 4, px = (tid & 15) * 16;
            stage_row(S, src, y0, j, px);
            if (tid < 32) stage_row(S, src, y0, 16 + (tid >> 4), px);
            if (tid < 18) { S[tid][0] = 0.f; S[tid][257] = 0.f; }
            __syncthreads();
#pragma unroll
            for (int r = 0; r < 4; ++r)
#pragma unroll
                for (int e = 0; e < 4; ++e) acc[r][e] += conv9(S, r0 + r, px4 + e, w9);
        } else {
            float mv = means[b * 256 + ic - 128];
#pragma unroll
            for (int r = 0; r < 4; ++r) {
                int row = y0 + r0 + r;
#pragma unroll
                for (int e = 0; e < 4; ++e) {
                    int xc = px4 + e;
                    float ws = 0.f;
#pragma unroll
                    for (int ky = 0; ky < 3; ++ky) {
                        int yy = row + ky - 1;
                        if (yy < 0 || yy >= HHH) continue;
#pragma unroll
                        for (int kx = 0; kx < 3; ++kx) {
                            int xx = xc + kx - 1;
                            if (xx < 0 || xx >= WWW) continue;
                            ws += w9[ky * 3 + kx];
                        }
                    }
                    acc[r][e] += mv * ws;
                }
            }
        }
    }
    // gating + shuffle: cn1 gets sig(gelu(hl))*low[c], cn1+16 gets sig(relu(hl))*high[c]
    int cn1 = 32 * (c & 3) + (c >> 2);
    int cn2 = cn1 + 16;
    u16* d1 = Yout + (long)b * yBS + (long)cn1 * NP;
    u16* d2 = Yout + (long)b * yBS + (long)cn2 * NP;
    const float* lp = low + (long)b * lBS + (long)c * NP;
    const float* hp = high + (long)b * lBS + (long)c * NP;
    float s1 = 0.f, s2 = 0.f;
#pragma unroll
    for (int r = 0; r < 4; ++r) {
        int row = y0 + r0 + r;
        float4 lv = *(const float4*)(lp + row * WWW + px4);
        float4 hv = *(const float4*)(hp + row * WWW + px4);
        float l4[4] = {lv.x, lv.y, lv.z, lv.w};
        float h4[4] = {hv.x, hv.y, hv.z, hv.w};
        ushort4 o1, o2;
        u16* p1 = (u16*)&o1;
        u16* p2 = (u16*)&o2;
#pragma unroll
        for (int e = 0; e < 4; ++e) {
            float hl = acc[r][e];
            float v1 = sigmoidf_(gelu_exact(hl)) * l4[e];
            float v2 = sigmoidf_(fmaxf(hl, 0.f)) * h4[e];
            p1[e] = f2bf(v1); p2[e] = f2bf(v2);
            s1 += v1; s2 += v2;
        }
        *(ushort4*)&d1[row * WWW + px4] = o1;
        *(ushort4*)&d2[row * WWW + px4] = o2;
    }
    __syncthreads();
    float* redbuf = &S[0][0];
    redbuf[tid] = s1; redbuf[256 + tid] = s2;
    __syncthreads();
    for (int st = 128; st > 0; st >>= 1) {
        if (tid < st) { redbuf[tid] += redbuf[tid + st]; redbuf[256 + tid] += redbuf[256 + tid + st]; }
        __syncthreads();
    }
    if (tid == 0) {
        atomicAdd(&ecam[b * 128 + cn1], redbuf[0] * (1.f / NP));
        atomicAdd(&ecam[b * 128 + cn2], redbuf[256] * (1.f / NP));
    }
}

// scaled rc2 weights (bf16). grid (nb*32)
__global__ __launch_bounds__(256) void rc2w_build(
    const float* __restrict__ ecam, const float* __restrict__ ecaw,
    const float* __restrict__ wrc2, u16* __restrict__ wout)
{
    int idx = blockIdx.x * 256 + threadIdx.x;
    int c = idx & 127, o = (idx >> 7) & 63, b = idx >> 13;
    float y = sigmoidf_(ecam[b * 128 + c] * ecaw[c]);
    wout[idx] = f2bf(wrc2[o * 128 + c] * y);
}

// q.k dots + sumsq norms over pixel chunks. grid (QKCH, 8, nb)
__global__ __launch_bounds__(256) void qk_dot(
    const u16* __restrict__ D, long dBS, float* __restrict__ part)
{
    int chunk = blockIdx.x, h = blockIdx.y, b = blockIdx.z;
    int tid = threadIdx.x, lane = tid & 63, wave = tid >> 6;
    const u16* q = D + (long)b * dBS + (long)(h * 8) * NP;
    const u16* k = q + 64 * NP;
    float dots[64], nq[8], nk[8];
#pragma unroll
    for (int a = 0; a < 64; ++a) dots[a] = 0.f;
#pragma unroll
    for (int a = 0; a < 8; ++a) { nq[a] = 0.f; nk[a] = 0.f; }
    long p = (long)chunk * 2048 + tid * 8;
    {
        ushort8_t qv[8], kv[8];
#pragma unroll
        for (int i = 0; i < 8; ++i) qv[i] = *(const ushort8_t*)(q + (long)i * NP + p);
#pragma unroll
        for (int i = 0; i < 8; ++i) kv[i] = *(const ushort8_t*)(k + (long)i * NP + p);
#pragma unroll
        for (int e = 0; e < 8; ++e) {
            float qe[8], ke[8];
#pragma unroll
            for (int i = 0; i < 8; ++i) { qe[i] = bf2f(qv[i][e]); ke[i] = bf2f(kv[i][e]); }
#pragma unroll
            for (int i = 0; i < 8; ++i) {
                nq[i] = fmaf(qe[i], qe[i], nq[i]);
                nk[i] = fmaf(ke[i], ke[i], nk[i]);
#pragma unroll
                for (int jj = 0; jj < 8; ++jj)
                    dots[i * 8 + jj] = fmaf(qe[i], ke[jj], dots[i * 8 + jj]);
            }
        }
    }
    __shared__ float red[4][80];
#pragma unroll
    for (int a = 0; a < 64; ++a) {
        float v = dots[a];
#pragma unroll
        for (int o = 32; o > 0; o >>= 1) v += __shfl_xor(v, o);
        if (lane == 0) red[wave][a] = v;
    }
#pragma unroll
    for (int a = 0; a < 8; ++a) {
        float v1 = nq[a], v2 = nk[a];
#pragma unroll
        for (int o = 32; o > 0; o >>= 1) { v1 += __shfl_xor(v1, o); v2 += __shfl_xor(v2, o); }
        if (lane == 0) { red[wave][64 + a] = v1; red[wave][72 + a] = v2; }
    }
    __syncthreads();
    if (tid < 80) {
        float v = red[0][tid] + red[1][tid] + red[2][tid] + red[3][tid];
        part[(((long)b * 8 + h) * 80 + tid) * QKCH + chunk] = v;
    }
}

// head: conv1 (MFMA) + leaky + conv2 + inp + sigmoid.
// Xp is PIXEL-MAJOR bf16 [b][px][64c]. grid (19,19,nb)
__global__ __launch_bounds__(256) void head_fused(
    const u16* __restrict__ Xp, const u16* __restrict__ wtap,
    const float* __restrict__ wh2, const float* __restrict__ inp,
    float* __restrict__ out)
{
    __shared__ u16 P[18][18][72] __attribute__((aligned(16)));
    __shared__ u16 Hl[16][16][40] __attribute__((aligned(16)));
    __shared__ float w2t[288];
    int ty = blockIdx.x, tx = blockIdx.y, b = blockIdx.z;
    int tid = threadIdx.x, lane = tid & 63, wave = tid >> 6;
    int rl = lane & 15, rg = lane >> 4;
    int oy = ty * 14 - 2, ox = tx * 14 - 2;
    for (int idx = tid; idx < 288; idx += 256)
        w2t[(idx % 9) * 32 + idx / 9] = wh2[idx];
    {
        const u16* xb = Xp + (long)b * (64 * NP);
        int c0 = (tid & 7) * 8;
        for (int pp = tid >> 3; pp < 324; pp += 32) {
            int row = pp / 18, col = pp % 18;
            int gy = oy + row, gx = ox + col;
            ushort8_t v;
            if (gy >= 0 && gy < HHH && gx >= 0 && gx < WWW)
                v = *(const ushort8_t*)(xb + ((long)(gy * WWW + gx)) * 64 + c0);
            else
                v = (ushort8_t){0, 0, 0, 0, 0, 0, 0, 0};
            *(ushort8_t*)&P[row][col][c0] = v;
        }
    }
    __syncthreads();
    f32x4 acc[2][4];
#pragma unroll
    for (int m = 0; m < 2; ++m)
#pragma unroll
        for (int n = 0; n < 4; ++n) acc[m][n] = (f32x4){0.f, 0.f, 0.f, 0.f};
#pragma unroll
    for (int tap = 0; tap < 9; ++tap) {
        int ky = tap / 3, kx = tap % 3;
#pragma unroll
        for (int ks = 0; ks < 2; ++ks) {
            int kc = ks * 32 + rg * 8;
            s16x8 a0 = *(const s16x8*)(wtap + tap * 2048 + (long)(0 + rl) * 64 + kc);
            s16x8 a1 = *(const s16x8*)(wtap + tap * 2048 + (long)(16 + rl) * 64 + kc);
#pragma unroll
            for (int n = 0; n < 4; ++n) {
                int py = wave * 4 + n;
                s16x8 bb = *(const s16x8*)&P[py + ky][kx + rl][kc];
                acc[0][n] = __builtin_amdgcn_mfma_f32_16x16x32_bf16(a0, bb, acc[0][n], 0, 0, 0);
                acc[1][n] = __builtin_amdgcn_mfma_f32_16x16x32_bf16(a1, bb, acc[1][n], 0, 0, 0);
            }
        }
    }
#pragma unroll
    for (int m = 0; m < 2; ++m)
#pragma unroll
        for (int n = 0; n < 4; ++n) {
            int py = wave * 4 + n;
            int gy = ty * 14 - 1 + py, gx = tx * 14 - 1 + rl;
            bool ok = (gy >= 0 && gy < HHH && gx >= 0 && gx < WWW);
#pragma unroll
            for (int r = 0; r < 4; ++r) {
                int o = m * 16 + rg * 4 + r;
                float v = acc[m][n][r];
                v = v > 0.f ? v : 0.01f * v;
                Hl[py][rl][o] = ok ? f2bf(v) : (u16)0;
            }
        }
    __syncthreads();
    if (tid < 196) {
        int r = tid / 14, c = tid % 14;
        int gy = ty * 14 + r, gx = tx * 14 + c;
        if (gy < HHH && gx < WWW) {
            float acc2 = 0.f;
#pragma unroll
            for (int tap = 0; tap < 9; ++tap) {
                int hy = r + tap / 3, hx = c + tap % 3;
#pragma unroll
                for (int cg = 0; cg < 4; ++cg) {
                    ushort8_t hv = *(const ushort8_t*)&Hl[hy][hx][cg * 8];
#pragma unroll
                    for (int e = 0; e < 8; ++e)
                        acc2 = fmaf(w2t[tap * 32 + cg * 8 + e], bf2f(hv[e]), acc2);
                }
            }
            float v = acc2 + inp[(long)b * NP + gy * WWW + gx];
            out[(long)b * NP + gy * WWW + gx] = 1.f / (1.f + expf(-v));
        }
    }
}

// ---------------------------------------------------------------------------
extern "C" void kernel_launch(void* const* d_in, const int* in_sizes, int n_in,
                              void* d_out, int out_size, void* d_ws, size_t ws_size,
                              hipStream_t stream)
{
    const float* inp    = (const float*)d_in[0];
    const float* base   = (const float*)d_in[1];
    const float* detail = (const float*)d_in[2];
    const float* w_ir   = (const float*)d_in[3];
    const float* w_vi   = (const float*)d_in[4];
    const float* w_fu   = (const float*)d_in[5];
    const float* b_fu   = (const float*)d_in[6];
    const float* w_dwc  = (const float*)d_in[7];
    const float* b_dwc  = (const float*)d_in[8];
    const float* eca_w  = (const float*)d_in[9];
    const float* w_rc2  = (const float*)d_in[10];
    const float* ln1w   = (const float*)d_in[11];
    const float* ln1b   = (const float*)d_in[12];
    const float* w_qkv  = (const float*)d_in[13];
    const float* w_qdw  = (const float*)d_in[14];
    const float* temp   = (const float*)d_in[15];
    const float* w_proj = (const float*)d_in[16];
    const float* ln2w   = (const float*)d_in[17];
    const float* ln2b   = (const float*)d_in[18];
    const float* w_in_  = (const float*)d_in[19];
    const float* w_fdw  = (const float*)d_in[20];
    const float* w_out_ = (const float*)d_in[21];
    const float* w_h1   = (const float*)d_in[22];
    const float* w_h2   = (const float*)d_in[23];

    float* out = (float*)d_out;

    auto needB = [&](long nb) -> size_t {
        return (size_t)nb * NP * (64 * 2 + 256 * 2 + 128 * 2) + (4u << 20);
    };
    int bInner;
    if (ws_size >= needB(4)) bInner = 4;
    else if (ws_size >= needB(2)) bInner = 2;
    else if (ws_size >= needB(1)) bInner = 1;
    else {
        diag_kernel<<<1, 64, 0, stream>>>(out, (float)(ws_size >> 20));
        return;
    }
    const long nb = bInner;

    char* p = (char*)d_ws;
    auto alloc = [&](size_t bytes) -> char* {
        char* r = p; p += (bytes + 255) & ~(size_t)255; return r;
    };
    u16*   X      = (u16*)alloc((size_t)nb * 64 * NP * 2);
    u16*   Y      = (u16*)alloc((size_t)nb * 256 * NP * 2);
    u16*   Dq     = (u16*)alloc((size_t)nb * 128 * NP * 2);
    float* part   = (float*)alloc((size_t)nb * 8 * 80 * QKCH * 4);
    float* means  = (float*)alloc((size_t)nb * 384 * 4);
    float* ecam   = means + nb * 256;
    u16*   rc2wb  = (u16*)alloc((size_t)nb * 8192 * 2);
    u16*   fq_bf  = (u16*)alloc((size_t)4 * 192 * 64 * 2);
    float* fqB    = (float*)alloc((size_t)4 * 192 * 4);
    u16*   ff_bf  = (u16*)alloc((size_t)4 * 256 * 64 * 2);
    float* ffB    = (float*)alloc((size_t)4 * 256 * 4);
    u16*   wir_bf = (u16*)alloc(8192 * 2);
    u16*   wvi_bf = (u16*)alloc(8192 * 2);
    u16*   wfu_bf = (u16*)alloc(32768 * 2);
    u16*   wout_bf= (u16*)alloc(32768 * 2);
    u16*   wtap   = (u16*)alloc(9 * 2048 * 2);

    dim3 blk(256);

    fold_ln<<<dim3(28), dim3(64), 0, stream>>>(w_qkv, ln1w, ln1b, w_in_, ln2w, ln2b,
                                               fq_bf, fqB, ff_bf, ffB);
    prep_misc<<<dim3(89), blk, 0, stream>>>(w_ir, w_vi, w_fu, w_out_, w_h1,
                                            wir_bf, wvi_bf, wfu_bf, wout_bf, wtap);

    for (int b0 = 0; b0 < 4; b0 += bInner) {
        const float* inpB    = inp + (long)b0 * NP;
        const float* baseB   = base + (long)b0 * 64 * NP;
        const float* detailB = detail + (long)b0 * 64 * NP;
        float* out0  = out + (long)b0 * NP;
        float* outX0 = out + 262144 + (long)b0 * 64 * NP;

        // ---- CIIM ----
        hipMemsetAsync(means, 0, (size_t)nb * 384 * 4, stream);
        gemm_irvi<<<dim3(4, 256, nb), blk, 0, stream>>>(
            baseB, detailB, wir_bf, wvi_bf, Y, means);
        // fuse conv: Y[0:256] -> Dq[0:128]
        gemm_plain<<<dim3(2, 256, nb), blk, 0, stream>>>(
            Y, 256 * NP, wfu_bf, b_fu, Dq, 128 * NP, 256);
        // grouped dw + gating + shuffle + ecam: Dq[0:128] -> Y[0:128]
        ciim_dw_gate<<<dim3(16, 64, nb), blk, 0, stream>>>(
            Dq, 128 * NP, means, w_dwc, b_dwc, baseB, 64 * NP, detailB,
            Y, 256 * NP, ecam);
        rc2w_build<<<dim3(nb * 32), blk, 0, stream>>>(ecam, eca_w, w_rc2, rc2wb);
        // rc2 gemm (reads Y[0:128], dual->outX0 fp32) + LN + qkv -> Y[0:192]
        gemm_fused<0, 0, 1, 192, 0><<<dim3(512, 1, nb), blk, 0, stream>>>(
            Y, 256 * NP, rc2wb, 8192, nullptr, X, outX0,
            fq_bf, fqB, Y, nullptr, nullptr, nullptr, 128);

        // ---- transformer blocks ----
        for (int i = 0; i < 4; ++i) {
            // dw on Y[0:192]: q,k -> Dq[0:128]; v -> Y[192:256]
            dw3x3_strip<<<dim3(16, 192, nb), blk, 0, stream>>>(
                Y, 256 * NP, w_qdw + (long)i * 192 * 9,
                Dq, 128 * NP, Y, 256 * NP, 192, 128);
            qk_dot<<<dim3(QKCH, 8, nb), blk, 0, stream>>>(Dq, 128 * NP, part);
            // pv gemm (weff prologue, v from Y[192:256], resid X) + LN + ffn-in -> Y[0:256]
            gemm_fused<1, 1, 0, 256, 0><<<dim3(512, 1, nb), blk, 0, stream>>>(
                Y + 192 * NP, 256 * NP, nullptr, 0, X, X, nullptr,
                ff_bf + (long)i * 256 * 64, ffB + i * 256, Y,
                part, temp + i * 8, w_proj + (long)i * 4096, 64);
            // ffn dw+glu: Y[0:256] -> Dq[0:128]
            ffn_dw_glu_strip<<<dim3(16, 128, nb), blk, 0, stream>>>(
                Y, 256 * NP, w_fdw + (long)i * 256 * 9, Dq, 128 * NP);
            if (i < 3) {
                // ffn-out (reads Dq, resid X) + LN + next qkv -> Y[0:192]
                gemm_fused<0, 1, 0, 192, 0><<<dim3(512, 1, nb), blk, 0, stream>>>(
                    Dq, 128 * NP, wout_bf + (long)i * 8192, 0, X, X, nullptr,
                    fq_bf + (long)(i + 1) * 192 * 64, fqB + (i + 1) * 192, Y,
                    nullptr, nullptr, nullptr, 128);
            } else {
                // final ffn-out: write X PIXEL-MAJOR into dead Y buffer for head
                gemm_fused<0, 1, 0, 0, 1><<<dim3(512, 1, nb), blk, 0, stream>>>(
                    Dq, 128 * NP, wout_bf + (long)i * 8192, 0, X, Y, nullptr,
                    nullptr, nullptr, nullptr, nullptr, nullptr, nullptr, 128);
            }
        }

        // ---- head (reads pixel-major X from Y) ----
        head_fused<<<dim3(19, 19, nb), blk, 0, stream>>>(Y, wtap, w_h2, inpB, out0);
    }
}

// Round 14
// 1566.349 us; speedup vs baseline: 2.2180x; 1.0443x over previous
//
#include <hip/hip_runtime.h>
#include <hip/hip_bf16.h>
#include <math.h>

#define NP 65536L
#define HHH 256
#define WWW 256
#define QKCH 32

typedef unsigned short u16;
typedef unsigned short ushort8_t __attribute__((ext_vector_type(8)));
typedef short s16x8 __attribute__((ext_vector_type(8)));
typedef float f32x4 __attribute__((ext_vector_type(4)));

__device__ __forceinline__ float bf2f(u16 u) { return __uint_as_float(((unsigned)u) << 16); }
__device__ __forceinline__ u16 f2bf(float f) {
    __hip_bfloat16 h = __float2bfloat16(f);
    return *reinterpret_cast<u16*>(&h);
}
__device__ __forceinline__ float sigmoidf_(float x) { return 1.f / (1.f + __expf(-x)); }
__device__ __forceinline__ float gelu_exact(float x) {
    return 0.5f * x * (1.f + erff(x * 0.70710678118654752f));
}

__global__ void diag_kernel(float* out, float v) {
    if (threadIdx.x == 0 && blockIdx.x == 0) out[0] = v;
}

// one-shot weight prep: bf16 casts + wtap rearrange.
__global__ __launch_bounds__(256) void prep_misc(
    const float* __restrict__ wout, const float* __restrict__ wh1,
    u16* __restrict__ dout, u16* __restrict__ wtap)
{
    int bid = blockIdx.x;
    if (bid < 32) {
        long i = (long)bid * 1024 + threadIdx.x * 4;
        float4 v = *(const float4*)(wout + i);
        ushort4 o;
        o.x = f2bf(v.x); o.y = f2bf(v.y); o.z = f2bf(v.z); o.w = f2bf(v.w);
        *(ushort4*)(dout + i) = o;
    } else {
        int tap = bid - 32;
        for (int e = threadIdx.x; e < 2048; e += 256)
            wtap[tap * 2048 + e] = f2bf(wh1[(long)e * 9 + tap]);
    }
}

// combined fuse weight: w_comb[o][c<64] = sum_k w_fu[o][k] w_ir[k][c],
// w_comb[o][64+c] = sum_k w_fu[o][128+k] w_vi[k][c]. bf16 out. grid (64)
__global__ __launch_bounds__(256) void prep_comb(
    const float* __restrict__ wfu, const float* __restrict__ wir,
    const float* __restrict__ wvi, u16* __restrict__ wcomb)
{
    int idx = blockIdx.x * 256 + threadIdx.x;  // 128*128
    int o = idx >> 7, cc = idx & 127;
    float s = 0.f;
    if (cc < 64) {
        for (int k = 0; k < 128; ++k) s = fmaf(wfu[o * 256 + k], wir[k * 64 + cc], s);
    } else {
        for (int k = 0; k < 128; ++k) s = fmaf(wfu[o * 256 + 128 + k], wvi[k * 64 + cc - 64], s);
    }
    wcomb[idx] = f2bf(s);
}

// la/ha means from input means: means[b][k]=w_ir[k]·mb, means[b][128+k]=w_vi[k]·md.
// grid (nb), block 256
__global__ void means_xform(
    const float* __restrict__ inmean, const float* __restrict__ wir,
    const float* __restrict__ wvi, float* __restrict__ means)
{
    int b = blockIdx.x, t = threadIdx.x;
    float s = 0.f;
    if (t < 128) {
        for (int c = 0; c < 64; ++c) s = fmaf(wir[t * 64 + c], inmean[b * 128 + c], s);
    } else {
        for (int c = 0; c < 64; ++c) s = fmaf(wvi[(t - 128) * 64 + c], inmean[b * 128 + 64 + c], s);
    }
    means[b * 256 + t] = s;
}

// fold LN gamma/beta into qkv / ffn-in weights; bf16 weights + fp32 bias.
__global__ void fold_ln(
    const float* __restrict__ wqkv, const float* __restrict__ ln1w, const float* __restrict__ ln1b,
    const float* __restrict__ win,  const float* __restrict__ ln2w, const float* __restrict__ ln2b,
    u16* __restrict__ fq, float* __restrict__ fqB,
    u16* __restrict__ ff, float* __restrict__ ffB)
{
    int g = blockIdx.x;
    int i = g / 7, r = g % 7;
    const float *wsrc, *lg, *lb;
    u16* wd; float* Bd;
    int obase;
    if (r < 3) {
        wsrc = wqkv + (long)i * 192 * 64; lg = ln1w + i * 64; lb = ln1b + i * 64;
        wd = fq + (long)i * 192 * 64; Bd = fqB + i * 192; obase = r * 64;
    } else {
        wsrc = win + (long)i * 256 * 64; lg = ln2w + i * 64; lb = ln2b + i * 64;
        wd = ff + (long)i * 256 * 64; Bd = ffB + i * 256; obase = (r - 3) * 64;
    }
    int o = obase + threadIdx.x;
    float Bv = 0.f;
    for (int c = 0; c < 64; ++c) {
        float wv = wsrc[(long)o * 64 + c];
        wd[(long)o * 64 + c] = f2bf(wv * lg[c]);
        Bv += wv * lb[c];
    }
    Bd[o] = Bv;
}

// ---------------------------------------------------------------------------
// Fuse GEMM direct from fp32 base/detail with combined 128x128 weight + b_fu,
// computing per-channel input means (base|detail) via atomics (oBase==0 only).
// grid (2, 256, nb)
// ---------------------------------------------------------------------------
__global__ __launch_bounds__(256) void gemm_fuse128(
    const float* __restrict__ base, const float* __restrict__ detail,
    const u16* __restrict__ wcomb, const float* __restrict__ bias,
    u16* __restrict__ Dq, float* __restrict__ inmean)
{
    __shared__ u16 XT[256][72];
    __shared__ u16 WT[64][72];
    __shared__ float red[4][128];
    int b = blockIdx.z;
    int oBase = blockIdx.x * 64;
    long P0 = (long)blockIdx.y * 256;
    int tid = threadIdx.x, lane = tid & 63, wave = tid >> 6;
    int rl = lane & 15, rg = lane >> 4;

    f32x4 acc[4][4];
#pragma unroll
    for (int m = 0; m < 4; ++m)
#pragma unroll
        for (int n = 0; n < 4; ++n) acc[m][n] = (f32x4){0.f, 0.f, 0.f, 0.f};

#pragma unroll
    for (int ch = 0; ch < 2; ++ch) {
        int ck = ch * 64;
        if (ch) __syncthreads();
        {
            int o = tid >> 2, cs = (tid & 3) * 16;
            const u16* src = wcomb + (long)(oBase + o) * 128 + ck + cs;
            *(ushort8_t*)&WT[o][cs] = *(const ushort8_t*)src;
            *(ushort8_t*)&WT[o][cs + 8] = *(const ushort8_t*)(src + 8);
        }
        {
            const float* in = ((ch == 0) ? base : detail) + (long)b * 64 * NP;
            int c0 = (tid & 7) * 8;
            int pt = (tid >> 3) * 8;
            u16 rr[8][8];
            float ls[8];
#pragma unroll
            for (int i = 0; i < 8; ++i) {
                const float* sp = in + (long)(c0 + i) * NP + P0 + pt;
                float4 a = *(const float4*)sp;
                float4 b4 = *(const float4*)(sp + 4);
                rr[i][0] = f2bf(a.x); rr[i][1] = f2bf(a.y);
                rr[i][2] = f2bf(a.z); rr[i][3] = f2bf(a.w);
                rr[i][4] = f2bf(b4.x); rr[i][5] = f2bf(b4.y);
                rr[i][6] = f2bf(b4.z); rr[i][7] = f2bf(b4.w);
                ls[i] = a.x + a.y + a.z + a.w + b4.x + b4.y + b4.z + b4.w;
            }
#pragma unroll
            for (int j = 0; j < 8; ++j) {
                ushort8_t v;
#pragma unroll
                for (int i = 0; i < 8; ++i) v[i] = rr[i][j];
                *(ushort8_t*)&XT[pt + j][c0] = v;
            }
            if (oBase == 0) {
#pragma unroll
                for (int i = 0; i < 8; ++i) {
                    float v = ls[i];
                    v += __shfl_xor(v, 8);
                    v += __shfl_xor(v, 16);
                    v += __shfl_xor(v, 32);
                    if ((lane & 56) == 0) red[wave][ck + c0 + i] = v;
                }
            }
        }
        __syncthreads();
#pragma unroll
        for (int ks = 0; ks < 2; ++ks) {
            int kc = ks * 32 + rg * 8;
            s16x8 a[4], bb[4];
#pragma unroll
            for (int m = 0; m < 4; ++m) a[m] = *(const s16x8*)&WT[m * 16 + rl][kc];
#pragma unroll
            for (int n = 0; n < 4; ++n) bb[n] = *(const s16x8*)&XT[wave * 64 + n * 16 + rl][kc];
#pragma unroll
            for (int m = 0; m < 4; ++m)
#pragma unroll
                for (int n = 0; n < 4; ++n)
                    acc[m][n] = __builtin_amdgcn_mfma_f32_16x16x32_bf16(a[m], bb[n], acc[m][n], 0, 0, 0);
        }
    }
#pragma unroll
    for (int m = 0; m < 4; ++m) {
#pragma unroll
        for (int n = 0; n < 4; ++n) {
            long px = P0 + wave * 64 + n * 16 + rl;
#pragma unroll
            for (int r = 0; r < 4; ++r) {
                int oo = oBase + m * 16 + rg * 4 + r;
                Dq[((long)b * 128 + oo) * NP + px] = f2bf(acc[m][n][r] + bias[oo]);
            }
        }
    }
    if (oBase == 0) {
        __syncthreads();
        if (tid < 128) {
            float v = red[0][tid] + red[1][tid] + red[2][tid] + red[3][tid];
            atomicAdd(&inmean[b * 128 + tid], v * (1.f / NP));
        }
    }
}

// ---------------------------------------------------------------------------
// Fused GEMM -> X -> LN -> LDS -> second GEMM -> Y(bf16).
// 128-px tiles. grid (512, 1, nb). PIXMAJ: write X pixel-major for head.
// ---------------------------------------------------------------------------
template<int WEFF, int RESID, int DUAL, int M2, int PIXMAJ>
__global__ __launch_bounds__(256) void gemm_fused(
    const u16* __restrict__ in, long inBS,
    const u16* __restrict__ w1, long w1BS,
    const u16* __restrict__ residX,
    u16* __restrict__ Xout,
    float* __restrict__ out2,
    const u16* __restrict__ w2, const float* __restrict__ bias2,
    u16* __restrict__ Yout,
    const float* __restrict__ part, const float* __restrict__ temp,
    const float* __restrict__ wproj,
    int Cin)
{
    __shared__ u16 XT[128][72] __attribute__((aligned(16)));
    __shared__ u16 WT[64][72] __attribute__((aligned(16)));
    int b = blockIdx.z;
    long P0 = (long)blockIdx.x * 128;
    int tid = threadIdx.x, lane = tid & 63, wave = tid >> 6;
    int rl = lane & 15, rg = lane >> 4;
    const u16* inB = in + (long)b * inBS;

    if constexpr (WEFF) {
        float* SgF = (float*)&XT[0][0];
        float* attF = SgF + 640;
        for (int e = tid; e < 640; e += 256) {
            int h = e / 80, k = e % 80;
            const float* pp = part + (((long)b * 8 + h) * 80 + k) * QKCH;
            float s = 0.f;
#pragma unroll
            for (int c = 0; c < QKCH; ++c) s += pp[c];
            SgF[e] = s;
        }
        __syncthreads();
        if (tid < 64) {
            int h = tid >> 3, iq = tid & 7;
            float nqv = fmaxf(sqrtf(SgF[h * 80 + 64 + iq]), 1e-12f);
            float tp = temp[h];
            float row[8], mx = -1e30f;
#pragma unroll
            for (int jj = 0; jj < 8; ++jj) {
                float nkv = fmaxf(sqrtf(SgF[h * 80 + 72 + jj]), 1e-12f);
                row[jj] = SgF[h * 80 + iq * 8 + jj] / (nqv * nkv) * tp;
                mx = fmaxf(mx, row[jj]);
            }
            float sum = 0.f;
#pragma unroll
            for (int jj = 0; jj < 8; ++jj) { row[jj] = __expf(row[jj] - mx); sum += row[jj]; }
            float rinv = 1.f / sum;
#pragma unroll
            for (int jj = 0; jj < 8; ++jj) attF[(h * 8 + iq) * 8 + jj] = row[jj] * rinv;
        }
        __syncthreads();
        {
            int o = tid >> 2;
            int cv0 = (tid & 3) * 16;
#pragma unroll
            for (int cv = 0; cv < 16; ++cv) {
                int c = cv0 + cv;
                int h = c >> 3, jj = c & 7;
                float s = 0.f;
#pragma unroll
                for (int i = 0; i < 8; ++i)
                    s = fmaf(wproj[o * 64 + h * 8 + i], attF[(h * 8 + i) * 8 + jj], s);
                WT[o][c] = f2bf(s);
            }
        }
        __syncthreads();
    }

    f32x4 acc[4][2];
#pragma unroll
    for (int m = 0; m < 4; ++m)
#pragma unroll
        for (int n = 0; n < 2; ++n) acc[m][n] = (f32x4){0.f, 0.f, 0.f, 0.f};

    for (int ck = 0; ck < Cin; ck += 64) {
        if (ck) __syncthreads();
        if constexpr (!WEFF) {
            int o = tid >> 2, cs = (tid & 3) * 16;
            const u16* src = w1 + (long)b * w1BS + (long)o * Cin + ck + cs;
            *(ushort8_t*)&WT[o][cs] = *(const ushort8_t*)src;
            *(ushort8_t*)&WT[o][cs + 8] = *(const ushort8_t*)(src + 8);
        }
        if (tid < 128) {
            int c0 = (tid & 7) * 8;
            int pt = (tid >> 3) * 8;
            ushort8_t r[8];
#pragma unroll
            for (int i = 0; i < 8; ++i)
                r[i] = *(const ushort8_t*)(inB + (long)(ck + c0 + i) * NP + P0 + pt);
#pragma unroll
            for (int j = 0; j < 8; ++j) {
                ushort8_t v;
#pragma unroll
                for (int i = 0; i < 8; ++i) v[i] = r[i][j];
                *(ushort8_t*)&XT[pt + j][c0] = v;
            }
        }
        __syncthreads();
#pragma unroll
        for (int ks = 0; ks < 2; ++ks) {
            int kc = ks * 32 + rg * 8;
            s16x8 a[4], bb[2];
#pragma unroll
            for (int m = 0; m < 4; ++m) a[m] = *(const s16x8*)&WT[m * 16 + rl][kc];
#pragma unroll
            for (int n = 0; n < 2; ++n) bb[n] = *(const s16x8*)&XT[wave * 32 + n * 16 + rl][kc];
#pragma unroll
            for (int m = 0; m < 4; ++m)
#pragma unroll
                for (int n = 0; n < 2; ++n)
                    acc[m][n] = __builtin_amdgcn_mfma_f32_16x16x32_bf16(a[m], bb[n], acc[m][n], 0, 0, 0);
        }
    }

#pragma unroll
    for (int m = 0; m < 4; ++m)
#pragma unroll
        for (int n = 0; n < 2; ++n) {
            long px = P0 + wave * 32 + n * 16 + rl;
#pragma unroll
            for (int r = 0; r < 4; ++r) {
                int oo = m * 16 + rg * 4 + r;
                float t = acc[m][n][r];
                if constexpr (RESID) t += bf2f(residX[((long)b * 64 + oo) * NP + px]);
                acc[m][n][r] = t;
                if constexpr (!PIXMAJ) Xout[((long)b * 64 + oo) * NP + px] = f2bf(t);
                if constexpr (DUAL) out2[((long)b * 64 + oo) * NP + px] = t;
            }
        }

    if constexpr (PIXMAJ) {
        __syncthreads();
#pragma unroll
        for (int m = 0; m < 4; ++m)
#pragma unroll
            for (int n = 0; n < 2; ++n) {
                int pxl = wave * 32 + n * 16 + rl;
#pragma unroll
                for (int r = 0; r < 4; ++r)
                    XT[pxl][m * 16 + rg * 4 + r] = f2bf(acc[m][n][r]);
            }
        __syncthreads();
        int pxl = tid >> 1, c0 = (tid & 1) * 32;
        u16* dst = Xout + (long)b * (64 * NP) + (P0 + pxl) * 64 + c0;
        *(ushort8_t*)(dst)      = *(const ushort8_t*)&XT[pxl][c0];
        *(ushort8_t*)(dst + 8)  = *(const ushort8_t*)&XT[pxl][c0 + 8];
        *(ushort8_t*)(dst + 16) = *(const ushort8_t*)&XT[pxl][c0 + 16];
        *(ushort8_t*)(dst + 24) = *(const ushort8_t*)&XT[pxl][c0 + 24];
    }

    if constexpr (M2 > 0) {
        float muA[2], invA[2];
#pragma unroll
        for (int n = 0; n < 2; ++n) {
            float s = 0.f, s2 = 0.f;
#pragma unroll
            for (int m = 0; m < 4; ++m)
#pragma unroll
                for (int r = 0; r < 4; ++r) {
                    float t = acc[m][n][r];
                    s += t; s2 = fmaf(t, t, s2);
                }
            s += __shfl_xor(s, 16);  s += __shfl_xor(s, 32);
            s2 += __shfl_xor(s2, 16); s2 += __shfl_xor(s2, 32);
            float mu = s * (1.f / 64.f);
            float var = fmaxf(s2 * (1.f / 64.f) - mu * mu, 0.f);
            muA[n] = mu;
            invA[n] = rsqrtf(var + 1e-5f);
        }
        __syncthreads();
#pragma unroll
        for (int m = 0; m < 4; ++m)
#pragma unroll
            for (int n = 0; n < 2; ++n) {
                int pxl = wave * 32 + n * 16 + rl;
#pragma unroll
                for (int r = 0; r < 4; ++r)
                    XT[pxl][m * 16 + rg * 4 + r] = f2bf((acc[m][n][r] - muA[n]) * invA[n]);
            }
        __syncthreads();
        for (int mc = 0; mc < M2 / 64; ++mc) {
            if (mc) __syncthreads();
            {
                int o = tid >> 2, cs = (tid & 3) * 16;
                const u16* src = w2 + (long)(mc * 64 + o) * 64 + cs;
                *(ushort8_t*)&WT[o][cs] = *(const ushort8_t*)src;
                *(ushort8_t*)&WT[o][cs + 8] = *(const ushort8_t*)(src + 8);
            }
            __syncthreads();
            f32x4 a2[4][2];
#pragma unroll
            for (int m = 0; m < 4; ++m)
#pragma unroll
                for (int n = 0; n < 2; ++n) a2[m][n] = (f32x4){0.f, 0.f, 0.f, 0.f};
#pragma unroll
            for (int ks = 0; ks < 2; ++ks) {
                int kc = ks * 32 + rg * 8;
                s16x8 a[4], bb[2];
#pragma unroll
                for (int m = 0; m < 4; ++m) a[m] = *(const s16x8*)&WT[m * 16 + rl][kc];
#pragma unroll
                for (int n = 0; n < 2; ++n) bb[n] = *(const s16x8*)&XT[wave * 32 + n * 16 + rl][kc];
#pragma unroll
                for (int m = 0; m < 4; ++m)
#pragma unroll
                    for (int n = 0; n < 2; ++n)
                        a2[m][n] = __builtin_amdgcn_mfma_f32_16x16x32_bf16(a[m], bb[n], a2[m][n], 0, 0, 0);
            }
#pragma unroll
            for (int m = 0; m < 4; ++m) {
#pragma unroll
                for (int n = 0; n < 2; ++n) {
                    long px = P0 + wave * 32 + n * 16 + rl;
#pragma unroll
                    for (int r = 0; r < 4; ++r) {
                        int oo = mc * 64 + m * 16 + rg * 4 + r;
                        Yout[((long)b * 256 + oo) * NP + px] = f2bf(a2[m][n][r] + bias2[oo]);
                    }
                }
            }
        }
    }
}

// stage one LDS row (16 px) of a bf16 channel strip
__device__ __forceinline__ void stage_row(float (*S)[260], const u16* __restrict__ src,
                                          int y0, int j, int px)
{
    int row = y0 - 1 + j;
    if (row >= 0 && row < HHH) {
        ushort8_t a = *(const ushort8_t*)(src + row * WWW + px);
        ushort8_t b = *(const ushort8_t*)(src + row * WWW + px + 8);
#pragma unroll
        for (int e = 0; e < 8; ++e) { S[j][1 + px + e] = bf2f(a[e]); S[j][9 + px + e] = bf2f(b[e]); }
    } else {
#pragma unroll
        for (int e = 0; e < 16; ++e) S[j][1 + px + e] = 0.f;
    }
}
__device__ __forceinline__ float conv9(const float (*S)[260], int r, int col,
                                       const float* __restrict__ w9)
{
    float a = 0.f;
#pragma unroll
    for (int ky = 0; ky < 3; ++ky)
#pragma unroll
        for (int kx = 0; kx < 3; ++kx)
            a = fmaf(w9[ky * 3 + kx], S[r + ky][col + kx], a);
    return a;
}

// depthwise 3x3, 16-row strips, vectorized stores, split output routing.
// grid (16, C, nb)
__global__ __launch_bounds__(256) void dw3x3_strip(
    const u16* __restrict__ in, long inBS, const float* __restrict__ w,
    u16* __restrict__ out1, long out1BS,
    u16* __restrict__ out2, long out2BS, int obase2, int csplit)
{
    int strip = blockIdx.x, c = blockIdx.y, b = blockIdx.z;
    int y0 = strip * 16, tid = threadIdx.x;
    __shared__ float S[18][260];
    const u16* src = in + (long)b * inBS + (long)c * NP;
    int j = tid >> 4, px = (tid & 15) * 16;
    stage_row(S, src, y0, j, px);
    if (tid < 32) stage_row(S, src, y0, 16 + (tid >> 4), px);
    if (tid < 18) { S[tid][0] = 0.f; S[tid][257] = 0.f; }
    __syncthreads();
    float w9[9];
#pragma unroll
    for (int k = 0; k < 9; ++k) w9[k] = w[c * 9 + k];
    u16* dst = (c < csplit)
                   ? out1 + (long)b * out1BS + (long)c * NP
                   : out2 + (long)b * out2BS + (long)(obase2 + c - csplit) * NP;
    int px4 = (tid & 63) * 4;
    int r0 = (tid >> 6) * 4;
#pragma unroll
    for (int r = 0; r < 4; ++r) {
        int row = r0 + r;
        ushort4 ovec;
        u16* ov = (u16*)&ovec;
#pragma unroll
        for (int e = 0; e < 4; ++e) ov[e] = f2bf(conv9(S, row, px4 + e, w9));
        *(ushort4*)&dst[(y0 + row) * WWW + px4] = ovec;
    }
}

// ffn: dw3x3 on (c, c+128) + gelu(y1)*y2, strips, vectorized. grid (16, 128, nb)
__global__ __launch_bounds__(256) void ffn_dw_glu_strip(
    const u16* __restrict__ y, long yBS, const float* __restrict__ w,
    u16* __restrict__ g, long gBS)
{
    int strip = blockIdx.x, c = blockIdx.y, b = blockIdx.z;
    int y0 = strip * 16, tid = threadIdx.x;
    __shared__ float S1[18][260];
    __shared__ float S2[18][260];
    const u16* s1 = y + (long)b * yBS + (long)c * NP;
    const u16* s2 = y + (long)b * yBS + (long)(c + 128) * NP;
    int j = tid >> 4, px = (tid & 15) * 16;
    stage_row(S1, s1, y0, j, px);
    if (tid < 32) stage_row(S1, s1, y0, 16 + (tid >> 4), px);
    stage_row(S2, s2, y0, j, px);
    if (tid < 32) stage_row(S2, s2, y0, 16 + (tid >> 4), px);
    if (tid < 18) { S1[tid][0] = S1[tid][257] = 0.f; S2[tid][0] = S2[tid][257] = 0.f; }
    __syncthreads();
    float w1[9], w2[9];
#pragma unroll
    for (int k = 0; k < 9; ++k) { w1[k] = w[c * 9 + k]; w2[k] = w[(c + 128) * 9 + k]; }
    u16* dst = g + (long)b * gBS + (long)c * NP;
    int px4 = (tid & 63) * 4;
    int r0 = (tid >> 6) * 4;
#pragma unroll
    for (int r = 0; r < 4; ++r) {
        int row = r0 + r;
        ushort4 ovec;
        u16* ov = (u16*)&ovec;
#pragma unroll
        for (int e = 0; e < 4; ++e) {
            float a1 = conv9(S1, row, px4 + e, w1);
            float a2 = conv9(S2, row, px4 + e, w2);
            ov[e] = f2bf(gelu_exact(a1) * a2);
        }
        *(ushort4*)&dst[(y0 + row) * WWW + px4] = ovec;
    }
}

// CIIM grouped dw conv + gating + channel shuffle + ecam atomics, strips.
// grid (16, 64, nb)
__global__ __launch_bounds__(256) void ciim_dw_gate(
    const u16* __restrict__ fuse, long fBS, const float* __restrict__ means,
    const float* __restrict__ wdw, const float* __restrict__ bdw,
    const float* __restrict__ low, long lBS, const float* __restrict__ high,
    u16* __restrict__ Yout, long yBS, float* __restrict__ ecam)
{
    int strip = blockIdx.x, c = blockIdx.y, b = blockIdx.z;
    int y0 = strip * 16, tid = threadIdx.x;
    __shared__ float S[18][260];
    int px4 = (tid & 63) * 4;
    int r0 = (tid >> 6) * 4;
    float acc[4][4];
    float bias = bdw[c];
#pragma unroll
    for (int r = 0; r < 4; ++r)
#pragma unroll
        for (int e = 0; e < 4; ++e) acc[r][e] = bias;
    for (int j6 = 0; j6 < 6; ++j6) {
        int ic = 6 * c + j6;
        const float* w9p = wdw + (c * 6 + j6) * 9;
        float w9[9];
#pragma unroll
        for (int k = 0; k < 9; ++k) w9[k] = w9p[k];
        if (ic < 128) {
            __syncthreads();
            const u16* src = fuse + (long)b * fBS + (long)ic * NP;
            int j = tid >> 4, px = (tid & 15) * 16;
            stage_row(S, src, y0, j, px);
            if (tid < 32) stage_row(S, src, y0, 16 + (tid >> 4), px);
            if (tid < 18) { S[tid][0] = 0.f; S[tid][257] = 0.f; }
            __syncthreads();
#pragma unroll
            for (int r = 0; r < 4; ++r)
#pragma unroll
                for (int e = 0; e < 4; ++e) acc[r][e] += conv9(S, r0 + r, px4 + e, w9);
        } else {
            float mv = means[b * 256 + ic - 128];
#pragma unroll
            for (int r = 0; r < 4; ++r) {
                int row = y0 + r0 + r;
#pragma unroll
                for (int e = 0; e < 4; ++e) {
                    int xc = px4 + e;
                    float ws = 0.f;
#pragma unroll
                    for (int ky = 0; ky < 3; ++ky) {
                        int yy = row + ky - 1;
                        if (yy < 0 || yy >= HHH) continue;
#pragma unroll
                        for (int kx = 0; kx < 3; ++kx) {
                            int xx = xc + kx - 1;
                            if (xx < 0 || xx >= WWW) continue;
                            ws += w9[ky * 3 + kx];
                        }
                    }
                    acc[r][e] += mv * ws;
                }
            }
        }
    }
    int cn1 = 32 * (c & 3) + (c >> 2);
    int cn2 = cn1 + 16;
    u16* d1 = Yout + (long)b * yBS + (long)cn1 * NP;
    u16* d2 = Yout + (long)b * yBS + (long)cn2 * NP;
    const float* lp = low + (long)b * lBS + (long)c * NP;
    const float* hp = high + (long)b * lBS + (long)c * NP;
    float s1 = 0.f, s2 = 0.f;
#pragma unroll
    for (int r = 0; r < 4; ++r) {
        int row = y0 + r0 + r;
        float4 lv = *(const float4*)(lp + row * WWW + px4);
        float4 hv = *(const float4*)(hp + row * WWW + px4);
        float l4[4] = {lv.x, lv.y, lv.z, lv.w};
        float h4[4] = {hv.x, hv.y, hv.z, hv.w};
        ushort4 o1, o2;
        u16* p1 = (u16*)&o1;
        u16* p2 = (u16*)&o2;
#pragma unroll
        for (int e = 0; e < 4; ++e) {
            float hl = acc[r][e];
            float v1 = sigmoidf_(gelu_exact(hl)) * l4[e];
            float v2 = sigmoidf_(fmaxf(hl, 0.f)) * h4[e];
            p1[e] = f2bf(v1); p2[e] = f2bf(v2);
            s1 += v1; s2 += v2;
        }
        *(ushort4*)&d1[row * WWW + px4] = o1;
        *(ushort4*)&d2[row * WWW + px4] = o2;
    }
    __syncthreads();
    float* redbuf = &S[0][0];
    redbuf[tid] = s1; redbuf[256 + tid] = s2;
    __syncthreads();
    for (int st = 128; st > 0; st >>= 1) {
        if (tid < st) { redbuf[tid] += redbuf[tid + st]; redbuf[256 + tid] += redbuf[256 + tid + st]; }
        __syncthreads();
    }
    if (tid == 0) {
        atomicAdd(&ecam[b * 128 + cn1], redbuf[0] * (1.f / NP));
        atomicAdd(&ecam[b * 128 + cn2], redbuf[256] * (1.f / NP));
    }
}

// scaled rc2 weights (bf16). grid (nb*32)
__global__ __launch_bounds__(256) void rc2w_build(
    const float* __restrict__ ecam, const float* __restrict__ ecaw,
    const float* __restrict__ wrc2, u16* __restrict__ wout)
{
    int idx = blockIdx.x * 256 + threadIdx.x;
    int c = idx & 127, o = (idx >> 7) & 63, b = idx >> 13;
    float y = sigmoidf_(ecam[b * 128 + c] * ecaw[c]);
    wout[idx] = f2bf(wrc2[o * 128 + c] * y);
}

// q.k dots + sumsq norms over pixel chunks. grid (QKCH, 8, nb)
__global__ __launch_bounds__(256) void qk_dot(
    const u16* __restrict__ D, long dBS, float* __restrict__ part)
{
    int chunk = blockIdx.x, h = blockIdx.y, b = blockIdx.z;
    int tid = threadIdx.x, lane = tid & 63, wave = tid >> 6;
    const u16* q = D + (long)b * dBS + (long)(h * 8) * NP;
    const u16* k = q + 64 * NP;
    float dots[64], nq[8], nk[8];
#pragma unroll
    for (int a = 0; a < 64; ++a) dots[a] = 0.f;
#pragma unroll
    for (int a = 0; a < 8; ++a) { nq[a] = 0.f; nk[a] = 0.f; }
    long p = (long)chunk * 2048 + tid * 8;
    {
        ushort8_t qv[8], kv[8];
#pragma unroll
        for (int i = 0; i < 8; ++i) qv[i] = *(const ushort8_t*)(q + (long)i * NP + p);
#pragma unroll
        for (int i = 0; i < 8; ++i) kv[i] = *(const ushort8_t*)(k + (long)i * NP + p);
#pragma unroll
        for (int e = 0; e < 8; ++e) {
            float qe[8], ke[8];
#pragma unroll
            for (int i = 0; i < 8; ++i) { qe[i] = bf2f(qv[i][e]); ke[i] = bf2f(kv[i][e]); }
#pragma unroll
            for (int i = 0; i < 8; ++i) {
                nq[i] = fmaf(qe[i], qe[i], nq[i]);
                nk[i] = fmaf(ke[i], ke[i], nk[i]);
#pragma unroll
                for (int jj = 0; jj < 8; ++jj)
                    dots[i * 8 + jj] = fmaf(qe[i], ke[jj], dots[i * 8 + jj]);
            }
        }
    }
    __shared__ float red[4][80];
#pragma unroll
    for (int a = 0; a < 64; ++a) {
        float v = dots[a];
#pragma unroll
        for (int o = 32; o > 0; o >>= 1) v += __shfl_xor(v, o);
        if (lane == 0) red[wave][a] = v;
    }
#pragma unroll
    for (int a = 0; a < 8; ++a) {
        float v1 = nq[a], v2 = nk[a];
#pragma unroll
        for (int o = 32; o > 0; o >>= 1) { v1 += __shfl_xor(v1, o); v2 += __shfl_xor(v2, o); }
        if (lane == 0) { red[wave][64 + a] = v1; red[wave][72 + a] = v2; }
    }
    __syncthreads();
    if (tid < 80) {
        float v = red[0][tid] + red[1][tid] + red[2][tid] + red[3][tid];
        part[(((long)b * 8 + h) * 80 + tid) * QKCH + chunk] = v;
    }
}

// head: conv1 (MFMA) + leaky + conv2 + inp + sigmoid. Xp pixel-major. grid (19,19,nb)
__global__ __launch_bounds__(256) void head_fused(
    const u16* __restrict__ Xp, const u16* __restrict__ wtap,
    const float* __restrict__ wh2, const float* __restrict__ inp,
    float* __restrict__ out)
{
    __shared__ u16 P[18][18][72] __attribute__((aligned(16)));
    __shared__ u16 Hl[16][16][40] __attribute__((aligned(16)));
    __shared__ float w2t[288];
    int ty = blockIdx.x, tx = blockIdx.y, b = blockIdx.z;
    int tid = threadIdx.x, lane = tid & 63, wave = tid >> 6;
    int rl = lane & 15, rg = lane >> 4;
    int oy = ty * 14 - 2, ox = tx * 14 - 2;
    for (int idx = tid; idx < 288; idx += 256)
        w2t[(idx % 9) * 32 + idx / 9] = wh2[idx];
    {
        const u16* xb = Xp + (long)b * (64 * NP);
        int c0 = (tid & 7) * 8;
        for (int pp = tid >> 3; pp < 324; pp += 32) {
            int row = pp / 18, col = pp % 18;
            int gy = oy + row, gx = ox + col;
            ushort8_t v;
            if (gy >= 0 && gy < HHH && gx >= 0 && gx < WWW)
                v = *(const ushort8_t*)(xb + ((long)(gy * WWW + gx)) * 64 + c0);
            else
                v = (ushort8_t){0, 0, 0, 0, 0, 0, 0, 0};
            *(ushort8_t*)&P[row][col][c0] = v;
        }
    }
    __syncthreads();
    f32x4 acc[2][4];
#pragma unroll
    for (int m = 0; m < 2; ++m)
#pragma unroll
        for (int n = 0; n < 4; ++n) acc[m][n] = (f32x4){0.f, 0.f, 0.f, 0.f};
#pragma unroll
    for (int tap = 0; tap < 9; ++tap) {
        int ky = tap / 3, kx = tap % 3;
#pragma unroll
        for (int ks = 0; ks < 2; ++ks) {
            int kc = ks * 32 + rg * 8;
            s16x8 a0 = *(const s16x8*)(wtap + tap * 2048 + (long)(0 + rl) * 64 + kc);
            s16x8 a1 = *(const s16x8*)(wtap + tap * 2048 + (long)(16 + rl) * 64 + kc);
#pragma unroll
            for (int n = 0; n < 4; ++n) {
                int py = wave * 4 + n;
                s16x8 bb = *(const s16x8*)&P[py + ky][kx + rl][kc];
                acc[0][n] = __builtin_amdgcn_mfma_f32_16x16x32_bf16(a0, bb, acc[0][n], 0, 0, 0);
                acc[1][n] = __builtin_amdgcn_mfma_f32_16x16x32_bf16(a1, bb, acc[1][n], 0, 0, 0);
            }
        }
    }
#pragma unroll
    for (int m = 0; m < 2; ++m)
#pragma unroll
        for (int n = 0; n < 4; ++n) {
            int py = wave * 4 + n;
            int gy = ty * 14 - 1 + py, gx = tx * 14 - 1 + rl;
            bool ok = (gy >= 0 && gy < HHH && gx >= 0 && gx < WWW);
#pragma unroll
            for (int r = 0; r < 4; ++r) {
                int o = m * 16 + rg * 4 + r;
                float v = acc[m][n][r];
                v = v > 0.f ? v : 0.01f * v;
                Hl[py][rl][o] = ok ? f2bf(v) : (u16)0;
            }
        }
    __syncthreads();
    if (tid < 196) {
        int r = tid / 14, c = tid % 14;
        int gy = ty * 14 + r, gx = tx * 14 + c;
        if (gy < HHH && gx < WWW) {
            float acc2 = 0.f;
#pragma unroll
            for (int tap = 0; tap < 9; ++tap) {
                int hy = r + tap / 3, hx = c + tap % 3;
#pragma unroll
                for (int cg = 0; cg < 4; ++cg) {
                    ushort8_t hv = *(const ushort8_t*)&Hl[hy][hx][cg * 8];
#pragma unroll
                    for (int e = 0; e < 8; ++e)
                        acc2 = fmaf(w2t[tap * 32 + cg * 8 + e], bf2f(hv[e]), acc2);
                }
            }
            float v = acc2 + inp[(long)b * NP + gy * WWW + gx];
            out[(long)b * NP + gy * WWW + gx] = 1.f / (1.f + expf(-v));
        }
    }
}

// ---------------------------------------------------------------------------
extern "C" void kernel_launch(void* const* d_in, const int* in_sizes, int n_in,
                              void* d_out, int out_size, void* d_ws, size_t ws_size,
                              hipStream_t stream)
{
    const float* inp    = (const float*)d_in[0];
    const float* base   = (const float*)d_in[1];
    const float* detail = (const float*)d_in[2];
    const float* w_ir   = (const float*)d_in[3];
    const float* w_vi   = (const float*)d_in[4];
    const float* w_fu   = (const float*)d_in[5];
    const float* b_fu   = (const float*)d_in[6];
    const float* w_dwc  = (const float*)d_in[7];
    const float* b_dwc  = (const float*)d_in[8];
    const float* eca_w  = (const float*)d_in[9];
    const float* w_rc2  = (const float*)d_in[10];
    const float* ln1w   = (const float*)d_in[11];
    const float* ln1b   = (const float*)d_in[12];
    const float* w_qkv  = (const float*)d_in[13];
    const float* w_qdw  = (const float*)d_in[14];
    const float* temp   = (const float*)d_in[15];
    const float* w_proj = (const float*)d_in[16];
    const float* ln2w   = (const float*)d_in[17];
    const float* ln2b   = (const float*)d_in[18];
    const float* w_in_  = (const float*)d_in[19];
    const float* w_fdw  = (const float*)d_in[20];
    const float* w_out_ = (const float*)d_in[21];
    const float* w_h1   = (const float*)d_in[22];
    const float* w_h2   = (const float*)d_in[23];

    float* out = (float*)d_out;

    auto needB = [&](long nb) -> size_t {
        return (size_t)nb * NP * (64 * 2 + 256 * 2 + 128 * 2) + (4u << 20);
    };
    int bInner;
    if (ws_size >= needB(4)) bInner = 4;
    else if (ws_size >= needB(2)) bInner = 2;
    else if (ws_size >= needB(1)) bInner = 1;
    else {
        diag_kernel<<<1, 64, 0, stream>>>(out, (float)(ws_size >> 20));
        return;
    }
    const long nb = bInner;

    char* p = (char*)d_ws;
    auto alloc = [&](size_t bytes) -> char* {
        char* r = p; p += (bytes + 255) & ~(size_t)255; return r;
    };
    u16*   X      = (u16*)alloc((size_t)nb * 64 * NP * 2);
    u16*   Y      = (u16*)alloc((size_t)nb * 256 * NP * 2);
    u16*   Dq     = (u16*)alloc((size_t)nb * 128 * NP * 2);
    float* part   = (float*)alloc((size_t)nb * 8 * 80 * QKCH * 4);
    float* means  = (float*)alloc((size_t)nb * 640 * 4);  // means 256 + ecam 128 + inmean 128 (+pad)
    float* ecam   = means + nb * 256;
    float* inmean = ecam + nb * 128;
    u16*   rc2wb  = (u16*)alloc((size_t)nb * 8192 * 2);
    u16*   fq_bf  = (u16*)alloc((size_t)4 * 192 * 64 * 2);
    float* fqB    = (float*)alloc((size_t)4 * 192 * 4);
    u16*   ff_bf  = (u16*)alloc((size_t)4 * 256 * 64 * 2);
    float* ffB    = (float*)alloc((size_t)4 * 256 * 4);
    u16*   wcomb  = (u16*)alloc(16384 * 2);
    u16*   wout_bf= (u16*)alloc(32768 * 2);
    u16*   wtap   = (u16*)alloc(9 * 2048 * 2);

    dim3 blk(256);

    fold_ln<<<dim3(28), dim3(64), 0, stream>>>(w_qkv, ln1w, ln1b, w_in_, ln2w, ln2b,
                                               fq_bf, fqB, ff_bf, ffB);
    prep_misc<<<dim3(41), blk, 0, stream>>>(w_out_, w_h1, wout_bf, wtap);
    prep_comb<<<dim3(64), blk, 0, stream>>>(w_fu, w_ir, w_vi, wcomb);

    for (int b0 = 0; b0 < 4; b0 += bInner) {
        const float* inpB    = inp + (long)b0 * NP;
        const float* baseB   = base + (long)b0 * 64 * NP;
        const float* detailB = detail + (long)b0 * 64 * NP;
        float* out0  = out + (long)b0 * NP;
        float* outX0 = out + 262144 + (long)b0 * 64 * NP;

        // ---- CIIM ----
        hipMemsetAsync(means, 0, (size_t)nb * 640 * 4, stream);
        // fuse conv directly from base/detail (+input means): -> Dq[0:128]
        gemm_fuse128<<<dim3(2, 256, nb), blk, 0, stream>>>(
            baseB, detailB, wcomb, b_fu, Dq, inmean);
        means_xform<<<dim3(nb), blk, 0, stream>>>(inmean, w_ir, w_vi, means);
        // grouped dw + gating + shuffle + ecam: Dq[0:128] -> Y[0:128]
        ciim_dw_gate<<<dim3(16, 64, nb), blk, 0, stream>>>(
            Dq, 128 * NP, means, w_dwc, b_dwc, baseB, 64 * NP, detailB,
            Y, 256 * NP, ecam);
        rc2w_build<<<dim3(nb * 32), blk, 0, stream>>>(ecam, eca_w, w_rc2, rc2wb);
        // rc2 gemm (reads Y[0:128], dual->outX0 fp32) + LN + qkv -> Y[0:192]
        gemm_fused<0, 0, 1, 192, 0><<<dim3(512, 1, nb), blk, 0, stream>>>(
            Y, 256 * NP, rc2wb, 8192, nullptr, X, outX0,
            fq_bf, fqB, Y, nullptr, nullptr, nullptr, 128);

        // ---- transformer blocks ----
        for (int i = 0; i < 4; ++i) {
            // dw on Y[0:192]: q,k -> Dq[0:128]; v -> Y[192:256]
            dw3x3_strip<<<dim3(16, 192, nb), blk, 0, stream>>>(
                Y, 256 * NP, w_qdw + (long)i * 192 * 9,
                Dq, 128 * NP, Y, 256 * NP, 192, 128);
            qk_dot<<<dim3(QKCH, 8, nb), blk, 0, stream>>>(Dq, 128 * NP, part);
            // pv gemm (weff prologue, v from Y[192:256], resid X) + LN + ffn-in -> Y[0:256]
            gemm_fused<1, 1, 0, 256, 0><<<dim3(512, 1, nb), blk, 0, stream>>>(
                Y + 192 * NP, 256 * NP, nullptr, 0, X, X, nullptr,
                ff_bf + (long)i * 256 * 64, ffB + i * 256, Y,
                part, temp + i * 8, w_proj + (long)i * 4096, 64);
            // ffn dw+glu: Y[0:256] -> Dq[0:128]
            ffn_dw_glu_strip<<<dim3(16, 128, nb), blk, 0, stream>>>(
                Y, 256 * NP, w_fdw + (long)i * 256 * 9, Dq, 128 * NP);
            if (i < 3) {
                gemm_fused<0, 1, 0, 192, 0><<<dim3(512, 1, nb), blk, 0, stream>>>(
                    Dq, 128 * NP, wout_bf + (long)i * 8192, 0, X, X, nullptr,
                    fq_bf + (long)(i + 1) * 192 * 64, fqB + (i + 1) * 192, Y,
                    nullptr, nullptr, nullptr, 128);
            } else {
                gemm_fused<0, 1, 0, 0, 1><<<dim3(512, 1, nb), blk, 0, stream>>>(
                    Dq, 128 * NP, wout_bf + (long)i * 8192, 0, X, Y, nullptr,
                    nullptr, nullptr, nullptr, nullptr, nullptr, nullptr, 128);
            }
        }

        // ---- head (reads pixel-major X from Y) ----
        head_fused<<<dim3(19, 19, nb), blk, 0, stream>>>(Y, wtap, w_h2, inpB, out0);
    }
}